// Round 1
// baseline (412.397 us; speedup 1.0000x reference)
//
#include <hip/hip_runtime.h>

// ---------- types ----------
typedef __bf16 bf16x8_t __attribute__((ext_vector_type(8)));
typedef bf16x8_t bf16x8 __attribute__((may_alias));
typedef float f32x4 __attribute__((ext_vector_type(4)));
typedef unsigned short u16x4 __attribute__((ext_vector_type(4)));
typedef unsigned short u16x8 __attribute__((ext_vector_type(8)));

#define DEV __device__ __forceinline__

DEV float b2f(unsigned short u) {
  union { unsigned int i; float f; } x; x.i = ((unsigned int)u) << 16; return x.f;
}
DEV unsigned short f2b(float f) {
  union { float f; unsigned int i; } x; x.f = f;
  return (unsigned short)((x.i + 0x7fffu + ((x.i >> 16) & 1u)) >> 16);
}

#define AS1(p) ((__attribute__((address_space(1))) void*)(p))
#define AS3(p) ((__attribute__((address_space(3))) void*)(p))

// ---------- tiny kernels ----------
__global__ void k_silu(const float* __restrict__ c, float* __restrict__ o) {
  int i = blockIdx.x * 256 + threadIdx.x;
  float v = c[i];
  o[i] = v / (1.f + __expf(-v));
}

// ada[b][j] = silu(cond[b]) . ada_w[j] + ada_b[j]   (wave per output)
__global__ __launch_bounds__(256) void k_ada(const float* __restrict__ sc,
                                             const float* __restrict__ w,
                                             const float* __restrict__ bias,
                                             float* __restrict__ out) {
  int idx = blockIdx.x * 4 + (threadIdx.x >> 6);
  int lane = threadIdx.x & 63;
  int b = idx / 6144;
  int j = idx - b * 6144;
  const float* wr = w + (size_t)j * 1024;
  const float* cr = sc + b * 1024;
  float s = 0.f;
#pragma unroll
  for (int u = 0; u < 4; ++u) {
    int k = u * 256 + lane * 4;
    float4 a = *(const float4*)(wr + k);
    float4 cc = *(const float4*)(cr + k);
    s += a.x * cc.x + a.y * cc.y + a.z * cc.z + a.w * cc.w;
  }
#pragma unroll
  for (int o = 1; o < 64; o <<= 1) s += __shfl_xor(s, o);
  if (lane == 0) out[idx] = s + bias[j];
}

__global__ void k_cast(const float* __restrict__ s, unsigned short* __restrict__ d, int n) {
  int i = (blockIdx.x * 256 + threadIdx.x) * 4;
  if (i >= n) return;
  float4 v = *(const float4*)(s + i);
  u16x4 o;
  o[0] = f2b(v.x); o[1] = f2b(v.y); o[2] = f2b(v.z); o[3] = f2b(v.w);
  *(u16x4*)(d + i) = o;
}

// LayerNorm (affine-free) + AdaLN modulate -> bf16
__global__ __launch_bounds__(256) void k_ln_mod(const float* __restrict__ src,
                                                const float* __restrict__ ada,
                                                unsigned short* __restrict__ dst,
                                                int sidx, int hidx) {
  int row = blockIdx.x;
  int b = row >> 10;
  int t = threadIdx.x, lane = t & 63, wv = t >> 6;
  float4 v = *(const float4*)(src + (size_t)row * 1024 + t * 4);
  float s = v.x + v.y + v.z + v.w;
  float s2 = v.x * v.x + v.y * v.y + v.z * v.z + v.w * v.w;
#pragma unroll
  for (int o = 1; o < 64; o <<= 1) { s += __shfl_xor(s, o); s2 += __shfl_xor(s2, o); }
  __shared__ float red[8];
  if (lane == 0) { red[wv] = s; red[4 + wv] = s2; }
  __syncthreads();
  float ts = red[0] + red[1] + red[2] + red[3];
  float ts2 = red[4] + red[5] + red[6] + red[7];
  float mu = ts * (1.f / 1024.f);
  float var = ts2 * (1.f / 1024.f) - mu * mu;
  float rstd = rsqrtf(var + 1e-6f);
  const float* ar = ada + (size_t)b * 6144;
  float4 sc = *(const float4*)(ar + sidx * 1024 + t * 4);
  float4 sh = *(const float4*)(ar + hidx * 1024 + t * 4);
  u16x4 o;
  o[0] = f2b((v.x - mu) * rstd * (sc.x + 1.f) + sh.x);
  o[1] = f2b((v.y - mu) * rstd * (sc.y + 1.f) + sh.y);
  o[2] = f2b((v.z - mu) * rstd * (sc.z + 1.f) + sh.z);
  o[3] = f2b((v.w - mu) * rstd * (sc.w + 1.f) + sh.w);
  *(u16x4*)(dst + (size_t)row * 1024 + t * 4) = o;
}

// ---------- bf16 GEMM: C = A[M,K] * W[N,K]^T, 128x128 tile, m97 structure ----------
// EPI: 0=qkv(+concat bias, bf16 out) 1=proj(+b,*g1,+x, f32) 2=fc1(gelu, bf16) 3=fc2(+b,*g2,+xmid, f32)
template <int EPI>
__global__ __launch_bounds__(256) void k_gemm(const unsigned short* __restrict__ A,
                                              const unsigned short* __restrict__ W,
                                              int M, int N, int K,
                                              const float* __restrict__ bias,
                                              const float* __restrict__ qb,
                                              const float* __restrict__ vb,
                                              const float* __restrict__ resid,
                                              const float* __restrict__ ada,
                                              void* __restrict__ outp) {
  __shared__ unsigned short As[128 * 32];
  __shared__ unsigned short Bs[128 * 32];
  const int t = threadIdx.x, lane = t & 63, wv = t >> 6;
  const int wr = wv >> 1, wc = wv & 1;
  const int m0 = blockIdx.y * 128, n0 = blockIdx.x * 128;

  f32x4 zz = {0.f, 0.f, 0.f, 0.f};
  f32x4 acc[4][4];
#pragma unroll
  for (int i = 0; i < 4; ++i)
#pragma unroll
    for (int j = 0; j < 4; ++j) acc[i][j] = zz;

  const int srow = lane >> 2, scol = (lane & 3) * 8;
  const unsigned short* aSrc0 = A + (size_t)(m0 + wv * 16 + srow) * K + scol;
  const unsigned short* aSrc1 = aSrc0 + (size_t)64 * K;
  const unsigned short* bSrc0 = W + (size_t)(n0 + wv * 16 + srow) * K + scol;
  const unsigned short* bSrc1 = bSrc0 + (size_t)64 * K;
  unsigned short* aDst0 = As + wv * 512;
  unsigned short* aDst1 = As + 2048 + wv * 512;
  unsigned short* bDst0 = Bs + wv * 512;
  unsigned short* bDst1 = Bs + 2048 + wv * 512;

  const int fr = lane & 15, fk = (lane >> 4) * 8;
  const unsigned short* aRd = As + (wr * 64 + fr) * 32 + fk;
  const unsigned short* bRd = Bs + (wc * 64 + fr) * 32 + fk;

  for (int k0 = 0; k0 < K; k0 += 32) {
    __builtin_amdgcn_global_load_lds(AS1(aSrc0 + k0), AS3(aDst0), 16, 0, 0);
    __builtin_amdgcn_global_load_lds(AS1(aSrc1 + k0), AS3(aDst1), 16, 0, 0);
    __builtin_amdgcn_global_load_lds(AS1(bSrc0 + k0), AS3(bDst0), 16, 0, 0);
    __builtin_amdgcn_global_load_lds(AS1(bSrc1 + k0), AS3(bDst1), 16, 0, 0);
    __syncthreads();
    bf16x8 af[4], bfv[4];
#pragma unroll
    for (int i = 0; i < 4; ++i) af[i] = *(const bf16x8*)(aRd + i * 512);
#pragma unroll
    for (int i = 0; i < 4; ++i) bfv[i] = *(const bf16x8*)(bRd + i * 512);
#pragma unroll
    for (int mi = 0; mi < 4; ++mi)
#pragma unroll
      for (int ni = 0; ni < 4; ++ni)
        acc[mi][ni] = __builtin_amdgcn_mfma_f32_16x16x32_bf16(af[mi], bfv[ni], acc[mi][ni], 0, 0, 0);
    __syncthreads();
  }

  const int fg = lane >> 4;
#pragma unroll
  for (int mi = 0; mi < 4; ++mi) {
#pragma unroll
    for (int ni = 0; ni < 4; ++ni) {
#pragma unroll
      for (int r = 0; r < 4; ++r) {
        int m = m0 + wr * 64 + mi * 16 + fg * 4 + r;
        int n = n0 + wc * 64 + ni * 16 + fr;
        float v = acc[mi][ni][r];
        if constexpr (EPI == 0) {
          float bb = (n < 1024) ? qb[n] : ((n < 2048) ? 0.f : vb[n - 2048]);
          ((unsigned short*)outp)[(size_t)m * N + n] = f2b(v + bb);
        } else if constexpr (EPI == 1) {
          float g = ada[(size_t)(m >> 10) * 6144 + n];
          ((float*)outp)[(size_t)m * N + n] = resid[(size_t)m * N + n] + (v + bias[n]) * g;
        } else if constexpr (EPI == 2) {
          float z = v + bias[n];
          ((unsigned short*)outp)[(size_t)m * N + n] =
              f2b(0.5f * z * (1.f + erff(z * 0.70710678118654752f)));
        } else {
          float g = ada[(size_t)(m >> 10) * 6144 + 1024 + n];
          ((float*)outp)[(size_t)m * N + n] = resid[(size_t)m * N + n] + (v + bias[n]) * g;
        }
      }
    }
  }
}

// ---------- q/k l2norm (+sm scale on q) into per-head layout ----------
__global__ __launch_bounds__(256) void k_qknorm(const unsigned short* __restrict__ qkv,
                                                const float* __restrict__ smul,
                                                unsigned short* __restrict__ Qn,
                                                unsigned short* __restrict__ Kn) {
  int row = blockIdx.x;  // b*1024 + l
  int b = row >> 10, l = row & 1023;
  int t = threadIdx.x;
  int h = t >> 4, sl = t & 15;
  const unsigned short* base = qkv + (size_t)row * 3072 + h * 64 + sl * 4;
  size_t off = ((size_t)(b * 16 + h) * 1024 + l) * 64 + sl * 4;
  // Q
  {
    u16x4 qv = *(const u16x4*)base;
    float q0 = b2f(qv[0]), q1 = b2f(qv[1]), q2 = b2f(qv[2]), q3 = b2f(qv[3]);
    float ss = q0 * q0 + q1 * q1 + q2 * q2 + q3 * q3;
#pragma unroll
    for (int o = 1; o < 16; o <<= 1) ss += __shfl_xor(ss, o);
    float sm = __expf(fminf(smul[h], 4.6051701859880914f));
    float qs = sm / fmaxf(sqrtf(ss), 1e-12f);
    u16x4 o; o[0] = f2b(q0 * qs); o[1] = f2b(q1 * qs); o[2] = f2b(q2 * qs); o[3] = f2b(q3 * qs);
    *(u16x4*)(Qn + off) = o;
  }
  // K
  {
    u16x4 kv = *(const u16x4*)(base + 1024);
    float k0 = b2f(kv[0]), k1 = b2f(kv[1]), k2 = b2f(kv[2]), k3 = b2f(kv[3]);
    float ss = k0 * k0 + k1 * k1 + k2 * k2 + k3 * k3;
#pragma unroll
    for (int o = 1; o < 16; o <<= 1) ss += __shfl_xor(ss, o);
    float ks = 1.f / fmaxf(sqrtf(ss), 1e-12f);
    u16x4 o; o[0] = f2b(k0 * ks); o[1] = f2b(k1 * ks); o[2] = f2b(k2 * ks); o[3] = f2b(k3 * ks);
    *(u16x4*)(Kn + off) = o;
  }
}

// ---------- V transpose: Vt[bh][d][l] ----------
__global__ __launch_bounds__(256) void k_vtrans(const unsigned short* __restrict__ qkv,
                                                unsigned short* __restrict__ Vt) {
  int bh = blockIdx.y, b = bh >> 4, h = bh & 15;
  int l0 = blockIdx.x * 64;
  __shared__ unsigned short tile[64][72];
  int t = threadIdx.x;
  int lr = t >> 2, dp = (t & 3) * 16;
  const unsigned short* src = qkv + (size_t)(b * 1024 + l0 + lr) * 3072 + 2048 + h * 64 + dp;
  *(u16x8*)&tile[lr][dp] = *(const u16x8*)src;
  *(u16x8*)&tile[lr][dp + 8] = *(const u16x8*)(src + 8);
  __syncthreads();
  int d = t >> 2, lp = (t & 3) * 16;
  unsigned short ov[16];
#pragma unroll
  for (int j = 0; j < 16; ++j) ov[j] = tile[lp + j][d];
  unsigned short* dst = Vt + ((size_t)bh * 64 + d) * 1024 + l0 + lp;
  *(u16x8*)dst = *(u16x8*)&ov[0];
  *(u16x8*)(dst + 8) = *(u16x8*)&ov[8];
}

// ---------- flash attention: 4 waves x 16 q-rows, KV tile 32, K/V straight from L2 ----------
__global__ __launch_bounds__(256) void k_attn(const unsigned short* __restrict__ Qn,
                                              const unsigned short* __restrict__ Kn,
                                              const unsigned short* __restrict__ Vt,
                                              unsigned short* __restrict__ O) {
  const int qt = blockIdx.x, bh = blockIdx.y;
  const int b = bh >> 4, h = bh & 15;
  const int t = threadIdx.x, lane = t & 63, wv = t >> 6;
  const int fr = lane & 15, fg = lane >> 4;
  __shared__ unsigned short plds[4][512];

  const int q0 = qt * 64 + wv * 16;
  const unsigned short* qb = Qn + ((size_t)bh * 1024 + q0 + fr) * 64 + fg * 8;
  bf16x8 qf0 = *(const bf16x8*)qb;
  bf16x8 qf1 = *(const bf16x8*)(qb + 32);

  f32x4 zz = {0.f, 0.f, 0.f, 0.f};
  f32x4 oacc[4];
#pragma unroll
  for (int i = 0; i < 4; ++i) oacc[i] = zz;
  float mrun[4], lrun[4];
#pragma unroll
  for (int r = 0; r < 4; ++r) { mrun[r] = -1e30f; lrun[r] = 0.f; }

  const unsigned short* kbase = Kn + (size_t)bh * 65536;
  const unsigned short* vbase = Vt + (size_t)bh * 65536;

  for (int kv = 0; kv < 1024; kv += 32) {
    f32x4 s[2];
#pragma unroll
    for (int ct = 0; ct < 2; ++ct) {
      const unsigned short* kp = kbase + (size_t)(kv + ct * 16 + fr) * 64 + fg * 8;
      bf16x8 kf0 = *(const bf16x8*)kp;
      bf16x8 kf1 = *(const bf16x8*)(kp + 32);
      f32x4 z = zz;
      z = __builtin_amdgcn_mfma_f32_16x16x32_bf16(qf0, kf0, z, 0, 0, 0);
      z = __builtin_amdgcn_mfma_f32_16x16x32_bf16(qf1, kf1, z, 0, 0, 0);
      s[ct] = z;
    }
    float scl[4];
#pragma unroll
    for (int r = 0; r < 4; ++r) {
      float mx = fmaxf(s[0][r], s[1][r]);
      mx = fmaxf(mx, __shfl_xor(mx, 1));
      mx = fmaxf(mx, __shfl_xor(mx, 2));
      mx = fmaxf(mx, __shfl_xor(mx, 4));
      mx = fmaxf(mx, __shfl_xor(mx, 8));
      float mnew = fmaxf(mrun[r], mx);
      float e0 = __expf(s[0][r] - mnew);
      float e1 = __expf(s[1][r] - mnew);
      plds[wv][(fg * 4 + r) * 32 + fr] = f2b(e0);
      plds[wv][(fg * 4 + r) * 32 + 16 + fr] = f2b(e1);
      float rs = e0 + e1;
      rs += __shfl_xor(rs, 1); rs += __shfl_xor(rs, 2);
      rs += __shfl_xor(rs, 4); rs += __shfl_xor(rs, 8);
      float sc = __expf(mrun[r] - mnew);
      lrun[r] = lrun[r] * sc + rs;
      mrun[r] = mnew;
      scl[r] = sc;
    }
#pragma unroll
    for (int dt = 0; dt < 4; ++dt)
#pragma unroll
      for (int r = 0; r < 4; ++r) oacc[dt][r] *= scl[r];
    asm volatile("s_waitcnt lgkmcnt(0)" ::: "memory");
    bf16x8 pf = *(const bf16x8*)&plds[wv][fr * 32 + fg * 8];
#pragma unroll
    for (int dt = 0; dt < 4; ++dt) {
      const unsigned short* vp = vbase + (size_t)(dt * 16 + fr) * 1024 + kv + fg * 8;
      bf16x8 vf = *(const bf16x8*)vp;
      oacc[dt] = __builtin_amdgcn_mfma_f32_16x16x32_bf16(pf, vf, oacc[dt], 0, 0, 0);
    }
  }
#pragma unroll
  for (int r = 0; r < 4; ++r) lrun[r] = 1.f / lrun[r];
  unsigned short* ob = O + ((size_t)(b * 1024 + q0 + fg * 4)) * 1024 + h * 64 + fr;
#pragma unroll
  for (int dt = 0; dt < 4; ++dt)
#pragma unroll
    for (int r = 0; r < 4; ++r)
      ob[(size_t)r * 1024 + dt * 16] = f2b(oacc[dt][r] * lrun[r]);
}

// ---------- launch ----------
extern "C" void kernel_launch(void* const* d_in, const int* in_sizes, int n_in,
                              void* d_out, int out_size, void* d_ws, size_t ws_size,
                              hipStream_t stream) {
  const float* x        = (const float*)d_in[0];
  const float* cond     = (const float*)d_in[1];
  const float* qkv_w    = (const float*)d_in[2];
  const float* q_bias   = (const float*)d_in[3];
  const float* v_bias   = (const float*)d_in[4];
  const float* scale_mul= (const float*)d_in[5];
  const float* proj_w   = (const float*)d_in[6];
  const float* proj_b   = (const float*)d_in[7];
  const float* ada_w    = (const float*)d_in[8];
  const float* ada_b    = (const float*)d_in[9];
  const float* fc1_w    = (const float*)d_in[10];
  const float* fc1_b    = (const float*)d_in[11];
  const float* fc2_w    = (const float*)d_in[12];
  const float* fc2_b    = (const float*)d_in[13];
  float* out = (float*)d_out;
  char* ws = (char*)d_ws;

  unsigned short* WQ   = (unsigned short*)(ws + 0);          // 6291456
  unsigned short* WP   = (unsigned short*)(ws + 6291456);    // 2097152
  unsigned short* WF1  = (unsigned short*)(ws + 8388608);    // 8388608
  unsigned short* WF2  = (unsigned short*)(ws + 16777216);   // 8388608
  float*          SIL  = (float*)(ws + 25165824);            // 16384
  float*          ADA  = (float*)(ws + 25182208);            // 98304
  unsigned short* X1   = (unsigned short*)(ws + 25280512);   // 8388608 (reused for x2)
  unsigned short* QKVB = (unsigned short*)(ws + 33669120);   // 25165824 (dead after norm/vtrans)
  unsigned short* QN   = (unsigned short*)(ws + 58834944);   // 8388608
  unsigned short* KN   = (unsigned short*)(ws + 67223552);   // 8388608
  unsigned short* VT   = (unsigned short*)(ws + 75612160);   // 8388608
  unsigned short* OB   = (unsigned short*)(ws + 84000768);   // 8388608  -> ws top 92389376
  float*          XMID = (float*)(ws + 33669120);            // 16777216 (reuses dead QKVB)
  unsigned short* HB   = (unsigned short*)(ws + 50446336);   // 33554432 (reuses dead QKVB/QN/KN/VT)

  (void)in_sizes; (void)n_in; (void)out_size; (void)ws_size;

  k_silu<<<16, 256, 0, stream>>>(cond, SIL);
  k_ada<<<6144, 256, 0, stream>>>(SIL, ada_w, ada_b, ADA);
  k_cast<<<3072, 256, 0, stream>>>(qkv_w, WQ, 3145728);
  k_cast<<<1024, 256, 0, stream>>>(proj_w, WP, 1048576);
  k_cast<<<4096, 256, 0, stream>>>(fc1_w, WF1, 4194304);
  k_cast<<<4096, 256, 0, stream>>>(fc2_w, WF2, 4194304);

  k_ln_mod<<<4096, 256, 0, stream>>>(x, ADA, X1, 2, 4);
  k_gemm<0><<<dim3(24, 32), 256, 0, stream>>>(X1, WQ, 4096, 3072, 1024,
                                              nullptr, q_bias, v_bias, nullptr, nullptr, QKVB);
  k_qknorm<<<4096, 256, 0, stream>>>(QKVB, scale_mul, QN, KN);
  k_vtrans<<<dim3(16, 64), 256, 0, stream>>>(QKVB, VT);
  k_attn<<<dim3(16, 64), 256, 0, stream>>>(QN, KN, VT, OB);
  k_gemm<1><<<dim3(8, 32), 256, 0, stream>>>(OB, WP, 4096, 1024, 1024,
                                             proj_b, nullptr, nullptr, x, ADA, XMID);
  k_ln_mod<<<4096, 256, 0, stream>>>(XMID, ADA, X1, 3, 5);
  k_gemm<2><<<dim3(32, 32), 256, 0, stream>>>(X1, WF1, 4096, 4096, 1024,
                                              fc1_b, nullptr, nullptr, nullptr, nullptr, HB);
  k_gemm<3><<<dim3(8, 32), 256, 0, stream>>>(HB, WF2, 4096, 1024, 4096,
                                             fc2_b, nullptr, nullptr, XMID, ADA, out);
}

// Round 2
// 408.181 us; speedup vs baseline: 1.0103x; 1.0103x over previous
//
#include <hip/hip_runtime.h>

// ---------- types ----------
typedef __bf16 bf16x8_t __attribute__((ext_vector_type(8)));
typedef bf16x8_t bf16x8 __attribute__((may_alias));
typedef float f32x4 __attribute__((ext_vector_type(4)));
typedef unsigned short u16x4 __attribute__((ext_vector_type(4)));
typedef unsigned short u16x8 __attribute__((ext_vector_type(8)));

#define DEV __device__ __forceinline__

DEV float b2f(unsigned short u) {
  union { unsigned int i; float f; } x; x.i = ((unsigned int)u) << 16; return x.f;
}
DEV unsigned short f2b(float f) {
  union { float f; unsigned int i; } x; x.f = f;
  return (unsigned short)((x.i + 0x7fffu + ((x.i >> 16) & 1u)) >> 16);
}

#define AS1(p) ((__attribute__((address_space(1))) void*)(p))
#define AS3(p) ((__attribute__((address_space(3))) void*)(p))

// ---------- tiny kernels ----------
__global__ void k_silu(const float* __restrict__ c, float* __restrict__ o) {
  int i = blockIdx.x * 256 + threadIdx.x;
  float v = c[i];
  o[i] = v / (1.f + __expf(-v));
}

// wave per output column j; computes all 4 batches so ada_w is read ONCE.
__global__ __launch_bounds__(256) void k_ada(const float* __restrict__ sc,
                                             const float* __restrict__ w,
                                             const float* __restrict__ bias,
                                             float* __restrict__ out) {
  int j = blockIdx.x * 4 + (threadIdx.x >> 6);
  int lane = threadIdx.x & 63;
  const float* wr = w + (size_t)j * 1024;
  float s0 = 0.f, s1 = 0.f, s2 = 0.f, s3 = 0.f;
#pragma unroll
  for (int u = 0; u < 4; ++u) {
    int k = u * 256 + lane * 4;
    float4 a = *(const float4*)(wr + k);
    float4 c0 = *(const float4*)(sc + k);
    float4 c1 = *(const float4*)(sc + 1024 + k);
    float4 c2 = *(const float4*)(sc + 2048 + k);
    float4 c3 = *(const float4*)(sc + 3072 + k);
    s0 += a.x * c0.x + a.y * c0.y + a.z * c0.z + a.w * c0.w;
    s1 += a.x * c1.x + a.y * c1.y + a.z * c1.z + a.w * c1.w;
    s2 += a.x * c2.x + a.y * c2.y + a.z * c2.z + a.w * c2.w;
    s3 += a.x * c3.x + a.y * c3.y + a.z * c3.z + a.w * c3.w;
  }
#pragma unroll
  for (int o = 1; o < 64; o <<= 1) {
    s0 += __shfl_xor(s0, o); s1 += __shfl_xor(s1, o);
    s2 += __shfl_xor(s2, o); s3 += __shfl_xor(s3, o);
  }
  if (lane == 0) {
    float bb = bias[j];
    out[j] = s0 + bb;
    out[6144 + j] = s1 + bb;
    out[12288 + j] = s2 + bb;
    out[18432 + j] = s3 + bb;
  }
}

__global__ void k_cast(const float* __restrict__ s, unsigned short* __restrict__ d, int n) {
  int i = (blockIdx.x * 256 + threadIdx.x) * 4;
  if (i >= n) return;
  float4 v = *(const float4*)(s + i);
  u16x4 o;
  o[0] = f2b(v.x); o[1] = f2b(v.y); o[2] = f2b(v.z); o[3] = f2b(v.w);
  *(u16x4*)(d + i) = o;
}

// LayerNorm (affine-free) + AdaLN modulate -> bf16
__global__ __launch_bounds__(256) void k_ln_mod(const float* __restrict__ src,
                                                const float* __restrict__ ada,
                                                unsigned short* __restrict__ dst,
                                                int sidx, int hidx) {
  int row = blockIdx.x;
  int b = row >> 10;
  int t = threadIdx.x, lane = t & 63, wv = t >> 6;
  float4 v = *(const float4*)(src + (size_t)row * 1024 + t * 4);
  float s = v.x + v.y + v.z + v.w;
  float s2 = v.x * v.x + v.y * v.y + v.z * v.z + v.w * v.w;
#pragma unroll
  for (int o = 1; o < 64; o <<= 1) { s += __shfl_xor(s, o); s2 += __shfl_xor(s2, o); }
  __shared__ float red[8];
  if (lane == 0) { red[wv] = s; red[4 + wv] = s2; }
  __syncthreads();
  float ts = red[0] + red[1] + red[2] + red[3];
  float ts2 = red[4] + red[5] + red[6] + red[7];
  float mu = ts * (1.f / 1024.f);
  float var = ts2 * (1.f / 1024.f) - mu * mu;
  float rstd = rsqrtf(var + 1e-6f);
  const float* ar = ada + (size_t)b * 6144;
  float4 sc = *(const float4*)(ar + sidx * 1024 + t * 4);
  float4 sh = *(const float4*)(ar + hidx * 1024 + t * 4);
  u16x4 o;
  o[0] = f2b((v.x - mu) * rstd * (sc.x + 1.f) + sh.x);
  o[1] = f2b((v.y - mu) * rstd * (sc.y + 1.f) + sh.y);
  o[2] = f2b((v.z - mu) * rstd * (sc.z + 1.f) + sh.z);
  o[3] = f2b((v.w - mu) * rstd * (sc.w + 1.f) + sh.w);
  *(u16x4*)(dst + (size_t)row * 1024 + t * 4) = o;
}

// ---------- bf16 GEMM: C = A[M,K] * W[N,K]^T, 128x128 tile, m97 structure ----------
template <int EPI>
__global__ __launch_bounds__(256) void k_gemm(const unsigned short* __restrict__ A,
                                              const unsigned short* __restrict__ W,
                                              int M, int N, int K,
                                              const float* __restrict__ bias,
                                              const float* __restrict__ qb,
                                              const float* __restrict__ vb,
                                              const float* __restrict__ resid,
                                              const float* __restrict__ ada,
                                              void* __restrict__ outp) {
  __shared__ unsigned short As[128 * 32];
  __shared__ unsigned short Bs[128 * 32];
  const int t = threadIdx.x, lane = t & 63, wv = t >> 6;
  const int wr = wv >> 1, wc = wv & 1;
  const int m0 = blockIdx.y * 128, n0 = blockIdx.x * 128;

  f32x4 zz = {0.f, 0.f, 0.f, 0.f};
  f32x4 acc[4][4];
#pragma unroll
  for (int i = 0; i < 4; ++i)
#pragma unroll
    for (int j = 0; j < 4; ++j) acc[i][j] = zz;

  const int srow = lane >> 2, scol = (lane & 3) * 8;
  const unsigned short* aSrc0 = A + (size_t)(m0 + wv * 16 + srow) * K + scol;
  const unsigned short* aSrc1 = aSrc0 + (size_t)64 * K;
  const unsigned short* bSrc0 = W + (size_t)(n0 + wv * 16 + srow) * K + scol;
  const unsigned short* bSrc1 = bSrc0 + (size_t)64 * K;
  unsigned short* aDst0 = As + wv * 512;
  unsigned short* aDst1 = As + 2048 + wv * 512;
  unsigned short* bDst0 = Bs + wv * 512;
  unsigned short* bDst1 = Bs + 2048 + wv * 512;

  const int fr = lane & 15, fk = (lane >> 4) * 8;
  const unsigned short* aRd = As + (wr * 64 + fr) * 32 + fk;
  const unsigned short* bRd = Bs + (wc * 64 + fr) * 32 + fk;

  for (int k0 = 0; k0 < K; k0 += 32) {
    __builtin_amdgcn_global_load_lds(AS1(aSrc0 + k0), AS3(aDst0), 16, 0, 0);
    __builtin_amdgcn_global_load_lds(AS1(aSrc1 + k0), AS3(aDst1), 16, 0, 0);
    __builtin_amdgcn_global_load_lds(AS1(bSrc0 + k0), AS3(bDst0), 16, 0, 0);
    __builtin_amdgcn_global_load_lds(AS1(bSrc1 + k0), AS3(bDst1), 16, 0, 0);
    __syncthreads();
    bf16x8 af[4], bfv[4];
#pragma unroll
    for (int i = 0; i < 4; ++i) af[i] = *(const bf16x8*)(aRd + i * 512);
#pragma unroll
    for (int i = 0; i < 4; ++i) bfv[i] = *(const bf16x8*)(bRd + i * 512);
#pragma unroll
    for (int mi = 0; mi < 4; ++mi)
#pragma unroll
      for (int ni = 0; ni < 4; ++ni)
        acc[mi][ni] = __builtin_amdgcn_mfma_f32_16x16x32_bf16(af[mi], bfv[ni], acc[mi][ni], 0, 0, 0);
    __syncthreads();
  }

  const int fg = lane >> 4;
#pragma unroll
  for (int mi = 0; mi < 4; ++mi) {
#pragma unroll
    for (int ni = 0; ni < 4; ++ni) {
#pragma unroll
      for (int r = 0; r < 4; ++r) {
        int m = m0 + wr * 64 + mi * 16 + fg * 4 + r;
        int n = n0 + wc * 64 + ni * 16 + fr;
        float v = acc[mi][ni][r];
        if constexpr (EPI == 0) {
          float bb = (n < 1024) ? qb[n] : ((n < 2048) ? 0.f : vb[n - 2048]);
          ((unsigned short*)outp)[(size_t)m * N + n] = f2b(v + bb);
        } else if constexpr (EPI == 1) {
          float g = ada[(size_t)(m >> 10) * 6144 + n];
          ((float*)outp)[(size_t)m * N + n] = resid[(size_t)m * N + n] + (v + bias[n]) * g;
        } else if constexpr (EPI == 2) {
          float z = v + bias[n];
          ((unsigned short*)outp)[(size_t)m * N + n] =
              f2b(0.5f * z * (1.f + erff(z * 0.70710678118654752f)));
        } else {
          float g = ada[(size_t)(m >> 10) * 6144 + 1024 + n];
          ((float*)outp)[(size_t)m * N + n] = resid[(size_t)m * N + n] + (v + bias[n]) * g;
        }
      }
    }
  }
}

// ---------- q/k l2norm (+sm scale on q) into per-head layout ----------
__global__ __launch_bounds__(256) void k_qknorm(const unsigned short* __restrict__ qkv,
                                                const float* __restrict__ smul,
                                                unsigned short* __restrict__ Qn,
                                                unsigned short* __restrict__ Kn) {
  int row = blockIdx.x;  // b*1024 + l
  int b = row >> 10, l = row & 1023;
  int t = threadIdx.x;
  int h = t >> 4, sl = t & 15;
  const unsigned short* base = qkv + (size_t)row * 3072 + h * 64 + sl * 4;
  size_t off = ((size_t)(b * 16 + h) * 1024 + l) * 64 + sl * 4;
  {
    u16x4 qv = *(const u16x4*)base;
    float q0 = b2f(qv[0]), q1 = b2f(qv[1]), q2 = b2f(qv[2]), q3 = b2f(qv[3]);
    float ss = q0 * q0 + q1 * q1 + q2 * q2 + q3 * q3;
#pragma unroll
    for (int o = 1; o < 16; o <<= 1) ss += __shfl_xor(ss, o);
    float sm = __expf(fminf(smul[h], 4.6051701859880914f));
    float qs = sm / fmaxf(sqrtf(ss), 1e-12f);
    u16x4 o; o[0] = f2b(q0 * qs); o[1] = f2b(q1 * qs); o[2] = f2b(q2 * qs); o[3] = f2b(q3 * qs);
    *(u16x4*)(Qn + off) = o;
  }
  {
    u16x4 kv = *(const u16x4*)(base + 1024);
    float k0 = b2f(kv[0]), k1 = b2f(kv[1]), k2 = b2f(kv[2]), k3 = b2f(kv[3]);
    float ss = k0 * k0 + k1 * k1 + k2 * k2 + k3 * k3;
#pragma unroll
    for (int o = 1; o < 16; o <<= 1) ss += __shfl_xor(ss, o);
    float ks = 1.f / fmaxf(sqrtf(ss), 1e-12f);
    u16x4 o; o[0] = f2b(k0 * ks); o[1] = f2b(k1 * ks); o[2] = f2b(k2 * ks); o[3] = f2b(k3 * ks);
    *(u16x4*)(Kn + off) = o;
  }
}

// ---------- V transpose with k-interleave permutation ----------
// Physical position p within each 32-block holds logical k = (p&1)*16 + (p>>1),
// matching the u32-paired P layout consumed by the PV MFMA B-fragment.
__global__ __launch_bounds__(256) void k_vtrans(const unsigned short* __restrict__ qkv,
                                                unsigned short* __restrict__ Vt) {
  int bh = blockIdx.y, b = bh >> 4, h = bh & 15;
  int l0 = blockIdx.x * 64;
  __shared__ unsigned short tile[64][72];
  int t = threadIdx.x;
  int lr = t >> 2, dp = (t & 3) * 16;
  const unsigned short* src = qkv + (size_t)(b * 1024 + l0 + lr) * 3072 + 2048 + h * 64 + dp;
  *(u16x8*)&tile[lr][dp] = *(const u16x8*)src;
  *(u16x8*)&tile[lr][dp + 8] = *(const u16x8*)(src + 8);
  __syncthreads();
  int d = t >> 2, lp = (t & 3) * 16;
  unsigned short ov[16];
#pragma unroll
  for (int j = 0; j < 16; ++j) {
    int p = lp + j;
    int q = p & 31;
    int l = (p & 32) + ((q & 1) << 4) + (q >> 1);
    ov[j] = tile[l][d];
  }
  unsigned short* dst = Vt + ((size_t)bh * 64 + d) * 1024 + l0 + lp;
  *(u16x8*)dst = *(u16x8*)&ov[0];
  *(u16x8*)(dst + 8) = *(u16x8*)&ov[8];
}

// ---------- flash attention, static-max softmax ----------
// Scores bounded: |s| <= sm_h (l2-normed q scaled by sm, l2-normed k). So
// p = exp(s - sm_h) needs NO online max, NO rescale, NO per-tile reductions.
// P packed to bf16 u32-pairs (cols k, k+16) via v_perm; V^T pre-permuted to match.
// P LDS row stride 144B: 16B-aligned reads, stores spread over 32 banks (2/bank).
__global__ __launch_bounds__(256) void k_attn(const unsigned short* __restrict__ Qn,
                                              const unsigned short* __restrict__ Kn,
                                              const unsigned short* __restrict__ Vt,
                                              const float* __restrict__ smul,
                                              unsigned short* __restrict__ O) {
  const int qt = blockIdx.x, bh = blockIdx.y;
  const int b = bh >> 4, h = bh & 15;
  const int t = threadIdx.x, lane = t & 63, wv = t >> 6;
  const int fr = lane & 15, fg = lane >> 4;
  __shared__ unsigned int plds[4][16 * 36];
  unsigned int* pst = &plds[wv][0];

  const int q0 = qt * 64 + wv * 16;
  const unsigned short* qp = Qn + ((size_t)bh * 1024 + q0 + fr) * 64 + fg * 8;
  bf16x8 qf0 = *(const bf16x8*)qp;
  bf16x8 qf1 = *(const bf16x8*)(qp + 32);

  const float M = __expf(fminf(smul[h], 4.6051701859880914f));

  f32x4 zz = {0.f, 0.f, 0.f, 0.f};
  f32x4 oacc[4];
#pragma unroll
  for (int i = 0; i < 4; ++i) oacc[i] = zz;
  float lsum[4] = {0.f, 0.f, 0.f, 0.f};

  const unsigned short* kbase = Kn + (size_t)bh * 65536;
  const unsigned short* vbase = Vt + (size_t)bh * 65536;

  for (int kv = 0; kv < 1024; kv += 64) {
    f32x4 s[4];
#pragma unroll
    for (int ct = 0; ct < 4; ++ct) {
      const unsigned short* kp = kbase + (size_t)(kv + ct * 16 + fr) * 64 + fg * 8;
      bf16x8 kf0 = *(const bf16x8*)kp;
      bf16x8 kf1 = *(const bf16x8*)(kp + 32);
      f32x4 z = zz;
      z = __builtin_amdgcn_mfma_f32_16x16x32_bf16(qf0, kf0, z, 0, 0, 0);
      z = __builtin_amdgcn_mfma_f32_16x16x32_bf16(qf1, kf1, z, 0, 0, 0);
      s[ct] = z;
    }
#pragma unroll
    for (int r = 0; r < 4; ++r) {
      float p0 = __expf(s[0][r] - M);
      float p1 = __expf(s[1][r] - M);
      float p2 = __expf(s[2][r] - M);
      float p3 = __expf(s[3][r] - M);
      lsum[r] += (p0 + p1) + (p2 + p3);
      // round-half-up to bf16 then pack (hi=p_{k+16}, lo=p_k) in one v_perm
      unsigned int b0 = __float_as_uint(p0) + 0x8000u;
      unsigned int b1 = __float_as_uint(p1) + 0x8000u;
      unsigned int b2 = __float_as_uint(p2) + 0x8000u;
      unsigned int b3 = __float_as_uint(p3) + 0x8000u;
      unsigned int lo01 = __builtin_amdgcn_perm(b1, b0, 0x07060302u);
      unsigned int hi23 = __builtin_amdgcn_perm(b3, b2, 0x07060302u);
      int row = fg * 4 + r;
      pst[row * 36 + fr] = lo01;
      pst[row * 36 + 16 + fr] = hi23;
    }
#pragma unroll
    for (int kg = 0; kg < 2; ++kg) {
      bf16x8 pf = *(const bf16x8*)((const unsigned short*)pst + fr * 72 + kg * 32 + fg * 8);
#pragma unroll
      for (int dt = 0; dt < 4; ++dt) {
        const unsigned short* vp = vbase + (size_t)(dt * 16 + fr) * 1024 + kv + kg * 32 + fg * 8;
        bf16x8 vf = *(const bf16x8*)vp;
        oacc[dt] = __builtin_amdgcn_mfma_f32_16x16x32_bf16(pf, vf, oacc[dt], 0, 0, 0);
      }
    }
  }

  float inv[4];
#pragma unroll
  for (int r = 0; r < 4; ++r) {
    float ls = lsum[r];
    ls += __shfl_xor(ls, 1); ls += __shfl_xor(ls, 2);
    ls += __shfl_xor(ls, 4); ls += __shfl_xor(ls, 8);
    inv[r] = 1.f / ls;
  }
  unsigned short* ob = O + ((size_t)(b * 1024 + q0 + fg * 4)) * 1024 + h * 64 + fr;
#pragma unroll
  for (int dt = 0; dt < 4; ++dt)
#pragma unroll
    for (int r = 0; r < 4; ++r)
      ob[(size_t)r * 1024 + dt * 16] = f2b(oacc[dt][r] * inv[r]);
}

// ---------- launch ----------
extern "C" void kernel_launch(void* const* d_in, const int* in_sizes, int n_in,
                              void* d_out, int out_size, void* d_ws, size_t ws_size,
                              hipStream_t stream) {
  const float* x        = (const float*)d_in[0];
  const float* cond     = (const float*)d_in[1];
  const float* qkv_w    = (const float*)d_in[2];
  const float* q_bias   = (const float*)d_in[3];
  const float* v_bias   = (const float*)d_in[4];
  const float* scale_mul= (const float*)d_in[5];
  const float* proj_w   = (const float*)d_in[6];
  const float* proj_b   = (const float*)d_in[7];
  const float* ada_w    = (const float*)d_in[8];
  const float* ada_b    = (const float*)d_in[9];
  const float* fc1_w    = (const float*)d_in[10];
  const float* fc1_b    = (const float*)d_in[11];
  const float* fc2_w    = (const float*)d_in[12];
  const float* fc2_b    = (const float*)d_in[13];
  float* out = (float*)d_out;
  char* ws = (char*)d_ws;

  unsigned short* WQ   = (unsigned short*)(ws + 0);          // 6291456
  unsigned short* WP   = (unsigned short*)(ws + 6291456);    // 2097152
  unsigned short* WF1  = (unsigned short*)(ws + 8388608);    // 8388608
  unsigned short* WF2  = (unsigned short*)(ws + 16777216);   // 8388608
  float*          SIL  = (float*)(ws + 25165824);            // 16384
  float*          ADA  = (float*)(ws + 25182208);            // 98304
  unsigned short* X1   = (unsigned short*)(ws + 25280512);   // 8388608 (reused for x2)
  unsigned short* QKVB = (unsigned short*)(ws + 33669120);   // 25165824 (dead after norm/vtrans)
  unsigned short* QN   = (unsigned short*)(ws + 58834944);   // 8388608
  unsigned short* KN   = (unsigned short*)(ws + 67223552);   // 8388608
  unsigned short* VT   = (unsigned short*)(ws + 75612160);   // 8388608
  unsigned short* OB   = (unsigned short*)(ws + 84000768);   // 8388608  -> ws top 92389376
  float*          XMID = (float*)(ws + 33669120);            // 16777216 (reuses dead QKVB)
  unsigned short* HB   = (unsigned short*)(ws + 50446336);   // 33554432 (reuses dead QKVB/QN/KN/VT)

  (void)in_sizes; (void)n_in; (void)out_size; (void)ws_size;

  k_silu<<<16, 256, 0, stream>>>(cond, SIL);
  k_ada<<<1536, 256, 0, stream>>>(SIL, ada_w, ada_b, ADA);
  k_cast<<<3072, 256, 0, stream>>>(qkv_w, WQ, 3145728);
  k_cast<<<1024, 256, 0, stream>>>(proj_w, WP, 1048576);
  k_cast<<<4096, 256, 0, stream>>>(fc1_w, WF1, 4194304);
  k_cast<<<4096, 256, 0, stream>>>(fc2_w, WF2, 4194304);

  k_ln_mod<<<4096, 256, 0, stream>>>(x, ADA, X1, 2, 4);
  k_gemm<0><<<dim3(24, 32), 256, 0, stream>>>(X1, WQ, 4096, 3072, 1024,
                                              nullptr, q_bias, v_bias, nullptr, nullptr, QKVB);
  k_qknorm<<<4096, 256, 0, stream>>>(QKVB, scale_mul, QN, KN);
  k_vtrans<<<dim3(16, 64), 256, 0, stream>>>(QKVB, VT);
  k_attn<<<dim3(16, 64), 256, 0, stream>>>(QN, KN, VT, scale_mul, OB);
  k_gemm<1><<<dim3(8, 32), 256, 0, stream>>>(OB, WP, 4096, 1024, 1024,
                                             proj_b, nullptr, nullptr, x, ADA, XMID);
  k_ln_mod<<<4096, 256, 0, stream>>>(XMID, ADA, X1, 3, 5);
  k_gemm<2><<<dim3(32, 32), 256, 0, stream>>>(X1, WF1, 4096, 4096, 1024,
                                              fc1_b, nullptr, nullptr, nullptr, nullptr, HB);
  k_gemm<3><<<dim3(8, 32), 256, 0, stream>>>(HB, WF2, 4096, 1024, 4096,
                                             fc2_b, nullptr, nullptr, XMID, ADA, out);
}

// Round 3
// 322.106 us; speedup vs baseline: 1.2803x; 1.2672x over previous
//
#include <hip/hip_runtime.h>

// ---------- types ----------
typedef __bf16 bf16x8_t __attribute__((ext_vector_type(8)));
typedef bf16x8_t bf16x8 __attribute__((may_alias));
typedef float f32x4 __attribute__((ext_vector_type(4)));
typedef unsigned short u16x4 __attribute__((ext_vector_type(4)));
typedef unsigned short u16x8 __attribute__((ext_vector_type(8)));

#define DEV __device__ __forceinline__

DEV float b2f(unsigned short u) {
  union { unsigned int i; float f; } x; x.i = ((unsigned int)u) << 16; return x.f;
}
DEV unsigned short f2b(float f) {
  union { float f; unsigned int i; } x; x.f = f;
  return (unsigned short)((x.i + 0x7fffu + ((x.i >> 16) & 1u)) >> 16);
}

#define AS1(p) ((__attribute__((address_space(1))) void*)(p))
#define AS3(p) ((__attribute__((address_space(3))) void*)(p))

// ---------- tiny kernels ----------
__global__ void k_silu(const float* __restrict__ c, float* __restrict__ o) {
  int i = blockIdx.x * 256 + threadIdx.x;
  float v = c[i];
  o[i] = v / (1.f + __expf(-v));
}

// wave per output column j; computes all 4 batches so ada_w is read ONCE.
__global__ __launch_bounds__(256) void k_ada(const float* __restrict__ sc,
                                             const float* __restrict__ w,
                                             const float* __restrict__ bias,
                                             float* __restrict__ out) {
  int j = blockIdx.x * 4 + (threadIdx.x >> 6);
  int lane = threadIdx.x & 63;
  const float* wr = w + (size_t)j * 1024;
  float s0 = 0.f, s1 = 0.f, s2 = 0.f, s3 = 0.f;
#pragma unroll
  for (int u = 0; u < 4; ++u) {
    int k = u * 256 + lane * 4;
    float4 a = *(const float4*)(wr + k);
    float4 c0 = *(const float4*)(sc + k);
    float4 c1 = *(const float4*)(sc + 1024 + k);
    float4 c2 = *(const float4*)(sc + 2048 + k);
    float4 c3 = *(const float4*)(sc + 3072 + k);
    s0 += a.x * c0.x + a.y * c0.y + a.z * c0.z + a.w * c0.w;
    s1 += a.x * c1.x + a.y * c1.y + a.z * c1.z + a.w * c1.w;
    s2 += a.x * c2.x + a.y * c2.y + a.z * c2.z + a.w * c2.w;
    s3 += a.x * c3.x + a.y * c3.y + a.z * c3.z + a.w * c3.w;
  }
#pragma unroll
  for (int o = 1; o < 64; o <<= 1) {
    s0 += __shfl_xor(s0, o); s1 += __shfl_xor(s1, o);
    s2 += __shfl_xor(s2, o); s3 += __shfl_xor(s3, o);
  }
  if (lane == 0) {
    float bb = bias[j];
    out[j] = s0 + bb;
    out[6144 + j] = s1 + bb;
    out[12288 + j] = s2 + bb;
    out[18432 + j] = s3 + bb;
  }
}

__global__ void k_cast(const float* __restrict__ s, unsigned short* __restrict__ d, int n) {
  int i = (blockIdx.x * 256 + threadIdx.x) * 4;
  if (i >= n) return;
  float4 v = *(const float4*)(s + i);
  u16x4 o;
  o[0] = f2b(v.x); o[1] = f2b(v.y); o[2] = f2b(v.z); o[3] = f2b(v.w);
  *(u16x4*)(d + i) = o;
}

// LayerNorm (affine-free) + AdaLN modulate -> bf16
__global__ __launch_bounds__(256) void k_ln_mod(const float* __restrict__ src,
                                                const float* __restrict__ ada,
                                                unsigned short* __restrict__ dst,
                                                int sidx, int hidx) {
  int row = blockIdx.x;
  int b = row >> 10;
  int t = threadIdx.x, lane = t & 63, wv = t >> 6;
  float4 v = *(const float4*)(src + (size_t)row * 1024 + t * 4);
  float s = v.x + v.y + v.z + v.w;
  float s2 = v.x * v.x + v.y * v.y + v.z * v.z + v.w * v.w;
#pragma unroll
  for (int o = 1; o < 64; o <<= 1) { s += __shfl_xor(s, o); s2 += __shfl_xor(s2, o); }
  __shared__ float red[8];
  if (lane == 0) { red[wv] = s; red[4 + wv] = s2; }
  __syncthreads();
  float ts = red[0] + red[1] + red[2] + red[3];
  float ts2 = red[4] + red[5] + red[6] + red[7];
  float mu = ts * (1.f / 1024.f);
  float var = ts2 * (1.f / 1024.f) - mu * mu;
  float rstd = rsqrtf(var + 1e-6f);
  const float* ar = ada + (size_t)b * 6144;
  float4 sc = *(const float4*)(ar + sidx * 1024 + t * 4);
  float4 sh = *(const float4*)(ar + hidx * 1024 + t * 4);
  u16x4 o;
  o[0] = f2b((v.x - mu) * rstd * (sc.x + 1.f) + sh.x);
  o[1] = f2b((v.y - mu) * rstd * (sc.y + 1.f) + sh.y);
  o[2] = f2b((v.z - mu) * rstd * (sc.z + 1.f) + sh.z);
  o[3] = f2b((v.w - mu) * rstd * (sc.w + 1.f) + sh.w);
  *(u16x4*)(dst + (size_t)row * 1024 + t * 4) = o;
}

// ---------- bf16 GEMM: C = A[M,K] * W[N,K]^T, 128x128 tile, m97 structure ----------
template <int EPI>
__global__ __launch_bounds__(256) void k_gemm(const unsigned short* __restrict__ A,
                                              const unsigned short* __restrict__ W,
                                              int M, int N, int K,
                                              const float* __restrict__ bias,
                                              const float* __restrict__ qb,
                                              const float* __restrict__ vb,
                                              const float* __restrict__ resid,
                                              const float* __restrict__ ada,
                                              void* __restrict__ outp) {
  __shared__ unsigned short As[128 * 32];
  __shared__ unsigned short Bs[128 * 32];
  const int t = threadIdx.x, lane = t & 63, wv = t >> 6;
  const int wr = wv >> 1, wc = wv & 1;
  const int m0 = blockIdx.y * 128, n0 = blockIdx.x * 128;

  f32x4 zz = {0.f, 0.f, 0.f, 0.f};
  f32x4 acc[4][4];
#pragma unroll
  for (int i = 0; i < 4; ++i)
#pragma unroll
    for (int j = 0; j < 4; ++j) acc[i][j] = zz;

  const int srow = lane >> 2, scol = (lane & 3) * 8;
  const unsigned short* aSrc0 = A + (size_t)(m0 + wv * 16 + srow) * K + scol;
  const unsigned short* aSrc1 = aSrc0 + (size_t)64 * K;
  const unsigned short* bSrc0 = W + (size_t)(n0 + wv * 16 + srow) * K + scol;
  const unsigned short* bSrc1 = bSrc0 + (size_t)64 * K;
  unsigned short* aDst0 = As + wv * 512;
  unsigned short* aDst1 = As + 2048 + wv * 512;
  unsigned short* bDst0 = Bs + wv * 512;
  unsigned short* bDst1 = Bs + 2048 + wv * 512;

  const int fr = lane & 15, fk = (lane >> 4) * 8;
  const unsigned short* aRd = As + (wr * 64 + fr) * 32 + fk;
  const unsigned short* bRd = Bs + (wc * 64 + fr) * 32 + fk;

  for (int k0 = 0; k0 < K; k0 += 32) {
    __builtin_amdgcn_global_load_lds(AS1(aSrc0 + k0), AS3(aDst0), 16, 0, 0);
    __builtin_amdgcn_global_load_lds(AS1(aSrc1 + k0), AS3(aDst1), 16, 0, 0);
    __builtin_amdgcn_global_load_lds(AS1(bSrc0 + k0), AS3(bDst0), 16, 0, 0);
    __builtin_amdgcn_global_load_lds(AS1(bSrc1 + k0), AS3(bDst1), 16, 0, 0);
    __syncthreads();
    bf16x8 af[4], bfv[4];
#pragma unroll
    for (int i = 0; i < 4; ++i) af[i] = *(const bf16x8*)(aRd + i * 512);
#pragma unroll
    for (int i = 0; i < 4; ++i) bfv[i] = *(const bf16x8*)(bRd + i * 512);
#pragma unroll
    for (int mi = 0; mi < 4; ++mi)
#pragma unroll
      for (int ni = 0; ni < 4; ++ni)
        acc[mi][ni] = __builtin_amdgcn_mfma_f32_16x16x32_bf16(af[mi], bfv[ni], acc[mi][ni], 0, 0, 0);
    __syncthreads();
  }

  const int fg = lane >> 4;
#pragma unroll
  for (int mi = 0; mi < 4; ++mi) {
#pragma unroll
    for (int ni = 0; ni < 4; ++ni) {
#pragma unroll
      for (int r = 0; r < 4; ++r) {
        int m = m0 + wr * 64 + mi * 16 + fg * 4 + r;
        int n = n0 + wc * 64 + ni * 16 + fr;
        float v = acc[mi][ni][r];
        if constexpr (EPI == 0) {
          float bb = (n < 1024) ? qb[n] : ((n < 2048) ? 0.f : vb[n - 2048]);
          ((unsigned short*)outp)[(size_t)m * N + n] = f2b(v + bb);
        } else if constexpr (EPI == 1) {
          float g = ada[(size_t)(m >> 10) * 6144 + n];
          ((float*)outp)[(size_t)m * N + n] = resid[(size_t)m * N + n] + (v + bias[n]) * g;
        } else if constexpr (EPI == 2) {
          float z = v + bias[n];
          ((unsigned short*)outp)[(size_t)m * N + n] =
              f2b(0.5f * z * (1.f + erff(z * 0.70710678118654752f)));
        } else {
          float g = ada[(size_t)(m >> 10) * 6144 + 1024 + n];
          ((float*)outp)[(size_t)m * N + n] = resid[(size_t)m * N + n] + (v + bias[n]) * g;
        }
      }
    }
  }
}

// ---------- q/k l2norm (+sm scale on q) into per-head layout ----------
__global__ __launch_bounds__(256) void k_qknorm(const unsigned short* __restrict__ qkv,
                                                const float* __restrict__ smul,
                                                unsigned short* __restrict__ Qn,
                                                unsigned short* __restrict__ Kn) {
  int row = blockIdx.x;  // b*1024 + l
  int b = row >> 10, l = row & 1023;
  int t = threadIdx.x;
  int h = t >> 4, sl = t & 15;
  const unsigned short* base = qkv + (size_t)row * 3072 + h * 64 + sl * 4;
  size_t off = ((size_t)(b * 16 + h) * 1024 + l) * 64 + sl * 4;
  {
    u16x4 qv = *(const u16x4*)base;
    float q0 = b2f(qv[0]), q1 = b2f(qv[1]), q2 = b2f(qv[2]), q3 = b2f(qv[3]);
    float ss = q0 * q0 + q1 * q1 + q2 * q2 + q3 * q3;
#pragma unroll
    for (int o = 1; o < 16; o <<= 1) ss += __shfl_xor(ss, o);
    float sm = __expf(fminf(smul[h], 4.6051701859880914f));
    float qs = sm / fmaxf(sqrtf(ss), 1e-12f);
    u16x4 o; o[0] = f2b(q0 * qs); o[1] = f2b(q1 * qs); o[2] = f2b(q2 * qs); o[3] = f2b(q3 * qs);
    *(u16x4*)(Qn + off) = o;
  }
  {
    u16x4 kv = *(const u16x4*)(base + 1024);
    float k0 = b2f(kv[0]), k1 = b2f(kv[1]), k2 = b2f(kv[2]), k3 = b2f(kv[3]);
    float ss = k0 * k0 + k1 * k1 + k2 * k2 + k3 * k3;
#pragma unroll
    for (int o = 1; o < 16; o <<= 1) ss += __shfl_xor(ss, o);
    float ks = 1.f / fmaxf(sqrtf(ss), 1e-12f);
    u16x4 o; o[0] = f2b(k0 * ks); o[1] = f2b(k1 * ks); o[2] = f2b(k2 * ks); o[3] = f2b(k3 * ks);
    *(u16x4*)(Kn + off) = o;
  }
}

// ---------- V transpose with k-slot permutation ----------
// Vt[d][64t + p] := V[64t + phys(p)][d], phys(p) = ((p>>5)*2+((p>>2)&1))*16
// + ((p>>3)&3)*4 + (p&3): matches the in-register P layout of the swapped-QK
// MFMA output so PV needs NO cross-lane P movement.
__global__ __launch_bounds__(256) void k_vtrans(const unsigned short* __restrict__ qkv,
                                                unsigned short* __restrict__ Vt) {
  int bh = blockIdx.y, b = bh >> 4, h = bh & 15;
  int l0 = blockIdx.x * 64;
  __shared__ unsigned short tile[64][72];
  int t = threadIdx.x;
  int lr = t >> 2, dp = (t & 3) * 16;
  const unsigned short* src = qkv + (size_t)(b * 1024 + l0 + lr) * 3072 + 2048 + h * 64 + dp;
  *(u16x8*)&tile[lr][dp] = *(const u16x8*)src;
  *(u16x8*)&tile[lr][dp + 8] = *(const u16x8*)(src + 8);
  __syncthreads();
  int d = t >> 2, lp = (t & 3) * 16;
  unsigned short ov[16];
#pragma unroll
  for (int j = 0; j < 16; ++j) {
    int p = lp + j;
    int l = ((p >> 5) * 2 + ((p >> 2) & 1)) * 16 + ((p >> 3) & 3) * 4 + (p & 3);
    ov[j] = tile[l][d];
  }
  unsigned short* dst = Vt + ((size_t)bh * 64 + d) * 1024 + l0 + lp;
  *(u16x8*)dst = *(u16x8*)&ov[0];
  *(u16x8*)(dst + 8) = *(u16x8*)&ov[8];
}

// ---------- flash attention v3 ----------
// - static-max softmax (scores bounded by sm via l2-norm)
// - K,V tiles LDS-staged cooperatively, double-buffered 2-phase
// - pre-swizzled global source (XOR chunk^row&7) -> conflict-free ds_read_b128
// - swapped QK mfma(K,Q): P stays in registers; V^T pre-permuted to match
// - 32 q-rows per wave, 4 waves/block, grid (8, 64)
__global__ __launch_bounds__(256) void k_attn(const unsigned short* __restrict__ Qn,
                                              const unsigned short* __restrict__ Kn,
                                              const unsigned short* __restrict__ Vt,
                                              const float* __restrict__ smul,
                                              unsigned short* __restrict__ O) {
  const int qt = blockIdx.x, bh = blockIdx.y;
  const int b = bh >> 4, h = bh & 15;
  const int t = threadIdx.x, lane = t & 63, wv = t >> 6;
  const int fr = lane & 15, fg = lane >> 4;
  __shared__ unsigned short Kb[2][4096];
  __shared__ unsigned short Vb[2][4096];

  const int q0 = qt * 128 + wv * 32;
  const unsigned short* qp = Qn + ((size_t)bh * 1024 + q0 + fr) * 64 + fg * 8;
  bf16x8 qf00 = *(const bf16x8*)qp;
  bf16x8 qf01 = *(const bf16x8*)(qp + 32);
  bf16x8 qf10 = *(const bf16x8*)(qp + 1024);
  bf16x8 qf11 = *(const bf16x8*)(qp + 1024 + 32);

  const float M = __expf(fminf(smul[h], 4.6051701859880914f));

  // staging: each wave covers rows [wv*16, wv*16+16) of the 64-row tile,
  // two global_load_lds per operand; source pre-swizzled chunk^(row&7).
  const int srow = lane >> 3, sc = lane & 7;
  const int xr = (sc ^ srow) * 8;  // (row&7)==srow for both 8-row groups
  const unsigned short* kp0 = Kn + (size_t)bh * 65536 + (size_t)(wv * 16 + srow) * 64 + xr;
  const unsigned short* kp1 = kp0 + 8 * 64;
  const unsigned short* vp0 = Vt + (size_t)bh * 65536 + (size_t)(wv * 16 + srow) * 1024 + xr;
  const unsigned short* vp1 = vp0 + 8 * 1024;

  f32x4 zz = {0.f, 0.f, 0.f, 0.f};
  f32x4 oa0[4], oa1[4];
#pragma unroll
  for (int i = 0; i < 4; ++i) { oa0[i] = zz; oa1[i] = zz; }
  float ls0 = 0.f, ls1 = 0.f;

  {
    unsigned short* kd = &Kb[0][wv * 1024];
    unsigned short* vd = &Vb[0][wv * 1024];
    __builtin_amdgcn_global_load_lds(AS1(kp0), AS3(kd), 16, 0, 0);
    __builtin_amdgcn_global_load_lds(AS1(kp1), AS3(kd + 512), 16, 0, 0);
    __builtin_amdgcn_global_load_lds(AS1(vp0), AS3(vd), 16, 0, 0);
    __builtin_amdgcn_global_load_lds(AS1(vp1), AS3(vd + 512), 16, 0, 0);
  }
  __syncthreads();

  int cur = 0;
  for (int kv = 0; kv < 1024; kv += 64) {
    const int nxt = cur ^ 1;
    if (kv + 64 < 1024) {
      const int ko = (kv + 64) * 64;
      const int vo = kv + 64;
      unsigned short* kd = &Kb[nxt][wv * 1024];
      unsigned short* vd = &Vb[nxt][wv * 1024];
      __builtin_amdgcn_global_load_lds(AS1(kp0 + ko), AS3(kd), 16, 0, 0);
      __builtin_amdgcn_global_load_lds(AS1(kp1 + ko), AS3(kd + 512), 16, 0, 0);
      __builtin_amdgcn_global_load_lds(AS1(vp0 + vo), AS3(vd), 16, 0, 0);
      __builtin_amdgcn_global_load_lds(AS1(vp1 + vo), AS3(vd + 512), 16, 0, 0);
    }

    // QK^T (swapped: mfma(K, Q)) — lane holds P[k=ct*16+fg*4+r][q=fr]
    f32x4 s0[4], s1[4];
#pragma unroll
    for (int ct = 0; ct < 4; ++ct) {
      const int row = ct * 16 + fr, r7 = row & 7;
      const unsigned short* kr = &Kb[cur][row * 64];
      bf16x8 kf0 = *(const bf16x8*)(kr + ((fg ^ r7) << 3));
      bf16x8 kf1 = *(const bf16x8*)(kr + (((4 + fg) ^ r7) << 3));
      f32x4 z0 = __builtin_amdgcn_mfma_f32_16x16x32_bf16(kf0, qf00, zz, 0, 0, 0);
      s0[ct] = __builtin_amdgcn_mfma_f32_16x16x32_bf16(kf1, qf01, z0, 0, 0, 0);
      f32x4 z1 = __builtin_amdgcn_mfma_f32_16x16x32_bf16(kf0, qf10, zz, 0, 0, 0);
      s1[ct] = __builtin_amdgcn_mfma_f32_16x16x32_bf16(kf1, qf11, z1, 0, 0, 0);
    }

    // softmax numerators straight into PV A-fragments (no LDS, no shuffles)
    bf16x8 pa0[2], pa1[2];
#pragma unroll
    for (int kg = 0; kg < 2; ++kg) {
      bf16x8 a0, a1;
#pragma unroll
      for (int c2 = 0; c2 < 2; ++c2) {
#pragma unroll
        for (int r = 0; r < 4; ++r) {
          float e0 = __expf(s0[kg * 2 + c2][r] - M);
          float e1 = __expf(s1[kg * 2 + c2][r] - M);
          ls0 += e0; ls1 += e1;
          a0[c2 * 4 + r] = (__bf16)e0;
          a1[c2 * 4 + r] = (__bf16)e1;
        }
      }
      pa0[kg] = a0; pa1[kg] = a1;
    }

    // PV: B = V^T tile (pre-permuted to the in-register P k-slot order)
#pragma unroll
    for (int kg = 0; kg < 2; ++kg) {
#pragma unroll
      for (int dt = 0; dt < 4; ++dt) {
        const int row = dt * 16 + fr, r7 = row & 7;
        bf16x8 vf = *(const bf16x8*)(&Vb[cur][row * 64] + ((((kg << 2) + fg) ^ r7) << 3));
        oa0[dt] = __builtin_amdgcn_mfma_f32_16x16x32_bf16(pa0[kg], vf, oa0[dt], 0, 0, 0);
        oa1[dt] = __builtin_amdgcn_mfma_f32_16x16x32_bf16(pa1[kg], vf, oa1[dt], 0, 0, 0);
      }
    }
    __syncthreads();
    cur = nxt;
  }

  // lane partial sums are for q = fr; disjoint k-slots live at lane^16, ^32
  ls0 += __shfl_xor(ls0, 16); ls0 += __shfl_xor(ls0, 32);
  ls1 += __shfl_xor(ls1, 16); ls1 += __shfl_xor(ls1, 32);

#pragma unroll
  for (int r = 0; r < 4; ++r) {
    float i0 = 1.f / __shfl(ls0, fg * 4 + r);
    float i1 = 1.f / __shfl(ls1, fg * 4 + r);
    unsigned short* ob = O + ((size_t)(b * 1024 + q0 + fg * 4 + r)) * 1024 + h * 64 + fr;
#pragma unroll
    for (int dt = 0; dt < 4; ++dt) {
      ob[dt * 16] = f2b(oa0[dt][r] * i0);
      ob[(size_t)16 * 1024 + dt * 16] = f2b(oa1[dt][r] * i1);
    }
  }
}

// ---------- launch ----------
extern "C" void kernel_launch(void* const* d_in, const int* in_sizes, int n_in,
                              void* d_out, int out_size, void* d_ws, size_t ws_size,
                              hipStream_t stream) {
  const float* x        = (const float*)d_in[0];
  const float* cond     = (const float*)d_in[1];
  const float* qkv_w    = (const float*)d_in[2];
  const float* q_bias   = (const float*)d_in[3];
  const float* v_bias   = (const float*)d_in[4];
  const float* scale_mul= (const float*)d_in[5];
  const float* proj_w   = (const float*)d_in[6];
  const float* proj_b   = (const float*)d_in[7];
  const float* ada_w    = (const float*)d_in[8];
  const float* ada_b    = (const float*)d_in[9];
  const float* fc1_w    = (const float*)d_in[10];
  const float* fc1_b    = (const float*)d_in[11];
  const float* fc2_w    = (const float*)d_in[12];
  const float* fc2_b    = (const float*)d_in[13];
  float* out = (float*)d_out;
  char* ws = (char*)d_ws;

  unsigned short* WQ   = (unsigned short*)(ws + 0);          // 6291456
  unsigned short* WP   = (unsigned short*)(ws + 6291456);    // 2097152
  unsigned short* WF1  = (unsigned short*)(ws + 8388608);    // 8388608
  unsigned short* WF2  = (unsigned short*)(ws + 16777216);   // 8388608
  float*          SIL  = (float*)(ws + 25165824);            // 16384
  float*          ADA  = (float*)(ws + 25182208);            // 98304
  unsigned short* X1   = (unsigned short*)(ws + 25280512);   // 8388608 (reused for x2)
  unsigned short* QKVB = (unsigned short*)(ws + 33669120);   // 25165824 (dead after norm/vtrans)
  unsigned short* QN   = (unsigned short*)(ws + 58834944);   // 8388608
  unsigned short* KN   = (unsigned short*)(ws + 67223552);   // 8388608
  unsigned short* VT   = (unsigned short*)(ws + 75612160);   // 8388608
  unsigned short* OB   = (unsigned short*)(ws + 84000768);   // 8388608  -> ws top 92389376
  float*          XMID = (float*)(ws + 33669120);            // 16777216 (reuses dead QKVB)
  unsigned short* HB   = (unsigned short*)(ws + 50446336);   // 33554432 (reuses dead QKVB/QN/KN/VT)

  (void)in_sizes; (void)n_in; (void)out_size; (void)ws_size;

  k_silu<<<16, 256, 0, stream>>>(cond, SIL);
  k_ada<<<1536, 256, 0, stream>>>(SIL, ada_w, ada_b, ADA);
  k_cast<<<3072, 256, 0, stream>>>(qkv_w, WQ, 3145728);
  k_cast<<<1024, 256, 0, stream>>>(proj_w, WP, 1048576);
  k_cast<<<4096, 256, 0, stream>>>(fc1_w, WF1, 4194304);
  k_cast<<<4096, 256, 0, stream>>>(fc2_w, WF2, 4194304);

  k_ln_mod<<<4096, 256, 0, stream>>>(x, ADA, X1, 2, 4);
  k_gemm<0><<<dim3(24, 32), 256, 0, stream>>>(X1, WQ, 4096, 3072, 1024,
                                              nullptr, q_bias, v_bias, nullptr, nullptr, QKVB);
  k_qknorm<<<4096, 256, 0, stream>>>(QKVB, scale_mul, QN, KN);
  k_vtrans<<<dim3(16, 64), 256, 0, stream>>>(QKVB, VT);
  k_attn<<<dim3(8, 64), 256, 0, stream>>>(QN, KN, VT, scale_mul, OB);
  k_gemm<1><<<dim3(8, 32), 256, 0, stream>>>(OB, WP, 4096, 1024, 1024,
                                             proj_b, nullptr, nullptr, x, ADA, XMID);
  k_ln_mod<<<4096, 256, 0, stream>>>(XMID, ADA, X1, 3, 5);
  k_gemm<2><<<dim3(32, 32), 256, 0, stream>>>(X1, WF1, 4096, 4096, 1024,
                                              fc1_b, nullptr, nullptr, nullptr, nullptr, HB);
  k_gemm<3><<<dim3(8, 32), 256, 0, stream>>>(HB, WF2, 4096, 1024, 4096,
                                             fc2_b, nullptr, nullptr, XMID, ADA, out);
}

// Round 4
// 265.040 us; speedup vs baseline: 1.5560x; 1.2153x over previous
//
#include <hip/hip_runtime.h>

// ---------- types ----------
typedef __bf16 bf16x8_t __attribute__((ext_vector_type(8)));
typedef bf16x8_t bf16x8 __attribute__((may_alias));
typedef float f32x4 __attribute__((ext_vector_type(4)));
typedef unsigned short u16x4 __attribute__((ext_vector_type(4)));
typedef unsigned short u16x8 __attribute__((ext_vector_type(8)));

#define DEV __device__ __forceinline__

DEV float b2f(unsigned short u) {
  union { unsigned int i; float f; } x; x.i = ((unsigned int)u) << 16; return x.f;
}
DEV unsigned short f2b(float f) {
  union { float f; unsigned int i; } x; x.f = f;
  return (unsigned short)((x.i + 0x7fffu + ((x.i >> 16) & 1u)) >> 16);
}

#define AS1(p) ((__attribute__((address_space(1))) void*)(p))
#define AS3(p) ((__attribute__((address_space(3))) void*)(p))

// ---------- tiny kernels ----------
__global__ void k_silu(const float* __restrict__ c, float* __restrict__ o) {
  int i = blockIdx.x * 256 + threadIdx.x;
  float v = c[i];
  o[i] = v / (1.f + __expf(-v));
}

// wave per output column j; computes all 4 batches so ada_w is read ONCE.
__global__ __launch_bounds__(256) void k_ada(const float* __restrict__ sc,
                                             const float* __restrict__ w,
                                             const float* __restrict__ bias,
                                             float* __restrict__ out) {
  int j = blockIdx.x * 4 + (threadIdx.x >> 6);
  int lane = threadIdx.x & 63;
  const float* wr = w + (size_t)j * 1024;
  float s0 = 0.f, s1 = 0.f, s2 = 0.f, s3 = 0.f;
#pragma unroll
  for (int u = 0; u < 4; ++u) {
    int k = u * 256 + lane * 4;
    float4 a = *(const float4*)(wr + k);
    float4 c0 = *(const float4*)(sc + k);
    float4 c1 = *(const float4*)(sc + 1024 + k);
    float4 c2 = *(const float4*)(sc + 2048 + k);
    float4 c3 = *(const float4*)(sc + 3072 + k);
    s0 += a.x * c0.x + a.y * c0.y + a.z * c0.z + a.w * c0.w;
    s1 += a.x * c1.x + a.y * c1.y + a.z * c1.z + a.w * c1.w;
    s2 += a.x * c2.x + a.y * c2.y + a.z * c2.z + a.w * c2.w;
    s3 += a.x * c3.x + a.y * c3.y + a.z * c3.z + a.w * c3.w;
  }
#pragma unroll
  for (int o = 1; o < 64; o <<= 1) {
    s0 += __shfl_xor(s0, o); s1 += __shfl_xor(s1, o);
    s2 += __shfl_xor(s2, o); s3 += __shfl_xor(s3, o);
  }
  if (lane == 0) {
    float bb = bias[j];
    out[j] = s0 + bb;
    out[6144 + j] = s1 + bb;
    out[12288 + j] = s2 + bb;
    out[18432 + j] = s3 + bb;
  }
}

__global__ void k_cast(const float* __restrict__ s, unsigned short* __restrict__ d, int n) {
  int i = (blockIdx.x * 256 + threadIdx.x) * 4;
  if (i >= n) return;
  float4 v = *(const float4*)(s + i);
  u16x4 o;
  o[0] = f2b(v.x); o[1] = f2b(v.y); o[2] = f2b(v.z); o[3] = f2b(v.w);
  *(u16x4*)(d + i) = o;
}

// LayerNorm (affine-free) + AdaLN modulate -> bf16
__global__ __launch_bounds__(256) void k_ln_mod(const float* __restrict__ src,
                                                const float* __restrict__ ada,
                                                unsigned short* __restrict__ dst,
                                                int sidx, int hidx) {
  int row = blockIdx.x;
  int b = row >> 10;
  int t = threadIdx.x, lane = t & 63, wv = t >> 6;
  float4 v = *(const float4*)(src + (size_t)row * 1024 + t * 4);
  float s = v.x + v.y + v.z + v.w;
  float s2 = v.x * v.x + v.y * v.y + v.z * v.z + v.w * v.w;
#pragma unroll
  for (int o = 1; o < 64; o <<= 1) { s += __shfl_xor(s, o); s2 += __shfl_xor(s2, o); }
  __shared__ float red[8];
  if (lane == 0) { red[wv] = s; red[4 + wv] = s2; }
  __syncthreads();
  float ts = red[0] + red[1] + red[2] + red[3];
  float ts2 = red[4] + red[5] + red[6] + red[7];
  float mu = ts * (1.f / 1024.f);
  float var = ts2 * (1.f / 1024.f) - mu * mu;
  float rstd = rsqrtf(var + 1e-6f);
  const float* ar = ada + (size_t)b * 6144;
  float4 sc = *(const float4*)(ar + sidx * 1024 + t * 4);
  float4 sh = *(const float4*)(ar + hidx * 1024 + t * 4);
  u16x4 o;
  o[0] = f2b((v.x - mu) * rstd * (sc.x + 1.f) + sh.x);
  o[1] = f2b((v.y - mu) * rstd * (sc.y + 1.f) + sh.y);
  o[2] = f2b((v.z - mu) * rstd * (sc.z + 1.f) + sh.z);
  o[3] = f2b((v.w - mu) * rstd * (sc.w + 1.f) + sh.w);
  *(u16x4*)(dst + (size_t)row * 1024 + t * 4) = o;
}

// ---------- bf16 GEMM, 128x128 tile, 2-phase double-buffered, XCD-swizzled ----------
// EPI: 0=qkv(+concat bias, bf16 out) 2=fc1(+bias, exact gelu, bf16 out)
template <int EPI>
__global__ __launch_bounds__(256) void k_gemm(const unsigned short* __restrict__ A,
                                              const unsigned short* __restrict__ W,
                                              int M, int N, int K,
                                              const float* __restrict__ bias,
                                              const float* __restrict__ qb,
                                              const float* __restrict__ vb,
                                              void* __restrict__ outp) {
  __shared__ unsigned short As[2][4096];
  __shared__ unsigned short Bs[2][4096];
  const int t = threadIdx.x, lane = t & 63, wv = t >> 6;
  const int wr = wv >> 1, wc = wv & 1;
  // bijective XCD swizzle (grid % 8 == 0): XCD c owns a contiguous tile chunk
  const int cpx = gridDim.x >> 3;
  const int orig = blockIdx.x;
  const int wid = (orig & 7) * cpx + (orig >> 3);
  const int nx = N >> 7;
  const int m0 = (wid / nx) * 128, n0 = (wid % nx) * 128;

  f32x4 zz = {0.f, 0.f, 0.f, 0.f};
  f32x4 acc[4][4];
#pragma unroll
  for (int i = 0; i < 4; ++i)
#pragma unroll
    for (int j = 0; j < 4; ++j) acc[i][j] = zz;

  const int srow = lane >> 2, scol = (lane & 3) * 8;
  const unsigned short* aSrc0 = A + (size_t)(m0 + wv * 16 + srow) * K + scol;
  const unsigned short* aSrc1 = aSrc0 + (size_t)64 * K;
  const unsigned short* bSrc0 = W + (size_t)(n0 + wv * 16 + srow) * K + scol;
  const unsigned short* bSrc1 = bSrc0 + (size_t)64 * K;

  const int fr = lane & 15, fk = (lane >> 4) * 8;

#define STAGE_G(buf, k0)                                                                   \
  {                                                                                        \
    __builtin_amdgcn_global_load_lds(AS1(aSrc0 + (k0)), AS3(&As[buf][wv * 512]), 16, 0, 0);\
    __builtin_amdgcn_global_load_lds(AS1(aSrc1 + (k0)), AS3(&As[buf][2048 + wv * 512]), 16, 0, 0);\
    __builtin_amdgcn_global_load_lds(AS1(bSrc0 + (k0)), AS3(&Bs[buf][wv * 512]), 16, 0, 0);\
    __builtin_amdgcn_global_load_lds(AS1(bSrc1 + (k0)), AS3(&Bs[buf][2048 + wv * 512]), 16, 0, 0);\
  }

  STAGE_G(0, 0);
  __syncthreads();
  int cur = 0;
  for (int k0 = 0; k0 < K; k0 += 32) {
    if (k0 + 32 < K) STAGE_G(cur ^ 1, k0 + 32);
    const unsigned short* aRd = &As[cur][(wr * 64 + fr) * 32 + fk];
    const unsigned short* bRd = &Bs[cur][(wc * 64 + fr) * 32 + fk];
    bf16x8 af[4], bfv[4];
#pragma unroll
    for (int i = 0; i < 4; ++i) af[i] = *(const bf16x8*)(aRd + i * 512);
#pragma unroll
    for (int i = 0; i < 4; ++i) bfv[i] = *(const bf16x8*)(bRd + i * 512);
#pragma unroll
    for (int mi = 0; mi < 4; ++mi)
#pragma unroll
      for (int ni = 0; ni < 4; ++ni)
        acc[mi][ni] = __builtin_amdgcn_mfma_f32_16x16x32_bf16(af[mi], bfv[ni], acc[mi][ni], 0, 0, 0);
    __syncthreads();
    cur ^= 1;
  }

  const int fg = lane >> 4;
#pragma unroll
  for (int mi = 0; mi < 4; ++mi) {
#pragma unroll
    for (int ni = 0; ni < 4; ++ni) {
#pragma unroll
      for (int r = 0; r < 4; ++r) {
        int m = m0 + wr * 64 + mi * 16 + fg * 4 + r;
        int n = n0 + wc * 64 + ni * 16 + fr;
        float v = acc[mi][ni][r];
        if constexpr (EPI == 0) {
          float bb = (n < 1024) ? qb[n] : ((n < 2048) ? 0.f : vb[n - 2048]);
          ((unsigned short*)outp)[(size_t)m * N + n] = f2b(v + bb);
        } else {
          float z = v + bias[n];
          ((unsigned short*)outp)[(size_t)m * N + n] =
              f2b(0.5f * z * (1.f + erff(z * 0.70710678118654752f)));
        }
      }
    }
  }
}

// ---------- 8-wave split-K GEMM for N=1024 shapes (proj, fc2) ----------
// Two 4-wave groups, each 2-phase double-buffered over half of K; group 1
// passes f32 partials via LDS; group 0 combines + epilogue (resid + gamma).
// EPI: 1=proj(+b,*g1,+x resid, f32 out)  3=fc2(+b,*g2,+xmid resid, f32 out)
template <int EPI>
__global__ __launch_bounds__(512) void k_gemm8(const unsigned short* __restrict__ A,
                                               const unsigned short* __restrict__ W,
                                               int M, int N, int K, int Khalf,
                                               const float* __restrict__ bias,
                                               const float* __restrict__ resid,
                                               const float* __restrict__ ada,
                                               float* __restrict__ outp) {
  __shared__ unsigned short SM[32768];  // 64 KiB: [grp][buf] A(16K) | B(16K); reused as f32 xchg
  const int t = threadIdx.x, lane = t & 63, wv = t >> 6;
  const int grp = wv >> 2, w4 = wv & 3;
  const int wr = w4 >> 1, wc = w4 & 1;
  const int cpx = gridDim.x >> 3;
  const int orig = blockIdx.x;
  const int wid = (orig & 7) * cpx + (orig >> 3);
  const int nx = N >> 7;
  const int m0 = (wid / nx) * 128, n0 = (wid % nx) * 128;

  f32x4 zz = {0.f, 0.f, 0.f, 0.f};
  f32x4 acc[4][4];
#pragma unroll
  for (int i = 0; i < 4; ++i)
#pragma unroll
    for (int j = 0; j < 4; ++j) acc[i][j] = zz;

  const int srow = lane >> 2, scol = (lane & 3) * 8;
  const int kbase = grp * Khalf;
  const unsigned short* aSrc0 = A + (size_t)(m0 + w4 * 16 + srow) * K + kbase + scol;
  const unsigned short* aSrc1 = aSrc0 + (size_t)64 * K;
  const unsigned short* bSrc0 = W + (size_t)(n0 + w4 * 16 + srow) * K + kbase + scol;
  const unsigned short* bSrc1 = bSrc0 + (size_t)64 * K;
  unsigned short* aBase = SM + grp * 8192;
  unsigned short* bBase = SM + 16384 + grp * 8192;

  const int fr = lane & 15, fk = (lane >> 4) * 8;

#define STAGE_G8(buf, k0)                                                                       \
  {                                                                                             \
    __builtin_amdgcn_global_load_lds(AS1(aSrc0 + (k0)), AS3(aBase + (buf)*4096 + w4 * 512), 16, 0, 0); \
    __builtin_amdgcn_global_load_lds(AS1(aSrc1 + (k0)), AS3(aBase + (buf)*4096 + 2048 + w4 * 512), 16, 0, 0); \
    __builtin_amdgcn_global_load_lds(AS1(bSrc0 + (k0)), AS3(bBase + (buf)*4096 + w4 * 512), 16, 0, 0); \
    __builtin_amdgcn_global_load_lds(AS1(bSrc1 + (k0)), AS3(bBase + (buf)*4096 + 2048 + w4 * 512), 16, 0, 0); \
  }

  STAGE_G8(0, 0);
  __syncthreads();
  int cur = 0;
  for (int k0 = 0; k0 < Khalf; k0 += 32) {
    if (k0 + 32 < Khalf) STAGE_G8(cur ^ 1, k0 + 32);
    const unsigned short* aRd = aBase + cur * 4096 + (wr * 64 + fr) * 32 + fk;
    const unsigned short* bRd = bBase + cur * 4096 + (wc * 64 + fr) * 32 + fk;
    bf16x8 af[4], bfv[4];
#pragma unroll
    for (int i = 0; i < 4; ++i) af[i] = *(const bf16x8*)(aRd + i * 512);
#pragma unroll
    for (int i = 0; i < 4; ++i) bfv[i] = *(const bf16x8*)(bRd + i * 512);
#pragma unroll
    for (int mi = 0; mi < 4; ++mi)
#pragma unroll
      for (int ni = 0; ni < 4; ++ni)
        acc[mi][ni] = __builtin_amdgcn_mfma_f32_16x16x32_bf16(af[mi], bfv[ni], acc[mi][ni], 0, 0, 0);
    __syncthreads();
    cur ^= 1;
  }

  // split-K combine through LDS (64 KB = 4 waves x 64 lanes x 16 f32x4)
  float* xch = (float*)SM;
#pragma unroll
  for (int c = 0; c < 16; ++c) {
    if (grp == 1)
      *(f32x4*)&xch[c * 1024 + (w4 * 64 + lane) * 4] = acc[c >> 2][c & 3];
  }
  __syncthreads();
  if (grp == 1) return;
#pragma unroll
  for (int c = 0; c < 16; ++c) {
    f32x4 p = *(const f32x4*)&xch[c * 1024 + (w4 * 64 + lane) * 4];
    acc[c >> 2][c & 3] += p;
  }

  const int fg = lane >> 4;
#pragma unroll
  for (int mi = 0; mi < 4; ++mi) {
#pragma unroll
    for (int ni = 0; ni < 4; ++ni) {
#pragma unroll
      for (int r = 0; r < 4; ++r) {
        int m = m0 + wr * 64 + mi * 16 + fg * 4 + r;
        int n = n0 + wc * 64 + ni * 16 + fr;
        float v = acc[mi][ni][r];
        const int aoff = (EPI == 1) ? 0 : 1024;
        float g = ada[(size_t)(m >> 10) * 6144 + aoff + n];
        outp[(size_t)m * N + n] = resid[(size_t)m * N + n] + (v + bias[n]) * g;
      }
    }
  }
}

// ---------- q/k l2norm (+sm scale on q) into per-head layout ----------
__global__ __launch_bounds__(256) void k_qknorm(const unsigned short* __restrict__ qkv,
                                                const float* __restrict__ smul,
                                                unsigned short* __restrict__ Qn,
                                                unsigned short* __restrict__ Kn) {
  int row = blockIdx.x;  // b*1024 + l
  int b = row >> 10, l = row & 1023;
  int t = threadIdx.x;
  int h = t >> 4, sl = t & 15;
  const unsigned short* base = qkv + (size_t)row * 3072 + h * 64 + sl * 4;
  size_t off = ((size_t)(b * 16 + h) * 1024 + l) * 64 + sl * 4;
  {
    u16x4 qv = *(const u16x4*)base;
    float q0 = b2f(qv[0]), q1 = b2f(qv[1]), q2 = b2f(qv[2]), q3 = b2f(qv[3]);
    float ss = q0 * q0 + q1 * q1 + q2 * q2 + q3 * q3;
#pragma unroll
    for (int o = 1; o < 16; o <<= 1) ss += __shfl_xor(ss, o);
    float sm = __expf(fminf(smul[h], 4.6051701859880914f));
    float qs = sm / fmaxf(sqrtf(ss), 1e-12f);
    u16x4 o; o[0] = f2b(q0 * qs); o[1] = f2b(q1 * qs); o[2] = f2b(q2 * qs); o[3] = f2b(q3 * qs);
    *(u16x4*)(Qn + off) = o;
  }
  {
    u16x4 kv = *(const u16x4*)(base + 1024);
    float k0 = b2f(kv[0]), k1 = b2f(kv[1]), k2 = b2f(kv[2]), k3 = b2f(kv[3]);
    float ss = k0 * k0 + k1 * k1 + k2 * k2 + k3 * k3;
#pragma unroll
    for (int o = 1; o < 16; o <<= 1) ss += __shfl_xor(ss, o);
    float ks = 1.f / fmaxf(sqrtf(ss), 1e-12f);
    u16x4 o; o[0] = f2b(k0 * ks); o[1] = f2b(k1 * ks); o[2] = f2b(k2 * ks); o[3] = f2b(k3 * ks);
    *(u16x4*)(Kn + off) = o;
  }
}

// ---------- V transpose with k-slot permutation ----------
// Vt[d][64t + p] := V[64t + phys(p)][d], phys(p) = ((p>>5)*2+((p>>2)&1))*16
// + ((p>>3)&3)*4 + (p&3): matches the in-register P layout of the swapped-QK
// MFMA output so PV needs NO cross-lane P movement.
__global__ __launch_bounds__(256) void k_vtrans(const unsigned short* __restrict__ qkv,
                                                unsigned short* __restrict__ Vt) {
  int bh = blockIdx.y, b = bh >> 4, h = bh & 15;
  int l0 = blockIdx.x * 64;
  __shared__ unsigned short tile[64][72];
  int t = threadIdx.x;
  int lr = t >> 2, dp = (t & 3) * 16;
  const unsigned short* src = qkv + (size_t)(b * 1024 + l0 + lr) * 3072 + 2048 + h * 64 + dp;
  *(u16x8*)&tile[lr][dp] = *(const u16x8*)src;
  *(u16x8*)&tile[lr][dp + 8] = *(const u16x8*)(src + 8);
  __syncthreads();
  int d = t >> 2, lp = (t & 3) * 16;
  unsigned short ov[16];
#pragma unroll
  for (int j = 0; j < 16; ++j) {
    int p = lp + j;
    int l = ((p >> 5) * 2 + ((p >> 2) & 1)) * 16 + ((p >> 3) & 3) * 4 + (p & 3);
    ov[j] = tile[l][d];
  }
  unsigned short* dst = Vt + ((size_t)bh * 64 + d) * 1024 + l0 + lp;
  *(u16x8*)dst = *(u16x8*)&ov[0];
  *(u16x8*)(dst + 8) = *(u16x8*)&ov[8];
}

// ---------- flash attention v3 (unchanged from round 3) ----------
__global__ __launch_bounds__(256) void k_attn(const unsigned short* __restrict__ Qn,
                                              const unsigned short* __restrict__ Kn,
                                              const unsigned short* __restrict__ Vt,
                                              const float* __restrict__ smul,
                                              unsigned short* __restrict__ O) {
  const int qt = blockIdx.x, bh = blockIdx.y;
  const int b = bh >> 4, h = bh & 15;
  const int t = threadIdx.x, lane = t & 63, wv = t >> 6;
  const int fr = lane & 15, fg = lane >> 4;
  __shared__ unsigned short Kb[2][4096];
  __shared__ unsigned short Vb[2][4096];

  const int q0 = qt * 128 + wv * 32;
  const unsigned short* qp = Qn + ((size_t)bh * 1024 + q0 + fr) * 64 + fg * 8;
  bf16x8 qf00 = *(const bf16x8*)qp;
  bf16x8 qf01 = *(const bf16x8*)(qp + 32);
  bf16x8 qf10 = *(const bf16x8*)(qp + 1024);
  bf16x8 qf11 = *(const bf16x8*)(qp + 1024 + 32);

  const float M = __expf(fminf(smul[h], 4.6051701859880914f));

  const int srow = lane >> 3, sc = lane & 7;
  const int xr = (sc ^ srow) * 8;
  const unsigned short* kp0 = Kn + (size_t)bh * 65536 + (size_t)(wv * 16 + srow) * 64 + xr;
  const unsigned short* kp1 = kp0 + 8 * 64;
  const unsigned short* vp0 = Vt + (size_t)bh * 65536 + (size_t)(wv * 16 + srow) * 1024 + xr;
  const unsigned short* vp1 = vp0 + 8 * 1024;

  f32x4 zz = {0.f, 0.f, 0.f, 0.f};
  f32x4 oa0[4], oa1[4];
#pragma unroll
  for (int i = 0; i < 4; ++i) { oa0[i] = zz; oa1[i] = zz; }
  float ls0 = 0.f, ls1 = 0.f;

  {
    unsigned short* kd = &Kb[0][wv * 1024];
    unsigned short* vd = &Vb[0][wv * 1024];
    __builtin_amdgcn_global_load_lds(AS1(kp0), AS3(kd), 16, 0, 0);
    __builtin_amdgcn_global_load_lds(AS1(kp1), AS3(kd + 512), 16, 0, 0);
    __builtin_amdgcn_global_load_lds(AS1(vp0), AS3(vd), 16, 0, 0);
    __builtin_amdgcn_global_load_lds(AS1(vp1), AS3(vd + 512), 16, 0, 0);
  }
  __syncthreads();

  int cur = 0;
  for (int kv = 0; kv < 1024; kv += 64) {
    const int nxt = cur ^ 1;
    if (kv + 64 < 1024) {
      const int ko = (kv + 64) * 64;
      const int vo = kv + 64;
      unsigned short* kd = &Kb[nxt][wv * 1024];
      unsigned short* vd = &Vb[nxt][wv * 1024];
      __builtin_amdgcn_global_load_lds(AS1(kp0 + ko), AS3(kd), 16, 0, 0);
      __builtin_amdgcn_global_load_lds(AS1(kp1 + ko), AS3(kd + 512), 16, 0, 0);
      __builtin_amdgcn_global_load_lds(AS1(vp0 + vo), AS3(vd), 16, 0, 0);
      __builtin_amdgcn_global_load_lds(AS1(vp1 + vo), AS3(vd + 512), 16, 0, 0);
    }

    f32x4 s0[4], s1[4];
#pragma unroll
    for (int ct = 0; ct < 4; ++ct) {
      const int row = ct * 16 + fr, r7 = row & 7;
      const unsigned short* kr = &Kb[cur][row * 64];
      bf16x8 kf0 = *(const bf16x8*)(kr + ((fg ^ r7) << 3));
      bf16x8 kf1 = *(const bf16x8*)(kr + (((4 + fg) ^ r7) << 3));
      f32x4 z0 = __builtin_amdgcn_mfma_f32_16x16x32_bf16(kf0, qf00, zz, 0, 0, 0);
      s0[ct] = __builtin_amdgcn_mfma_f32_16x16x32_bf16(kf1, qf01, z0, 0, 0, 0);
      f32x4 z1 = __builtin_amdgcn_mfma_f32_16x16x32_bf16(kf0, qf10, zz, 0, 0, 0);
      s1[ct] = __builtin_amdgcn_mfma_f32_16x16x32_bf16(kf1, qf11, z1, 0, 0, 0);
    }

    bf16x8 pa0[2], pa1[2];
#pragma unroll
    for (int kg = 0; kg < 2; ++kg) {
      bf16x8 a0, a1;
#pragma unroll
      for (int c2 = 0; c2 < 2; ++c2) {
#pragma unroll
        for (int r = 0; r < 4; ++r) {
          float e0 = __expf(s0[kg * 2 + c2][r] - M);
          float e1 = __expf(s1[kg * 2 + c2][r] - M);
          ls0 += e0; ls1 += e1;
          a0[c2 * 4 + r] = (__bf16)e0;
          a1[c2 * 4 + r] = (__bf16)e1;
        }
      }
      pa0[kg] = a0; pa1[kg] = a1;
    }

#pragma unroll
    for (int kg = 0; kg < 2; ++kg) {
#pragma unroll
      for (int dt = 0; dt < 4; ++dt) {
        const int row = dt * 16 + fr, r7 = row & 7;
        bf16x8 vf = *(const bf16x8*)(&Vb[cur][row * 64] + ((((kg << 2) + fg) ^ r7) << 3));
        oa0[dt] = __builtin_amdgcn_mfma_f32_16x16x32_bf16(pa0[kg], vf, oa0[dt], 0, 0, 0);
        oa1[dt] = __builtin_amdgcn_mfma_f32_16x16x32_bf16(pa1[kg], vf, oa1[dt], 0, 0, 0);
      }
    }
    __syncthreads();
    cur = nxt;
  }

  ls0 += __shfl_xor(ls0, 16); ls0 += __shfl_xor(ls0, 32);
  ls1 += __shfl_xor(ls1, 16); ls1 += __shfl_xor(ls1, 32);

#pragma unroll
  for (int r = 0; r < 4; ++r) {
    float i0 = 1.f / __shfl(ls0, fg * 4 + r);
    float i1 = 1.f / __shfl(ls1, fg * 4 + r);
    unsigned short* ob = O + ((size_t)(b * 1024 + q0 + fg * 4 + r)) * 1024 + h * 64 + fr;
#pragma unroll
    for (int dt = 0; dt < 4; ++dt) {
      ob[dt * 16] = f2b(oa0[dt][r] * i0);
      ob[(size_t)16 * 1024 + dt * 16] = f2b(oa1[dt][r] * i1);
    }
  }
}

// ---------- launch ----------
extern "C" void kernel_launch(void* const* d_in, const int* in_sizes, int n_in,
                              void* d_out, int out_size, void* d_ws, size_t ws_size,
                              hipStream_t stream) {
  const float* x        = (const float*)d_in[0];
  const float* cond     = (const float*)d_in[1];
  const float* qkv_w    = (const float*)d_in[2];
  const float* q_bias   = (const float*)d_in[3];
  const float* v_bias   = (const float*)d_in[4];
  const float* scale_mul= (const float*)d_in[5];
  const float* proj_w   = (const float*)d_in[6];
  const float* proj_b   = (const float*)d_in[7];
  const float* ada_w    = (const float*)d_in[8];
  const float* ada_b    = (const float*)d_in[9];
  const float* fc1_w    = (const float*)d_in[10];
  const float* fc1_b    = (const float*)d_in[11];
  const float* fc2_w    = (const float*)d_in[12];
  const float* fc2_b    = (const float*)d_in[13];
  float* out = (float*)d_out;
  char* ws = (char*)d_ws;

  unsigned short* WQ   = (unsigned short*)(ws + 0);          // 6291456
  unsigned short* WP   = (unsigned short*)(ws + 6291456);    // 2097152
  unsigned short* WF1  = (unsigned short*)(ws + 8388608);    // 8388608
  unsigned short* WF2  = (unsigned short*)(ws + 16777216);   // 8388608
  float*          SIL  = (float*)(ws + 25165824);            // 16384
  float*          ADA  = (float*)(ws + 25182208);            // 98304
  unsigned short* X1   = (unsigned short*)(ws + 25280512);   // 8388608 (reused for x2)
  unsigned short* QKVB = (unsigned short*)(ws + 33669120);   // 25165824 (dead after norm/vtrans)
  unsigned short* QN   = (unsigned short*)(ws + 58834944);   // 8388608
  unsigned short* KN   = (unsigned short*)(ws + 67223552);   // 8388608
  unsigned short* VT   = (unsigned short*)(ws + 75612160);   // 8388608
  unsigned short* OB   = (unsigned short*)(ws + 84000768);   // 8388608  -> ws top 92389376
  float*          XMID = (float*)(ws + 33669120);            // 16777216 (reuses dead QKVB)
  unsigned short* HB   = (unsigned short*)(ws + 50446336);   // 33554432 (reuses dead QKVB/QN/KN/VT)

  (void)in_sizes; (void)n_in; (void)out_size; (void)ws_size;

  k_silu<<<16, 256, 0, stream>>>(cond, SIL);
  k_ada<<<1536, 256, 0, stream>>>(SIL, ada_w, ada_b, ADA);
  k_cast<<<3072, 256, 0, stream>>>(qkv_w, WQ, 3145728);
  k_cast<<<1024, 256, 0, stream>>>(proj_w, WP, 1048576);
  k_cast<<<4096, 256, 0, stream>>>(fc1_w, WF1, 4194304);
  k_cast<<<4096, 256, 0, stream>>>(fc2_w, WF2, 4194304);

  k_ln_mod<<<4096, 256, 0, stream>>>(x, ADA, X1, 2, 4);
  k_gemm<0><<<768, 256, 0, stream>>>(X1, WQ, 4096, 3072, 1024,
                                     nullptr, q_bias, v_bias, QKVB);
  k_qknorm<<<4096, 256, 0, stream>>>(QKVB, scale_mul, QN, KN);
  k_vtrans<<<dim3(16, 64), 256, 0, stream>>>(QKVB, VT);
  k_attn<<<dim3(8, 64), 256, 0, stream>>>(QN, KN, VT, scale_mul, OB);
  k_gemm8<1><<<256, 512, 0, stream>>>(OB, WP, 4096, 1024, 1024, 512,
                                      proj_b, x, ADA, XMID);
  k_ln_mod<<<4096, 256, 0, stream>>>(XMID, ADA, X1, 3, 5);
  k_gemm<2><<<1024, 256, 0, stream>>>(X1, WF1, 4096, 4096, 1024,
                                      fc1_b, nullptr, nullptr, HB);
  k_gemm8<3><<<256, 512, 0, stream>>>(HB, WF2, 4096, 1024, 4096, 2048,
                                      fc2_b, XMID, ADA, out);
}

// Round 5
// 243.310 us; speedup vs baseline: 1.6949x; 1.0893x over previous
//
#include <hip/hip_runtime.h>

// ---------- types ----------
typedef __bf16 bf16x8_t __attribute__((ext_vector_type(8)));
typedef bf16x8_t bf16x8 __attribute__((may_alias));
typedef float f32x4 __attribute__((ext_vector_type(4)));
typedef unsigned short u16x4 __attribute__((ext_vector_type(4)));
typedef unsigned short u16x8 __attribute__((ext_vector_type(8)));

#define DEV __device__ __forceinline__

DEV float b2f(unsigned short u) {
  union { unsigned int i; float f; } x; x.i = ((unsigned int)u) << 16; return x.f;
}
DEV unsigned short f2b(float f) {
  union { float f; unsigned int i; } x; x.f = f;
  return (unsigned short)((x.i + 0x7fffu + ((x.i >> 16) & 1u)) >> 16);
}

#define AS1(p) ((__attribute__((address_space(1))) void*)(p))
#define AS3(p) ((__attribute__((address_space(3))) void*)(p))

// ---------- tiny kernels ----------
__global__ void k_silu(const float* __restrict__ c, float* __restrict__ o) {
  int i = blockIdx.x * 256 + threadIdx.x;
  float v = c[i];
  o[i] = v / (1.f + __expf(-v));
}

__global__ __launch_bounds__(256) void k_ada(const float* __restrict__ sc,
                                             const float* __restrict__ w,
                                             const float* __restrict__ bias,
                                             float* __restrict__ out) {
  int j = blockIdx.x * 4 + (threadIdx.x >> 6);
  int lane = threadIdx.x & 63;
  const float* wr = w + (size_t)j * 1024;
  float s0 = 0.f, s1 = 0.f, s2 = 0.f, s3 = 0.f;
#pragma unroll
  for (int u = 0; u < 4; ++u) {
    int k = u * 256 + lane * 4;
    float4 a = *(const float4*)(wr + k);
    float4 c0 = *(const float4*)(sc + k);
    float4 c1 = *(const float4*)(sc + 1024 + k);
    float4 c2 = *(const float4*)(sc + 2048 + k);
    float4 c3 = *(const float4*)(sc + 3072 + k);
    s0 += a.x * c0.x + a.y * c0.y + a.z * c0.z + a.w * c0.w;
    s1 += a.x * c1.x + a.y * c1.y + a.z * c1.z + a.w * c1.w;
    s2 += a.x * c2.x + a.y * c2.y + a.z * c2.z + a.w * c2.w;
    s3 += a.x * c3.x + a.y * c3.y + a.z * c3.z + a.w * c3.w;
  }
#pragma unroll
  for (int o = 1; o < 64; o <<= 1) {
    s0 += __shfl_xor(s0, o); s1 += __shfl_xor(s1, o);
    s2 += __shfl_xor(s2, o); s3 += __shfl_xor(s3, o);
  }
  if (lane == 0) {
    float bb = bias[j];
    out[j] = s0 + bb;
    out[6144 + j] = s1 + bb;
    out[12288 + j] = s2 + bb;
    out[18432 + j] = s3 + bb;
  }
}

__global__ void k_cast(const float* __restrict__ s, unsigned short* __restrict__ d, int n) {
  int i = (blockIdx.x * 256 + threadIdx.x) * 4;
  if (i >= n) return;
  float4 v = *(const float4*)(s + i);
  u16x4 o;
  o[0] = f2b(v.x); o[1] = f2b(v.y); o[2] = f2b(v.z); o[3] = f2b(v.w);
  *(u16x4*)(d + i) = o;
}

__global__ __launch_bounds__(256) void k_ln_mod(const float* __restrict__ src,
                                                const float* __restrict__ ada,
                                                unsigned short* __restrict__ dst,
                                                int sidx, int hidx) {
  int row = blockIdx.x;
  int b = row >> 10;
  int t = threadIdx.x, lane = t & 63, wv = t >> 6;
  float4 v = *(const float4*)(src + (size_t)row * 1024 + t * 4);
  float s = v.x + v.y + v.z + v.w;
  float s2 = v.x * v.x + v.y * v.y + v.z * v.z + v.w * v.w;
#pragma unroll
  for (int o = 1; o < 64; o <<= 1) { s += __shfl_xor(s, o); s2 += __shfl_xor(s2, o); }
  __shared__ float red[8];
  if (lane == 0) { red[wv] = s; red[4 + wv] = s2; }
  __syncthreads();
  float ts = red[0] + red[1] + red[2] + red[3];
  float ts2 = red[4] + red[5] + red[6] + red[7];
  float mu = ts * (1.f / 1024.f);
  float var = ts2 * (1.f / 1024.f) - mu * mu;
  float rstd = rsqrtf(var + 1e-6f);
  const float* ar = ada + (size_t)b * 6144;
  float4 sc = *(const float4*)(ar + sidx * 1024 + t * 4);
  float4 sh = *(const float4*)(ar + hidx * 1024 + t * 4);
  u16x4 o;
  o[0] = f2b((v.x - mu) * rstd * (sc.x + 1.f) + sh.x);
  o[1] = f2b((v.y - mu) * rstd * (sc.y + 1.f) + sh.y);
  o[2] = f2b((v.z - mu) * rstd * (sc.z + 1.f) + sh.z);
  o[3] = f2b((v.w - mu) * rstd * (sc.w + 1.f) + sh.w);
  *(u16x4*)(dst + (size_t)row * 1024 + t * 4) = o;
}

// ---------- 256x256 8-wave phase-pipelined GEMM (qkv, fc1) ----------
// BK=32, 4 LDS buffers (128 KiB), depth-3 half-tile prefetch, counted vmcnt(8),
// raw s_barrier per phase, setprio around MFMA clusters, swizzled LDS chunks.
// EPI: 0=qkv(+concat bias, bf16 out)  2=fc1(+bias, exact gelu, bf16 out)
template <int EPI>
__global__ __launch_bounds__(512, 2) void k_gemm256(const unsigned short* __restrict__ A,
                                                    const unsigned short* __restrict__ W,
                                                    int M, int N, int K,
                                                    const float* __restrict__ bias,
                                                    const float* __restrict__ qb,
                                                    const float* __restrict__ vb,
                                                    void* __restrict__ outp) {
  __shared__ unsigned short LDS[65536];  // 4 bufs x (A 256x32 | B 256x32)
  const int tid = threadIdx.x;
  const int wv = tid >> 6, lane = tid & 63;
  const int fr = lane & 15, fg = lane >> 4;
  const int wm = wv >> 2, wn = wv & 3;

  const int nx = N >> 8;
  const int cpx = gridDim.x >> 3;
  const int wid = ((int)blockIdx.x & 7) * cpx + ((int)blockIdx.x >> 3);
  const int m0 = (wid / nx) * 256, n0 = (wid % nx) * 256;

  // staging map: thread -> (row 0..127, phys chunk 0..3); source pre-swizzled
  const int srow = tid >> 2;
  const int sgc = (tid & 3) ^ ((srow >> 1) & 3);
  const unsigned short* srcA = A + (size_t)(m0 + srow) * K + sgc * 8;
  const unsigned short* srcB = W + (size_t)(n0 + srow) * K + sgc * 8;

#define STG256(t_, h_)                                                                        \
  __builtin_amdgcn_global_load_lds(                                                           \
      AS1(((h_) < 2 ? srcA : srcB) + (size_t)((h_)&1) * 128 * K + (size_t)(t_) * 32),         \
      AS3(LDS + ((t_)&3) * 16384 + ((h_) >> 1) * 8192 + ((h_)&1) * 4096 + wv * 512), 16, 0, 0)

  f32x4 zz = {0.f, 0.f, 0.f, 0.f};
  f32x4 acc[8][4];
#pragma unroll
  for (int i = 0; i < 8; ++i)
#pragma unroll
    for (int j = 0; j < 4; ++j) acc[i][j] = zz;

  // read offsets (swizzled chunk)
  const int xc = (fg ^ ((fr >> 1) & 3)) * 8;
  const int aoff = (wm * 128 + fr) * 32 + xc;
  const int boff = 8192 + (wn * 64 + fr) * 32 + xc;

  const int nt = K >> 5;  // 32 for K=1024

  // prologue: stage tiles 0..2 (12 half-tiles), wait for tile 0
#pragma unroll
  for (int t2 = 0; t2 < 3; ++t2) {
    STG256(t2, 0); STG256(t2, 1); STG256(t2, 2); STG256(t2, 3);
  }
  asm volatile("s_waitcnt vmcnt(8)" ::: "memory");
  __builtin_amdgcn_s_barrier();

#define LDSV(off) (*(const bf16x8*)(LDS + (off)))
#define MM2(r0, r1, aX0, aX1)                                                                 \
  {                                                                                           \
    _Pragma("unroll") for (int ni = 0; ni < 4; ++ni) {                                        \
      acc[r0][ni] = __builtin_amdgcn_mfma_f32_16x16x32_bf16(aX0, bfr[ni], acc[r0][ni], 0, 0, 0); \
      acc[r1][ni] = __builtin_amdgcn_mfma_f32_16x16x32_bf16(aX1, bfr[ni], acc[r1][ni], 0, 0, 0); \
    }                                                                                         \
  }

  for (int t = 0; t < nt; ++t) {
    const int bufo = (t & 3) * 16384;
    const bool more = (t + 3) < nt;
    bf16x8 bfr[4], aA0, aA1, aB0, aB1;
    // ---- phase 0: read B(all) + A frags 0..3; stage h0; MFMA rows 0,1
#pragma unroll
    for (int ni = 0; ni < 4; ++ni) bfr[ni] = LDSV(bufo + boff + ni * 512);
    aA0 = LDSV(bufo + aoff);
    aA1 = LDSV(bufo + aoff + 512);
    aB0 = LDSV(bufo + aoff + 2 * 512);
    aB1 = LDSV(bufo + aoff + 3 * 512);
    if (more) STG256(t + 3, 0);
    __builtin_amdgcn_s_setprio(1);
    MM2(0, 1, aA0, aA1);
    __builtin_amdgcn_s_setprio(0);
    __builtin_amdgcn_s_barrier();
    // ---- phase 1: read A frags 4,5; stage h1; MFMA rows 2,3
    aA0 = LDSV(bufo + aoff + 4 * 512);
    aA1 = LDSV(bufo + aoff + 5 * 512);
    if (more) STG256(t + 3, 1);
    __builtin_amdgcn_s_setprio(1);
    MM2(2, 3, aB0, aB1);
    __builtin_amdgcn_s_setprio(0);
    __builtin_amdgcn_s_barrier();
    // ---- phase 2: read A frags 6,7; stage h2; MFMA rows 4,5
    aB0 = LDSV(bufo + aoff + 6 * 512);
    aB1 = LDSV(bufo + aoff + 7 * 512);
    if (more) STG256(t + 3, 2);
    __builtin_amdgcn_s_setprio(1);
    MM2(4, 5, aA0, aA1);
    __builtin_amdgcn_s_setprio(0);
    __builtin_amdgcn_s_barrier();
    // ---- phase 3: stage h3; MFMA rows 6,7; boundary counted vmcnt
    if (more) STG256(t + 3, 3);
    __builtin_amdgcn_s_setprio(1);
    MM2(6, 7, aB0, aB1);
    __builtin_amdgcn_s_setprio(0);
    if (t < nt - 1) {
      if (t <= nt - 4) {
        asm volatile("s_waitcnt vmcnt(8)" ::: "memory");
      } else if (t == nt - 3) {
        asm volatile("s_waitcnt vmcnt(4)" ::: "memory");
      } else {
        asm volatile("s_waitcnt vmcnt(0)" ::: "memory");
      }
      __builtin_amdgcn_s_barrier();
    }
  }

  // epilogue
#pragma unroll
  for (int mi = 0; mi < 8; ++mi) {
#pragma unroll
    for (int ni = 0; ni < 4; ++ni) {
#pragma unroll
      for (int r = 0; r < 4; ++r) {
        int m = m0 + wm * 128 + mi * 16 + fg * 4 + r;
        int n = n0 + wn * 64 + ni * 16 + fr;
        float v = acc[mi][ni][r];
        if constexpr (EPI == 0) {
          float bb = (n < 1024) ? qb[n] : ((n < 2048) ? 0.f : vb[n - 2048]);
          ((unsigned short*)outp)[(size_t)m * N + n] = f2b(v + bb);
        } else {
          float z = v + bias[n];
          ((unsigned short*)outp)[(size_t)m * N + n] =
              f2b(0.5f * z * (1.f + erff(z * 0.70710678118654752f)));
        }
      }
    }
  }
#undef STG256
#undef LDSV
#undef MM2
}

// ---------- 8-wave split-K GEMM (proj, fc2): 3-buffer depth-2 counted pipeline ----------
// EPI: 1=proj(+b,*g1,+x resid, f32 out)  3=fc2(+b,*g2,+xmid resid, f32 out)
template <int EPI>
__global__ __launch_bounds__(512) void k_gemm8(const unsigned short* __restrict__ A,
                                               const unsigned short* __restrict__ W,
                                               int M, int N, int K, int Khalf,
                                               const float* __restrict__ bias,
                                               const float* __restrict__ resid,
                                               const float* __restrict__ ada,
                                               float* __restrict__ outp) {
  __shared__ unsigned short SM[49152];  // 96 KiB: 2 grp x 3 buf x (A 8K | B 8K); reused as xchg
  const int t = threadIdx.x, lane = t & 63, wv = t >> 6;
  const int grp = wv >> 2, w4 = wv & 3;
  const int wr = w4 >> 1, wc = w4 & 1;
  const int cpx = gridDim.x >> 3;
  const int orig = blockIdx.x;
  const int wid = (orig & 7) * cpx + (orig >> 3);
  const int nx = N >> 7;
  const int m0 = (wid / nx) * 128, n0 = (wid % nx) * 128;

  f32x4 zz = {0.f, 0.f, 0.f, 0.f};
  f32x4 acc[4][4];
#pragma unroll
  for (int i = 0; i < 4; ++i)
#pragma unroll
    for (int j = 0; j < 4; ++j) acc[i][j] = zz;

  const int srow = lane >> 2, scol = (lane & 3) * 8;
  const int kbase = grp * Khalf;
  const unsigned short* aSrc0 = A + (size_t)(m0 + w4 * 16 + srow) * K + kbase + scol;
  const unsigned short* aSrc1 = aSrc0 + (size_t)64 * K;
  const unsigned short* bSrc0 = W + (size_t)(n0 + w4 * 16 + srow) * K + kbase + scol;
  const unsigned short* bSrc1 = bSrc0 + (size_t)64 * K;
  unsigned short* grpA = SM + grp * 24576;

  const int fr = lane & 15, fk = (lane >> 4) * 8;

#define STG8(buf_, k0_)                                                                            \
  {                                                                                                \
    __builtin_amdgcn_global_load_lds(AS1(aSrc0 + (k0_)), AS3(grpA + (buf_)*8192 + w4 * 512), 16, 0, 0); \
    __builtin_amdgcn_global_load_lds(AS1(aSrc1 + (k0_)), AS3(grpA + (buf_)*8192 + 2048 + w4 * 512), 16, 0, 0); \
    __builtin_amdgcn_global_load_lds(AS1(bSrc0 + (k0_)), AS3(grpA + (buf_)*8192 + 4096 + w4 * 512), 16, 0, 0); \
    __builtin_amdgcn_global_load_lds(AS1(bSrc1 + (k0_)), AS3(grpA + (buf_)*8192 + 6144 + w4 * 512), 16, 0, 0); \
  }

  const int nsteps = Khalf >> 5;
  STG8(0, 0);
  STG8(1, 32);
  asm volatile("s_waitcnt vmcnt(4)" ::: "memory");
  __builtin_amdgcn_s_barrier();

  for (int i = 0; i < nsteps; ++i) {
    const int buf = i % 3;
    if (i + 2 < nsteps) STG8((i + 2) % 3, (i + 2) * 32);
    const unsigned short* aRd = grpA + buf * 8192 + (wr * 64 + fr) * 32 + fk;
    const unsigned short* bRd = grpA + buf * 8192 + 4096 + (wc * 64 + fr) * 32 + fk;
    bf16x8 af[4], bfv[4];
#pragma unroll
    for (int q = 0; q < 4; ++q) af[q] = *(const bf16x8*)(aRd + q * 512);
#pragma unroll
    for (int q = 0; q < 4; ++q) bfv[q] = *(const bf16x8*)(bRd + q * 512);
#pragma unroll
    for (int mi = 0; mi < 4; ++mi)
#pragma unroll
      for (int ni = 0; ni < 4; ++ni)
        acc[mi][ni] = __builtin_amdgcn_mfma_f32_16x16x32_bf16(af[mi], bfv[ni], acc[mi][ni], 0, 0, 0);
    if (i < nsteps - 1) {
      if (i + 2 < nsteps) {
        asm volatile("s_waitcnt vmcnt(4)" ::: "memory");
      } else {
        asm volatile("s_waitcnt vmcnt(0)" ::: "memory");
      }
      __builtin_amdgcn_s_barrier();
    }
  }
  __syncthreads();

  // split-K combine through LDS
  float* xch = (float*)SM;
#pragma unroll
  for (int c = 0; c < 16; ++c) {
    if (grp == 1)
      *(f32x4*)&xch[c * 1024 + (w4 * 64 + lane) * 4] = acc[c >> 2][c & 3];
  }
  __syncthreads();
  if (grp == 1) return;
#pragma unroll
  for (int c = 0; c < 16; ++c) {
    f32x4 p = *(const f32x4*)&xch[c * 1024 + (w4 * 64 + lane) * 4];
    acc[c >> 2][c & 3] += p;
  }

  const int fg = lane >> 4;
#pragma unroll
  for (int mi = 0; mi < 4; ++mi) {
#pragma unroll
    for (int ni = 0; ni < 4; ++ni) {
#pragma unroll
      for (int r = 0; r < 4; ++r) {
        int m = m0 + wr * 64 + mi * 16 + fg * 4 + r;
        int n = n0 + wc * 64 + ni * 16 + fr;
        float v = acc[mi][ni][r];
        const int aoff = (EPI == 1) ? 0 : 1024;
        float g = ada[(size_t)(m >> 10) * 6144 + aoff + n];
        outp[(size_t)m * N + n] = resid[(size_t)m * N + n] + (v + bias[n]) * g;
      }
    }
  }
#undef STG8
}

// ---------- q/k l2norm (+sm scale on q) into per-head layout ----------
__global__ __launch_bounds__(256) void k_qknorm(const unsigned short* __restrict__ qkv,
                                                const float* __restrict__ smul,
                                                unsigned short* __restrict__ Qn,
                                                unsigned short* __restrict__ Kn) {
  int row = blockIdx.x;  // b*1024 + l
  int b = row >> 10, l = row & 1023;
  int t = threadIdx.x;
  int h = t >> 4, sl = t & 15;
  const unsigned short* base = qkv + (size_t)row * 3072 + h * 64 + sl * 4;
  size_t off = ((size_t)(b * 16 + h) * 1024 + l) * 64 + sl * 4;
  {
    u16x4 qv = *(const u16x4*)base;
    float q0 = b2f(qv[0]), q1 = b2f(qv[1]), q2 = b2f(qv[2]), q3 = b2f(qv[3]);
    float ss = q0 * q0 + q1 * q1 + q2 * q2 + q3 * q3;
#pragma unroll
    for (int o = 1; o < 16; o <<= 1) ss += __shfl_xor(ss, o);
    float sm = __expf(fminf(smul[h], 4.6051701859880914f));
    float qs = sm / fmaxf(sqrtf(ss), 1e-12f);
    u16x4 o; o[0] = f2b(q0 * qs); o[1] = f2b(q1 * qs); o[2] = f2b(q2 * qs); o[3] = f2b(q3 * qs);
    *(u16x4*)(Qn + off) = o;
  }
  {
    u16x4 kv = *(const u16x4*)(base + 1024);
    float k0 = b2f(kv[0]), k1 = b2f(kv[1]), k2 = b2f(kv[2]), k3 = b2f(kv[3]);
    float ss = k0 * k0 + k1 * k1 + k2 * k2 + k3 * k3;
#pragma unroll
    for (int o = 1; o < 16; o <<= 1) ss += __shfl_xor(ss, o);
    float ks = 1.f / fmaxf(sqrtf(ss), 1e-12f);
    u16x4 o; o[0] = f2b(k0 * ks); o[1] = f2b(k1 * ks); o[2] = f2b(k2 * ks); o[3] = f2b(k3 * ks);
    *(u16x4*)(Kn + off) = o;
  }
}

// ---------- V transpose with k-slot permutation ----------
__global__ __launch_bounds__(256) void k_vtrans(const unsigned short* __restrict__ qkv,
                                                unsigned short* __restrict__ Vt) {
  int bh = blockIdx.y, b = bh >> 4, h = bh & 15;
  int l0 = blockIdx.x * 64;
  __shared__ unsigned short tile[64][72];
  int t = threadIdx.x;
  int lr = t >> 2, dp = (t & 3) * 16;
  const unsigned short* src = qkv + (size_t)(b * 1024 + l0 + lr) * 3072 + 2048 + h * 64 + dp;
  *(u16x8*)&tile[lr][dp] = *(const u16x8*)src;
  *(u16x8*)&tile[lr][dp + 8] = *(const u16x8*)(src + 8);
  __syncthreads();
  int d = t >> 2, lp = (t & 3) * 16;
  unsigned short ov[16];
#pragma unroll
  for (int j = 0; j < 16; ++j) {
    int p = lp + j;
    int l = ((p >> 5) * 2 + ((p >> 2) & 1)) * 16 + ((p >> 3) & 3) * 4 + (p & 3);
    ov[j] = tile[l][d];
  }
  unsigned short* dst = Vt + ((size_t)bh * 64 + d) * 1024 + l0 + lp;
  *(u16x8*)dst = *(u16x8*)&ov[0];
  *(u16x8*)(dst + 8) = *(u16x8*)&ov[8];
}

// ---------- flash attention (unchanged from round 3) ----------
__global__ __launch_bounds__(256) void k_attn(const unsigned short* __restrict__ Qn,
                                              const unsigned short* __restrict__ Kn,
                                              const unsigned short* __restrict__ Vt,
                                              const float* __restrict__ smul,
                                              unsigned short* __restrict__ O) {
  const int qt = blockIdx.x, bh = blockIdx.y;
  const int b = bh >> 4, h = bh & 15;
  const int t = threadIdx.x, lane = t & 63, wv = t >> 6;
  const int fr = lane & 15, fg = lane >> 4;
  __shared__ unsigned short Kb[2][4096];
  __shared__ unsigned short Vb[2][4096];

  const int q0 = qt * 128 + wv * 32;
  const unsigned short* qp = Qn + ((size_t)bh * 1024 + q0 + fr) * 64 + fg * 8;
  bf16x8 qf00 = *(const bf16x8*)qp;
  bf16x8 qf01 = *(const bf16x8*)(qp + 32);
  bf16x8 qf10 = *(const bf16x8*)(qp + 1024);
  bf16x8 qf11 = *(const bf16x8*)(qp + 1024 + 32);

  const float M = __expf(fminf(smul[h], 4.6051701859880914f));

  const int srow = lane >> 3, sc = lane & 7;
  const int xr = (sc ^ srow) * 8;
  const unsigned short* kp0 = Kn + (size_t)bh * 65536 + (size_t)(wv * 16 + srow) * 64 + xr;
  const unsigned short* kp1 = kp0 + 8 * 64;
  const unsigned short* vp0 = Vt + (size_t)bh * 65536 + (size_t)(wv * 16 + srow) * 1024 + xr;
  const unsigned short* vp1 = vp0 + 8 * 1024;

  f32x4 zz = {0.f, 0.f, 0.f, 0.f};
  f32x4 oa0[4], oa1[4];
#pragma unroll
  for (int i = 0; i < 4; ++i) { oa0[i] = zz; oa1[i] = zz; }
  float ls0 = 0.f, ls1 = 0.f;

  {
    unsigned short* kd = &Kb[0][wv * 1024];
    unsigned short* vd = &Vb[0][wv * 1024];
    __builtin_amdgcn_global_load_lds(AS1(kp0), AS3(kd), 16, 0, 0);
    __builtin_amdgcn_global_load_lds(AS1(kp1), AS3(kd + 512), 16, 0, 0);
    __builtin_amdgcn_global_load_lds(AS1(vp0), AS3(vd), 16, 0, 0);
    __builtin_amdgcn_global_load_lds(AS1(vp1), AS3(vd + 512), 16, 0, 0);
  }
  __syncthreads();

  int cur = 0;
  for (int kv = 0; kv < 1024; kv += 64) {
    const int nxt = cur ^ 1;
    if (kv + 64 < 1024) {
      const int ko = (kv + 64) * 64;
      const int vo = kv + 64;
      unsigned short* kd = &Kb[nxt][wv * 1024];
      unsigned short* vd = &Vb[nxt][wv * 1024];
      __builtin_amdgcn_global_load_lds(AS1(kp0 + ko), AS3(kd), 16, 0, 0);
      __builtin_amdgcn_global_load_lds(AS1(kp1 + ko), AS3(kd + 512), 16, 0, 0);
      __builtin_amdgcn_global_load_lds(AS1(vp0 + vo), AS3(vd), 16, 0, 0);
      __builtin_amdgcn_global_load_lds(AS1(vp1 + vo), AS3(vd + 512), 16, 0, 0);
    }

    f32x4 s0[4], s1[4];
#pragma unroll
    for (int ct = 0; ct < 4; ++ct) {
      const int row = ct * 16 + fr, r7 = row & 7;
      const unsigned short* kr = &Kb[cur][row * 64];
      bf16x8 kf0 = *(const bf16x8*)(kr + ((fg ^ r7) << 3));
      bf16x8 kf1 = *(const bf16x8*)(kr + (((4 + fg) ^ r7) << 3));
      f32x4 z0 = __builtin_amdgcn_mfma_f32_16x16x32_bf16(kf0, qf00, zz, 0, 0, 0);
      s0[ct] = __builtin_amdgcn_mfma_f32_16x16x32_bf16(kf1, qf01, z0, 0, 0, 0);
      f32x4 z1 = __builtin_amdgcn_mfma_f32_16x16x32_bf16(kf0, qf10, zz, 0, 0, 0);
      s1[ct] = __builtin_amdgcn_mfma_f32_16x16x32_bf16(kf1, qf11, z1, 0, 0, 0);
    }

    bf16x8 pa0[2], pa1[2];
#pragma unroll
    for (int kg = 0; kg < 2; ++kg) {
      bf16x8 a0, a1;
#pragma unroll
      for (int c2 = 0; c2 < 2; ++c2) {
#pragma unroll
        for (int r = 0; r < 4; ++r) {
          float e0 = __expf(s0[kg * 2 + c2][r] - M);
          float e1 = __expf(s1[kg * 2 + c2][r] - M);
          ls0 += e0; ls1 += e1;
          a0[c2 * 4 + r] = (__bf16)e0;
          a1[c2 * 4 + r] = (__bf16)e1;
        }
      }
      pa0[kg] = a0; pa1[kg] = a1;
    }

#pragma unroll
    for (int kg = 0; kg < 2; ++kg) {
#pragma unroll
      for (int dt = 0; dt < 4; ++dt) {
        const int row = dt * 16 + fr, r7 = row & 7;
        bf16x8 vf = *(const bf16x8*)(&Vb[cur][row * 64] + ((((kg << 2) + fg) ^ r7) << 3));
        oa0[dt] = __builtin_amdgcn_mfma_f32_16x16x32_bf16(pa0[kg], vf, oa0[dt], 0, 0, 0);
        oa1[dt] = __builtin_amdgcn_mfma_f32_16x16x32_bf16(pa1[kg], vf, oa1[dt], 0, 0, 0);
      }
    }
    __syncthreads();
    cur = nxt;
  }

  ls0 += __shfl_xor(ls0, 16); ls0 += __shfl_xor(ls0, 32);
  ls1 += __shfl_xor(ls1, 16); ls1 += __shfl_xor(ls1, 32);

#pragma unroll
  for (int r = 0; r < 4; ++r) {
    float i0 = 1.f / __shfl(ls0, fg * 4 + r);
    float i1 = 1.f / __shfl(ls1, fg * 4 + r);
    unsigned short* ob = O + ((size_t)(b * 1024 + q0 + fg * 4 + r)) * 1024 + h * 64 + fr;
#pragma unroll
    for (int dt = 0; dt < 4; ++dt) {
      ob[dt * 16] = f2b(oa0[dt][r] * i0);
      ob[(size_t)16 * 1024 + dt * 16] = f2b(oa1[dt][r] * i1);
    }
  }
}

// ---------- launch ----------
extern "C" void kernel_launch(void* const* d_in, const int* in_sizes, int n_in,
                              void* d_out, int out_size, void* d_ws, size_t ws_size,
                              hipStream_t stream) {
  const float* x        = (const float*)d_in[0];
  const float* cond     = (const float*)d_in[1];
  const float* qkv_w    = (const float*)d_in[2];
  const float* q_bias   = (const float*)d_in[3];
  const float* v_bias   = (const float*)d_in[4];
  const float* scale_mul= (const float*)d_in[5];
  const float* proj_w   = (const float*)d_in[6];
  const float* proj_b   = (const float*)d_in[7];
  const float* ada_w    = (const float*)d_in[8];
  const float* ada_b    = (const float*)d_in[9];
  const float* fc1_w    = (const float*)d_in[10];
  const float* fc1_b    = (const float*)d_in[11];
  const float* fc2_w    = (const float*)d_in[12];
  const float* fc2_b    = (const float*)d_in[13];
  float* out = (float*)d_out;
  char* ws = (char*)d_ws;

  unsigned short* WQ   = (unsigned short*)(ws + 0);          // 6291456
  unsigned short* WP   = (unsigned short*)(ws + 6291456);    // 2097152
  unsigned short* WF1  = (unsigned short*)(ws + 8388608);    // 8388608
  unsigned short* WF2  = (unsigned short*)(ws + 16777216);   // 8388608
  float*          SIL  = (float*)(ws + 25165824);            // 16384
  float*          ADA  = (float*)(ws + 25182208);            // 98304
  unsigned short* X1   = (unsigned short*)(ws + 25280512);   // 8388608 (reused for x2)
  unsigned short* QKVB = (unsigned short*)(ws + 33669120);   // 25165824 (dead after norm/vtrans)
  unsigned short* QN   = (unsigned short*)(ws + 58834944);   // 8388608
  unsigned short* KN   = (unsigned short*)(ws + 67223552);   // 8388608
  unsigned short* VT   = (unsigned short*)(ws + 75612160);   // 8388608
  unsigned short* OB   = (unsigned short*)(ws + 84000768);   // 8388608  -> ws top 92389376
  float*          XMID = (float*)(ws + 33669120);            // 16777216 (reuses dead QKVB)
  unsigned short* HB   = (unsigned short*)(ws + 50446336);   // 33554432 (reuses dead QKVB/QN/KN/VT)

  (void)in_sizes; (void)n_in; (void)out_size; (void)ws_size;

  k_silu<<<16, 256, 0, stream>>>(cond, SIL);
  k_ada<<<1536, 256, 0, stream>>>(SIL, ada_w, ada_b, ADA);
  k_cast<<<3072, 256, 0, stream>>>(qkv_w, WQ, 3145728);
  k_cast<<<1024, 256, 0, stream>>>(proj_w, WP, 1048576);
  k_cast<<<4096, 256, 0, stream>>>(fc1_w, WF1, 4194304);
  k_cast<<<4096, 256, 0, stream>>>(fc2_w, WF2, 4194304);

  k_ln_mod<<<4096, 256, 0, stream>>>(x, ADA, X1, 2, 4);
  k_gemm256<0><<<192, 512, 0, stream>>>(X1, WQ, 4096, 3072, 1024,
                                        nullptr, q_bias, v_bias, QKVB);
  k_qknorm<<<4096, 256, 0, stream>>>(QKVB, scale_mul, QN, KN);
  k_vtrans<<<dim3(16, 64), 256, 0, stream>>>(QKVB, VT);
  k_attn<<<dim3(8, 64), 256, 0, stream>>>(QN, KN, VT, scale_mul, OB);
  k_gemm8<1><<<256, 512, 0, stream>>>(OB, WP, 4096, 1024, 1024, 512,
                                      proj_b, x, ADA, XMID);
  k_ln_mod<<<4096, 256, 0, stream>>>(XMID, ADA, X1, 3, 5);
  k_gemm256<2><<<256, 512, 0, stream>>>(X1, WF1, 4096, 4096, 1024,
                                        fc1_b, nullptr, nullptr, HB);
  k_gemm8<3><<<256, 512, 0, stream>>>(HB, WF2, 4096, 1024, 4096, 2048,
                                      fc2_b, XMID, ADA, out);
}

// Round 6
// 237.830 us; speedup vs baseline: 1.7340x; 1.0230x over previous
//
#include <hip/hip_runtime.h>

// ---------- types ----------
typedef __bf16 bf16x8_t __attribute__((ext_vector_type(8)));
typedef bf16x8_t bf16x8 __attribute__((may_alias));
typedef float f32x4 __attribute__((ext_vector_type(4)));
typedef unsigned short u16x4 __attribute__((ext_vector_type(4)));
typedef unsigned short u16x8 __attribute__((ext_vector_type(8)));

#define DEV __device__ __forceinline__

DEV float b2f(unsigned short u) {
  union { unsigned int i; float f; } x; x.i = ((unsigned int)u) << 16; return x.f;
}
DEV unsigned short f2b(float f) {
  union { float f; unsigned int i; } x; x.f = f;
  return (unsigned short)((x.i + 0x7fffu + ((x.i >> 16) & 1u)) >> 16);
}

#define AS1(p) ((__attribute__((address_space(1))) void*)(p))
#define AS3(p) ((__attribute__((address_space(3))) void*)(p))

// ---------- tiny kernels ----------
__global__ void k_silu(const float* __restrict__ c, float* __restrict__ o) {
  int i = blockIdx.x * 256 + threadIdx.x;
  float v = c[i];
  o[i] = v / (1.f + __expf(-v));
}

__global__ __launch_bounds__(256) void k_ada(const float* __restrict__ sc,
                                             const float* __restrict__ w,
                                             const float* __restrict__ bias,
                                             float* __restrict__ out) {
  int j = blockIdx.x * 4 + (threadIdx.x >> 6);
  int lane = threadIdx.x & 63;
  const float* wr = w + (size_t)j * 1024;
  float s0 = 0.f, s1 = 0.f, s2 = 0.f, s3 = 0.f;
#pragma unroll
  for (int u = 0; u < 4; ++u) {
    int k = u * 256 + lane * 4;
    float4 a = *(const float4*)(wr + k);
    float4 c0 = *(const float4*)(sc + k);
    float4 c1 = *(const float4*)(sc + 1024 + k);
    float4 c2 = *(const float4*)(sc + 2048 + k);
    float4 c3 = *(const float4*)(sc + 3072 + k);
    s0 += a.x * c0.x + a.y * c0.y + a.z * c0.z + a.w * c0.w;
    s1 += a.x * c1.x + a.y * c1.y + a.z * c1.z + a.w * c1.w;
    s2 += a.x * c2.x + a.y * c2.y + a.z * c2.z + a.w * c2.w;
    s3 += a.x * c3.x + a.y * c3.y + a.z * c3.z + a.w * c3.w;
  }
#pragma unroll
  for (int o = 1; o < 64; o <<= 1) {
    s0 += __shfl_xor(s0, o); s1 += __shfl_xor(s1, o);
    s2 += __shfl_xor(s2, o); s3 += __shfl_xor(s3, o);
  }
  if (lane == 0) {
    float bb = bias[j];
    out[j] = s0 + bb;
    out[6144 + j] = s1 + bb;
    out[12288 + j] = s2 + bb;
    out[18432 + j] = s3 + bb;
  }
}

__global__ void k_cast(const float* __restrict__ s, unsigned short* __restrict__ d, int n) {
  int i = (blockIdx.x * 256 + threadIdx.x) * 4;
  if (i >= n) return;
  float4 v = *(const float4*)(s + i);
  u16x4 o;
  o[0] = f2b(v.x); o[1] = f2b(v.y); o[2] = f2b(v.z); o[3] = f2b(v.w);
  *(u16x4*)(d + i) = o;
}

__global__ __launch_bounds__(256) void k_ln_mod(const float* __restrict__ src,
                                                const float* __restrict__ ada,
                                                unsigned short* __restrict__ dst,
                                                int sidx, int hidx) {
  int row = blockIdx.x;
  int b = row >> 10;
  int t = threadIdx.x, lane = t & 63, wv = t >> 6;
  float4 v = *(const float4*)(src + (size_t)row * 1024 + t * 4);
  float s = v.x + v.y + v.z + v.w;
  float s2 = v.x * v.x + v.y * v.y + v.z * v.z + v.w * v.w;
#pragma unroll
  for (int o = 1; o < 64; o <<= 1) { s += __shfl_xor(s, o); s2 += __shfl_xor(s2, o); }
  __shared__ float red[8];
  if (lane == 0) { red[wv] = s; red[4 + wv] = s2; }
  __syncthreads();
  float ts = red[0] + red[1] + red[2] + red[3];
  float ts2 = red[4] + red[5] + red[6] + red[7];
  float mu = ts * (1.f / 1024.f);
  float var = ts2 * (1.f / 1024.f) - mu * mu;
  float rstd = rsqrtf(var + 1e-6f);
  const float* ar = ada + (size_t)b * 6144;
  float4 sc = *(const float4*)(ar + sidx * 1024 + t * 4);
  float4 sh = *(const float4*)(ar + hidx * 1024 + t * 4);
  u16x4 o;
  o[0] = f2b((v.x - mu) * rstd * (sc.x + 1.f) + sh.x);
  o[1] = f2b((v.y - mu) * rstd * (sc.y + 1.f) + sh.y);
  o[2] = f2b((v.z - mu) * rstd * (sc.z + 1.f) + sh.z);
  o[3] = f2b((v.w - mu) * rstd * (sc.w + 1.f) + sh.w);
  *(u16x4*)(dst + (size_t)row * 1024 + t * 4) = o;
}

// ---------- 256x256 8-wave, BK=64, m201-style phase pipeline ----------
// LDS: 4 Q-regions of 32KB; Q(q) = {A[256][32], B[256][32]} for K-half q.
// Per phase: {4-or-8 ds_read_b128 | 2 global_load_lds | barrier | lgkmcnt(0) |
// sched_barrier | setprio(1) 16 MFMA setprio(0) | (vmcnt(8) odd phases) | barrier}.
// Issue lead = 6 phases; endgame waits vmcnt(4), vmcnt(0). Conflict-free chunk-XOR.
// EPI: 0=qkv(+concat bias, bf16)  2=fc1(+bias, tanh-GELU, bf16)  4=fc2 split-K partial (bf16)
template <int EPI, int SPLIT>
__global__ __launch_bounds__(512, 2) void k_gemm256(const unsigned short* __restrict__ A,
                                                    const unsigned short* __restrict__ W,
                                                    int N, int lda, int ldb, int nt,
                                                    const float* __restrict__ bias,
                                                    const float* __restrict__ qb,
                                                    const float* __restrict__ vb,
                                                    unsigned short* __restrict__ o0,
                                                    unsigned short* __restrict__ o1,
                                                    unsigned short* __restrict__ o2,
                                                    unsigned short* __restrict__ o3) {
  __shared__ unsigned short LDS[65536];  // 128 KiB
  const int tid = threadIdx.x;
  const int wv = tid >> 6, lane = tid & 63;
  const int fr = lane & 15, fg = lane >> 4;
  const int wm = wv >> 2, wn = wv & 3;

  // XCD swizzle (grid % 8 == 0) then split extraction
  const int cpx = gridDim.x >> 3;
  int wid = ((int)blockIdx.x & 7) * cpx + ((int)blockIdx.x >> 3);
  int s = 0;
  if (SPLIT > 1) { s = wid & (SPLIT - 1); wid >>= 2; }
  const int nx = N >> 8;
  const int m0 = (wid / nx) * 256, n0 = (wid % nx) * 256;
  const int kbase = s * (nt << 6);
  unsigned short* outp = (SPLIT > 1) ? (s == 0 ? o0 : s == 1 ? o1 : s == 2 ? o2 : o3) : o0;

  // ---- staging addresses (pre-swizzled source, linear LDS dest) ----
  const int sRow = lane >> 2;                       // 0..15 in wave strip
  const int sCh = (lane & 3) ^ ((lane >> 3) & 3);   // inverse involution
  const unsigned short* aG = A + (size_t)(m0 + wv * 16 + sRow) * lda + kbase + sCh * 8;
  const unsigned short* bG = W + (size_t)(n0 + wv * 16 + sRow) * ldb + kbase + sCh * 8;

#define STQ(qi_, iop_, rh_)                                                                   \
  __builtin_amdgcn_global_load_lds(                                                          \
      AS1(((iop_) ? bG : aG) + (size_t)(rh_)*128 * ((iop_) ? ldb : lda) +                    \
          (((qi_) >> 1) * 64 + ((qi_)&1) * 32)),                                             \
      AS3(LDS + ((qi_)&3) * 16384 + (iop_)*8192 + (rh_)*4096 + wv * 512), 16, 0, 0)

  // ---- read offsets (swizzled chunk) ----
  const int rswz = (fr >> 1) & 3;
  const int aRd = (wm * 128 + fr) * 32 + ((fg ^ rswz) << 3);
  const int bRd = 8192 + (wn * 64 + fr) * 32 + ((fg ^ rswz) << 3);

  f32x4 zz = {0.f, 0.f, 0.f, 0.f};
  f32x4 acc[8][4];
#pragma unroll
  for (int i = 0; i < 8; ++i)
#pragma unroll
    for (int j = 0; j < 4; ++j) acc[i][j] = zz;

  // ---- prologue: issue Q0,Q1,Q2 (12 gloads); land Q0 ----
#pragma unroll
  for (int qq = 0; qq < 3; ++qq) {
    STQ(qq, 0, 0); STQ(qq, 0, 1); STQ(qq, 1, 0); STQ(qq, 1, 1);
  }
  asm volatile("s_waitcnt vmcnt(8)" ::: "memory");
  __builtin_amdgcn_s_barrier();

#define LDSV(off) (*(const bf16x8*)(LDS + (off)))

  for (int t = 0; t < nt; ++t) {
    bf16x8 bq0, bq1, bq2, bq3;
#pragma unroll
    for (int p = 0; p < 4; ++p) {
      const int kk = p >> 1;
      const int reg = ((2 * t + kk) & 3) * 16384;
      // ds-reads for this phase
      if ((p & 1) == 0) {
        bq0 = LDSV(reg + bRd);
        bq1 = LDSV(reg + bRd + 512);
        bq2 = LDSV(reg + bRd + 1024);
        bq3 = LDSV(reg + bRd + 1536);
      }
      bf16x8 a0 = LDSV(reg + aRd + (p & 1) * 2048);
      bf16x8 a1 = LDSV(reg + aRd + (p & 1) * 2048 + 512);
      bf16x8 a2 = LDSV(reg + aRd + (p & 1) * 2048 + 1024);
      bf16x8 a3 = LDSV(reg + aRd + (p & 1) * 2048 + 1536);
      // stage: half-Q (2 gloads), 6-phase lead
      {
        const int gph = 4 * t + p;
        const int qi = (gph >> 1) + 3;
        if (qi < 2 * nt) {
          const int iop = gph & 1;
          if (iop) { STQ(qi, 1, 0); STQ(qi, 1, 1); }
          else     { STQ(qi, 0, 0); STQ(qi, 0, 1); }
        }
      }
      __builtin_amdgcn_s_barrier();
      asm volatile("s_waitcnt lgkmcnt(0)" ::: "memory");
      __builtin_amdgcn_sched_barrier(0);
      __builtin_amdgcn_s_setprio(1);
      const int mg = (p & 1) * 4;
#pragma unroll
      for (int ni = 0; ni < 4; ++ni) {
        bf16x8 bb = ni == 0 ? bq0 : ni == 1 ? bq1 : ni == 2 ? bq2 : bq3;
        acc[mg + 0][ni] = __builtin_amdgcn_mfma_f32_16x16x32_bf16(a0, bb, acc[mg + 0][ni], 0, 0, 0);
        acc[mg + 1][ni] = __builtin_amdgcn_mfma_f32_16x16x32_bf16(a1, bb, acc[mg + 1][ni], 0, 0, 0);
        acc[mg + 2][ni] = __builtin_amdgcn_mfma_f32_16x16x32_bf16(a2, bb, acc[mg + 2][ni], 0, 0, 0);
        acc[mg + 3][ni] = __builtin_amdgcn_mfma_f32_16x16x32_bf16(a3, bb, acc[mg + 3][ni], 0, 0, 0);
      }
      __builtin_amdgcn_s_setprio(0);
      // counted waits: end of odd phases only; never 0 until endgame
      if (p == 1) {
        if (t == nt - 1) { asm volatile("s_waitcnt vmcnt(0)" ::: "memory"); }
        else             { asm volatile("s_waitcnt vmcnt(8)" ::: "memory"); }
      } else if (p == 3 && t < nt - 1) {
        if (t == nt - 2) { asm volatile("s_waitcnt vmcnt(4)" ::: "memory"); }
        else             { asm volatile("s_waitcnt vmcnt(8)" ::: "memory"); }
      }
      __builtin_amdgcn_s_barrier();
    }
  }

  // ---- epilogue ----
#pragma unroll
  for (int mi = 0; mi < 8; ++mi) {
#pragma unroll
    for (int ni = 0; ni < 4; ++ni) {
#pragma unroll
      for (int r = 0; r < 4; ++r) {
        int m = m0 + wm * 128 + mi * 16 + fg * 4 + r;
        int n = n0 + wn * 64 + ni * 16 + fr;
        float v = acc[mi][ni][r];
        if constexpr (EPI == 0) {
          float bb = (n < 1024) ? qb[n] : ((n < 2048) ? 0.f : vb[n - 2048]);
          outp[(size_t)m * N + n] = f2b(v + bb);
        } else if constexpr (EPI == 2) {
          float z = v + bias[n];
          float u = z * (0.7978845608f + 0.0356774081f * z * z);
          float e = __expf(2.f * u);
          float th = 1.f - 2.f / (e + 1.f);
          outp[(size_t)m * N + n] = f2b(0.5f * z * (1.f + th));
        } else {
          outp[(size_t)m * N + n] = f2b(v);
        }
      }
    }
  }
#undef STQ
#undef LDSV
}

// ---------- fc2 split-K reduce: out = xmid + (sum(P0..3) + bias) * g2 ----------
__global__ __launch_bounds__(256) void k_fc2red(const unsigned short* __restrict__ P0,
                                                const unsigned short* __restrict__ P1,
                                                const unsigned short* __restrict__ P2,
                                                const unsigned short* __restrict__ P3,
                                                const float* __restrict__ xmid,
                                                const float* __restrict__ bias,
                                                const float* __restrict__ ada,
                                                float* __restrict__ out) {
  size_t idx = ((size_t)blockIdx.x * 256 + threadIdx.x) * 8;
  int n = (int)(idx & 1023);
  int b = (int)(idx >> 20);
  u16x8 v0 = *(const u16x8*)(P0 + idx);
  u16x8 v1 = *(const u16x8*)(P1 + idx);
  u16x8 v2 = *(const u16x8*)(P2 + idx);
  u16x8 v3 = *(const u16x8*)(P3 + idx);
  const float* gp = ada + (size_t)b * 6144 + 1024 + n;
  const float* bp = bias + n;
  const float* xp = xmid + idx;
  float* op = out + idx;
#pragma unroll
  for (int i = 0; i < 8; ++i) {
    float sum = b2f(v0[i]) + b2f(v1[i]) + b2f(v2[i]) + b2f(v3[i]);
    op[i] = xp[i] + (sum + bp[i]) * gp[i];
  }
}

// ---------- 8-wave split-K GEMM (proj): 3-buffer depth-2 counted pipeline ----------
__global__ __launch_bounds__(512) void k_gemm8(const unsigned short* __restrict__ A,
                                               const unsigned short* __restrict__ W,
                                               int M, int N, int K, int Khalf,
                                               const float* __restrict__ bias,
                                               const float* __restrict__ resid,
                                               const float* __restrict__ ada,
                                               float* __restrict__ outp) {
  __shared__ unsigned short SM[49152];
  const int t = threadIdx.x, lane = t & 63, wv = t >> 6;
  const int grp = wv >> 2, w4 = wv & 3;
  const int wr = w4 >> 1, wc = w4 & 1;
  const int cpx = gridDim.x >> 3;
  const int orig = blockIdx.x;
  const int wid = (orig & 7) * cpx + (orig >> 3);
  const int nx = N >> 7;
  const int m0 = (wid / nx) * 128, n0 = (wid % nx) * 128;

  f32x4 zz = {0.f, 0.f, 0.f, 0.f};
  f32x4 acc[4][4];
#pragma unroll
  for (int i = 0; i < 4; ++i)
#pragma unroll
    for (int j = 0; j < 4; ++j) acc[i][j] = zz;

  const int srow = lane >> 2, scol = (lane & 3) * 8;
  const int kbase = grp * Khalf;
  const unsigned short* aSrc0 = A + (size_t)(m0 + w4 * 16 + srow) * K + kbase + scol;
  const unsigned short* aSrc1 = aSrc0 + (size_t)64 * K;
  const unsigned short* bSrc0 = W + (size_t)(n0 + w4 * 16 + srow) * K + kbase + scol;
  const unsigned short* bSrc1 = bSrc0 + (size_t)64 * K;
  unsigned short* grpA = SM + grp * 24576;

  const int fr = lane & 15, fk = (lane >> 4) * 8;

#define STG8(buf_, k0_)                                                                            \
  {                                                                                                \
    __builtin_amdgcn_global_load_lds(AS1(aSrc0 + (k0_)), AS3(grpA + (buf_)*8192 + w4 * 512), 16, 0, 0); \
    __builtin_amdgcn_global_load_lds(AS1(aSrc1 + (k0_)), AS3(grpA + (buf_)*8192 + 2048 + w4 * 512), 16, 0, 0); \
    __builtin_amdgcn_global_load_lds(AS1(bSrc0 + (k0_)), AS3(grpA + (buf_)*8192 + 4096 + w4 * 512), 16, 0, 0); \
    __builtin_amdgcn_global_load_lds(AS1(bSrc1 + (k0_)), AS3(grpA + (buf_)*8192 + 6144 + w4 * 512), 16, 0, 0); \
  }

  const int nsteps = Khalf >> 5;
  STG8(0, 0);
  STG8(1, 32);
  asm volatile("s_waitcnt vmcnt(4)" ::: "memory");
  __builtin_amdgcn_s_barrier();

  for (int i = 0; i < nsteps; ++i) {
    const int buf = i % 3;
    if (i + 2 < nsteps) STG8((i + 2) % 3, (i + 2) * 32);
    const unsigned short* aRd = grpA + buf * 8192 + (wr * 64 + fr) * 32 + fk;
    const unsigned short* bRd = grpA + buf * 8192 + 4096 + (wc * 64 + fr) * 32 + fk;
    bf16x8 af[4], bfv[4];
#pragma unroll
    for (int q = 0; q < 4; ++q) af[q] = *(const bf16x8*)(aRd + q * 512);
#pragma unroll
    for (int q = 0; q < 4; ++q) bfv[q] = *(const bf16x8*)(bRd + q * 512);
#pragma unroll
    for (int mi = 0; mi < 4; ++mi)
#pragma unroll
      for (int ni = 0; ni < 4; ++ni)
        acc[mi][ni] = __builtin_amdgcn_mfma_f32_16x16x32_bf16(af[mi], bfv[ni], acc[mi][ni], 0, 0, 0);
    if (i < nsteps - 1) {
      if (i + 2 < nsteps) {
        asm volatile("s_waitcnt vmcnt(4)" ::: "memory");
      } else {
        asm volatile("s_waitcnt vmcnt(0)" ::: "memory");
      }
      __builtin_amdgcn_s_barrier();
    }
  }
  __syncthreads();

  float* xch = (float*)SM;
#pragma unroll
  for (int c = 0; c < 16; ++c) {
    if (grp == 1)
      *(f32x4*)&xch[c * 1024 + (w4 * 64 + lane) * 4] = acc[c >> 2][c & 3];
  }
  __syncthreads();
  if (grp == 1) return;
#pragma unroll
  for (int c = 0; c < 16; ++c) {
    f32x4 p = *(const f32x4*)&xch[c * 1024 + (w4 * 64 + lane) * 4];
    acc[c >> 2][c & 3] += p;
  }

  const int fg = lane >> 4;
#pragma unroll
  for (int mi = 0; mi < 4; ++mi) {
#pragma unroll
    for (int ni = 0; ni < 4; ++ni) {
#pragma unroll
      for (int r = 0; r < 4; ++r) {
        int m = m0 + wr * 64 + mi * 16 + fg * 4 + r;
        int n = n0 + wc * 64 + ni * 16 + fr;
        float v = acc[mi][ni][r];
        float g = ada[(size_t)(m >> 10) * 6144 + n];
        outp[(size_t)m * N + n] = resid[(size_t)m * N + n] + (v + bias[n]) * g;
      }
    }
  }
#undef STG8
}

// ---------- q/k l2norm (+sm scale on q) into per-head layout ----------
__global__ __launch_bounds__(256) void k_qknorm(const unsigned short* __restrict__ qkv,
                                                const float* __restrict__ smul,
                                                unsigned short* __restrict__ Qn,
                                                unsigned short* __restrict__ Kn) {
  int row = blockIdx.x;
  int b = row >> 10, l = row & 1023;
  int t = threadIdx.x;
  int h = t >> 4, sl = t & 15;
  const unsigned short* base = qkv + (size_t)row * 3072 + h * 64 + sl * 4;
  size_t off = ((size_t)(b * 16 + h) * 1024 + l) * 64 + sl * 4;
  {
    u16x4 qv = *(const u16x4*)base;
    float q0 = b2f(qv[0]), q1 = b2f(qv[1]), q2 = b2f(qv[2]), q3 = b2f(qv[3]);
    float ss = q0 * q0 + q1 * q1 + q2 * q2 + q3 * q3;
#pragma unroll
    for (int o = 1; o < 16; o <<= 1) ss += __shfl_xor(ss, o);
    float sm = __expf(fminf(smul[h], 4.6051701859880914f));
    float qs = sm / fmaxf(sqrtf(ss), 1e-12f);
    u16x4 o; o[0] = f2b(q0 * qs); o[1] = f2b(q1 * qs); o[2] = f2b(q2 * qs); o[3] = f2b(q3 * qs);
    *(u16x4*)(Qn + off) = o;
  }
  {
    u16x4 kv = *(const u16x4*)(base + 1024);
    float k0 = b2f(kv[0]), k1 = b2f(kv[1]), k2 = b2f(kv[2]), k3 = b2f(kv[3]);
    float ss = k0 * k0 + k1 * k1 + k2 * k2 + k3 * k3;
#pragma unroll
    for (int o = 1; o < 16; o <<= 1) ss += __shfl_xor(ss, o);
    float ks = 1.f / fmaxf(sqrtf(ss), 1e-12f);
    u16x4 o; o[0] = f2b(k0 * ks); o[1] = f2b(k1 * ks); o[2] = f2b(k2 * ks); o[3] = f2b(k3 * ks);
    *(u16x4*)(Kn + off) = o;
  }
}

// ---------- V transpose with k-slot permutation ----------
__global__ __launch_bounds__(256) void k_vtrans(const unsigned short* __restrict__ qkv,
                                                unsigned short* __restrict__ Vt) {
  int bh = blockIdx.y, b = bh >> 4, h = bh & 15;
  int l0 = blockIdx.x * 64;
  __shared__ unsigned short tile[64][72];
  int t = threadIdx.x;
  int lr = t >> 2, dp = (t & 3) * 16;
  const unsigned short* src = qkv + (size_t)(b * 1024 + l0 + lr) * 3072 + 2048 + h * 64 + dp;
  *(u16x8*)&tile[lr][dp] = *(const u16x8*)src;
  *(u16x8*)&tile[lr][dp + 8] = *(const u16x8*)(src + 8);
  __syncthreads();
  int d = t >> 2, lp = (t & 3) * 16;
  unsigned short ov[16];
#pragma unroll
  for (int j = 0; j < 16; ++j) {
    int p = lp + j;
    int l = ((p >> 5) * 2 + ((p >> 2) & 1)) * 16 + ((p >> 3) & 3) * 4 + (p & 3);
    ov[j] = tile[l][d];
  }
  unsigned short* dst = Vt + ((size_t)bh * 64 + d) * 1024 + l0 + lp;
  *(u16x8*)dst = *(u16x8*)&ov[0];
  *(u16x8*)(dst + 8) = *(u16x8*)&ov[8];
}

// ---------- flash attention (unchanged) ----------
__global__ __launch_bounds__(256) void k_attn(const unsigned short* __restrict__ Qn,
                                              const unsigned short* __restrict__ Kn,
                                              const unsigned short* __restrict__ Vt,
                                              const float* __restrict__ smul,
                                              unsigned short* __restrict__ O) {
  const int qt = blockIdx.x, bh = blockIdx.y;
  const int b = bh >> 4, h = bh & 15;
  const int t = threadIdx.x, lane = t & 63, wv = t >> 6;
  const int fr = lane & 15, fg = lane >> 4;
  __shared__ unsigned short Kb[2][4096];
  __shared__ unsigned short Vb[2][4096];

  const int q0 = qt * 128 + wv * 32;
  const unsigned short* qp = Qn + ((size_t)bh * 1024 + q0 + fr) * 64 + fg * 8;
  bf16x8 qf00 = *(const bf16x8*)qp;
  bf16x8 qf01 = *(const bf16x8*)(qp + 32);
  bf16x8 qf10 = *(const bf16x8*)(qp + 1024);
  bf16x8 qf11 = *(const bf16x8*)(qp + 1024 + 32);

  const float M = __expf(fminf(smul[h], 4.6051701859880914f));

  const int srow = lane >> 3, sc = lane & 7;
  const int xr = (sc ^ srow) * 8;
  const unsigned short* kp0 = Kn + (size_t)bh * 65536 + (size_t)(wv * 16 + srow) * 64 + xr;
  const unsigned short* kp1 = kp0 + 8 * 64;
  const unsigned short* vp0 = Vt + (size_t)bh * 65536 + (size_t)(wv * 16 + srow) * 1024 + xr;
  const unsigned short* vp1 = vp0 + 8 * 1024;

  f32x4 zz = {0.f, 0.f, 0.f, 0.f};
  f32x4 oa0[4], oa1[4];
#pragma unroll
  for (int i = 0; i < 4; ++i) { oa0[i] = zz; oa1[i] = zz; }
  float ls0 = 0.f, ls1 = 0.f;

  {
    unsigned short* kd = &Kb[0][wv * 1024];
    unsigned short* vd = &Vb[0][wv * 1024];
    __builtin_amdgcn_global_load_lds(AS1(kp0), AS3(kd), 16, 0, 0);
    __builtin_amdgcn_global_load_lds(AS1(kp1), AS3(kd + 512), 16, 0, 0);
    __builtin_amdgcn_global_load_lds(AS1(vp0), AS3(vd), 16, 0, 0);
    __builtin_amdgcn_global_load_lds(AS1(vp1), AS3(vd + 512), 16, 0, 0);
  }
  __syncthreads();

  int cur = 0;
  for (int kv = 0; kv < 1024; kv += 64) {
    const int nxt = cur ^ 1;
    if (kv + 64 < 1024) {
      const int ko = (kv + 64) * 64;
      const int vo = kv + 64;
      unsigned short* kd = &Kb[nxt][wv * 1024];
      unsigned short* vd = &Vb[nxt][wv * 1024];
      __builtin_amdgcn_global_load_lds(AS1(kp0 + ko), AS3(kd), 16, 0, 0);
      __builtin_amdgcn_global_load_lds(AS1(kp1 + ko), AS3(kd + 512), 16, 0, 0);
      __builtin_amdgcn_global_load_lds(AS1(vp0 + vo), AS3(vd), 16, 0, 0);
      __builtin_amdgcn_global_load_lds(AS1(vp1 + vo), AS3(vd + 512), 16, 0, 0);
    }

    f32x4 s0[4], s1[4];
#pragma unroll
    for (int ct = 0; ct < 4; ++ct) {
      const int row = ct * 16 + fr, r7 = row & 7;
      const unsigned short* kr = &Kb[cur][row * 64];
      bf16x8 kf0 = *(const bf16x8*)(kr + ((fg ^ r7) << 3));
      bf16x8 kf1 = *(const bf16x8*)(kr + (((4 + fg) ^ r7) << 3));
      f32x4 z0 = __builtin_amdgcn_mfma_f32_16x16x32_bf16(kf0, qf00, zz, 0, 0, 0);
      s0[ct] = __builtin_amdgcn_mfma_f32_16x16x32_bf16(kf1, qf01, z0, 0, 0, 0);
      f32x4 z1 = __builtin_amdgcn_mfma_f32_16x16x32_bf16(kf0, qf10, zz, 0, 0, 0);
      s1[ct] = __builtin_amdgcn_mfma_f32_16x16x32_bf16(kf1, qf11, z1, 0, 0, 0);
    }

    bf16x8 pa0[2], pa1[2];
#pragma unroll
    for (int kg = 0; kg < 2; ++kg) {
      bf16x8 a0, a1;
#pragma unroll
      for (int c2 = 0; c2 < 2; ++c2) {
#pragma unroll
        for (int r = 0; r < 4; ++r) {
          float e0 = __expf(s0[kg * 2 + c2][r] - M);
          float e1 = __expf(s1[kg * 2 + c2][r] - M);
          ls0 += e0; ls1 += e1;
          a0[c2 * 4 + r] = (__bf16)e0;
          a1[c2 * 4 + r] = (__bf16)e1;
        }
      }
      pa0[kg] = a0; pa1[kg] = a1;
    }

#pragma unroll
    for (int kg = 0; kg < 2; ++kg) {
#pragma unroll
      for (int dt = 0; dt < 4; ++dt) {
        const int row = dt * 16 + fr, r7 = row & 7;
        bf16x8 vf = *(const bf16x8*)(&Vb[cur][row * 64] + ((((kg << 2) + fg) ^ r7) << 3));
        oa0[dt] = __builtin_amdgcn_mfma_f32_16x16x32_bf16(pa0[kg], vf, oa0[dt], 0, 0, 0);
        oa1[dt] = __builtin_amdgcn_mfma_f32_16x16x32_bf16(pa1[kg], vf, oa1[dt], 0, 0, 0);
      }
    }
    __syncthreads();
    cur = nxt;
  }

  ls0 += __shfl_xor(ls0, 16); ls0 += __shfl_xor(ls0, 32);
  ls1 += __shfl_xor(ls1, 16); ls1 += __shfl_xor(ls1, 32);

#pragma unroll
  for (int r = 0; r < 4; ++r) {
    float i0 = 1.f / __shfl(ls0, fg * 4 + r);
    float i1 = 1.f / __shfl(ls1, fg * 4 + r);
    unsigned short* ob = O + ((size_t)(b * 1024 + q0 + fg * 4 + r)) * 1024 + h * 64 + fr;
#pragma unroll
    for (int dt = 0; dt < 4; ++dt) {
      ob[dt * 16] = f2b(oa0[dt][r] * i0);
      ob[(size_t)16 * 1024 + dt * 16] = f2b(oa1[dt][r] * i1);
    }
  }
}

// ---------- launch ----------
extern "C" void kernel_launch(void* const* d_in, const int* in_sizes, int n_in,
                              void* d_out, int out_size, void* d_ws, size_t ws_size,
                              hipStream_t stream) {
  const float* x        = (const float*)d_in[0];
  const float* cond     = (const float*)d_in[1];
  const float* qkv_w    = (const float*)d_in[2];
  const float* q_bias   = (const float*)d_in[3];
  const float* v_bias   = (const float*)d_in[4];
  const float* scale_mul= (const float*)d_in[5];
  const float* proj_w   = (const float*)d_in[6];
  const float* proj_b   = (const float*)d_in[7];
  const float* ada_w    = (const float*)d_in[8];
  const float* ada_b    = (const float*)d_in[9];
  const float* fc1_w    = (const float*)d_in[10];
  const float* fc1_b    = (const float*)d_in[11];
  const float* fc2_w    = (const float*)d_in[12];
  const float* fc2_b    = (const float*)d_in[13];
  float* out = (float*)d_out;
  char* ws = (char*)d_ws;

  unsigned short* WQ   = (unsigned short*)(ws + 0);          // 6291456
  unsigned short* WP   = (unsigned short*)(ws + 6291456);    // 2097152
  unsigned short* WF1  = (unsigned short*)(ws + 8388608);    // 8388608
  unsigned short* WF2  = (unsigned short*)(ws + 16777216);   // 8388608
  float*          SIL  = (float*)(ws + 25165824);            // 16384
  float*          ADA  = (float*)(ws + 25182208);            // 98304
  unsigned short* X1   = (unsigned short*)(ws + 25280512);   // 8388608 (x1, then x2; dead after fc1)
  unsigned short* QKVB = (unsigned short*)(ws + 33669120);   // 25165824 (dead after norm/vtrans)
  unsigned short* QN   = (unsigned short*)(ws + 58834944);   // 8388608 (dead after attn)
  unsigned short* KN   = (unsigned short*)(ws + 67223552);   // 8388608 (dead after attn)
  unsigned short* VT   = (unsigned short*)(ws + 75612160);   // 8388608 (dead after attn)
  unsigned short* OB   = (unsigned short*)(ws + 84000768);   // 8388608 (dead after proj)
  float*          XMID = (float*)(ws + 33669120);            // 16777216 (reuses dead QKVB)
  unsigned short* HB   = (unsigned short*)(ws + 50446336);   // 33554432 (reuses QKVB tail/QN/KN/VT)
  // fc2 split-K partials: 4 x 8MB in regions dead by fc2 time
  unsigned short* FP0  = (unsigned short*)(ws + 0);          // over WQ (dead after qkv)
  unsigned short* FP1  = (unsigned short*)(ws + 8388608);    // over WP tail/WF1 (dead after fc1)
  unsigned short* FP2  = (unsigned short*)(ws + 25280512);   // over X1 (dead after fc1)
  unsigned short* FP3  = (unsigned short*)(ws + 84000768);   // over OB (dead after proj)

  (void)in_sizes; (void)n_in; (void)out_size; (void)ws_size;

  k_silu<<<16, 256, 0, stream>>>(cond, SIL);
  k_ada<<<1536, 256, 0, stream>>>(SIL, ada_w, ada_b, ADA);
  k_cast<<<3072, 256, 0, stream>>>(qkv_w, WQ, 3145728);
  k_cast<<<1024, 256, 0, stream>>>(proj_w, WP, 1048576);
  k_cast<<<4096, 256, 0, stream>>>(fc1_w, WF1, 4194304);
  k_cast<<<4096, 256, 0, stream>>>(fc2_w, WF2, 4194304);

  k_ln_mod<<<4096, 256, 0, stream>>>(x, ADA, X1, 2, 4);
  k_gemm256<0, 1><<<192, 512, 0, stream>>>(X1, WQ, 3072, 1024, 1024, 16,
                                           nullptr, q_bias, v_bias, QKVB, nullptr, nullptr, nullptr);
  k_qknorm<<<4096, 256, 0, stream>>>(QKVB, scale_mul, QN, KN);
  k_vtrans<<<dim3(16, 64), 256, 0, stream>>>(QKVB, VT);
  k_attn<<<dim3(8, 64), 256, 0, stream>>>(QN, KN, VT, scale_mul, OB);
  k_gemm8<<<256, 512, 0, stream>>>(OB, WP, 4096, 1024, 1024, 512,
                                   proj_b, x, ADA, XMID);
  k_ln_mod<<<4096, 256, 0, stream>>>(XMID, ADA, X1, 3, 5);
  k_gemm256<2, 1><<<256, 512, 0, stream>>>(X1, WF1, 4096, 1024, 1024, 16,
                                           fc1_b, nullptr, nullptr, HB, nullptr, nullptr, nullptr);
  k_gemm256<4, 4><<<256, 512, 0, stream>>>(HB, WF2, 1024, 4096, 4096, 16,
                                           nullptr, nullptr, nullptr, FP0, FP1, FP2, FP3);
  k_fc2red<<<2048, 256, 0, stream>>>(FP0, FP1, FP2, FP3, XMID, fc2_b, ADA, out);
}

// Round 7
// 227.612 us; speedup vs baseline: 1.8118x; 1.0449x over previous
//
#include <hip/hip_runtime.h>

// ---------- types ----------
typedef __bf16 bf16x8_t __attribute__((ext_vector_type(8)));
typedef bf16x8_t bf16x8 __attribute__((may_alias));
typedef float f32x4 __attribute__((ext_vector_type(4)));
typedef unsigned short u16x4 __attribute__((ext_vector_type(4)));
typedef unsigned short u16x8 __attribute__((ext_vector_type(8)));

#define DEV __device__ __forceinline__

DEV float b2f(unsigned short u) {
  union { unsigned int i; float f; } x; x.i = ((unsigned int)u) << 16; return x.f;
}
DEV unsigned short f2b(float f) {
  union { float f; unsigned int i; } x; x.f = f;
  return (unsigned short)((x.i + 0x7fffu + ((x.i >> 16) & 1u)) >> 16);
}

#define AS1(p) ((__attribute__((address_space(1))) void*)(p))
#define AS3(p) ((__attribute__((address_space(3))) void*)(p))

// ---------- ada (silu fused, weight read once for all 4 batches) ----------
__global__ __launch_bounds__(256) void k_ada(const float* __restrict__ cond,
                                             const float* __restrict__ w,
                                             const float* __restrict__ bias,
                                             float* __restrict__ out) {
  __shared__ float sc[4096];
  int tt = threadIdx.x;
#pragma unroll
  for (int i = 0; i < 16; ++i) {
    float v = cond[tt + i * 256];
    sc[tt + i * 256] = v / (1.f + __expf(-v));
  }
  __syncthreads();
  int j = blockIdx.x * 4 + (tt >> 6);
  int lane = tt & 63;
  const float* wr = w + (size_t)j * 1024;
  float s0 = 0.f, s1 = 0.f, s2 = 0.f, s3 = 0.f;
#pragma unroll
  for (int u = 0; u < 4; ++u) {
    int k = u * 256 + lane * 4;
    float4 a = *(const float4*)(wr + k);
    float4 c0 = *(const float4*)(sc + k);
    float4 c1 = *(const float4*)(sc + 1024 + k);
    float4 c2 = *(const float4*)(sc + 2048 + k);
    float4 c3 = *(const float4*)(sc + 3072 + k);
    s0 += a.x * c0.x + a.y * c0.y + a.z * c0.z + a.w * c0.w;
    s1 += a.x * c1.x + a.y * c1.y + a.z * c1.z + a.w * c1.w;
    s2 += a.x * c2.x + a.y * c2.y + a.z * c2.z + a.w * c2.w;
    s3 += a.x * c3.x + a.y * c3.y + a.z * c3.z + a.w * c3.w;
  }
#pragma unroll
  for (int o = 1; o < 64; o <<= 1) {
    s0 += __shfl_xor(s0, o); s1 += __shfl_xor(s1, o);
    s2 += __shfl_xor(s2, o); s3 += __shfl_xor(s3, o);
  }
  if (lane == 0) {
    float bb = bias[j];
    out[j] = s0 + bb;
    out[6144 + j] = s1 + bb;
    out[12288 + j] = s2 + bb;
    out[18432 + j] = s3 + bb;
  }
}

// ---------- all four weight casts in one launch ----------
__global__ __launch_bounds__(256) void k_castall(const float* __restrict__ q,
                                                 const float* __restrict__ p,
                                                 const float* __restrict__ f1,
                                                 const float* __restrict__ f2,
                                                 unsigned short* __restrict__ wq,
                                                 unsigned short* __restrict__ wp,
                                                 unsigned short* __restrict__ wf1,
                                                 unsigned short* __restrict__ wf2) {
  int i = blockIdx.x * 256 + threadIdx.x;
  for (int v = i; v < 3145728; v += 524288) {
    const float* s; unsigned short* d; int off;
    if (v < 786432) { s = q; d = wq; off = v; }
    else if (v < 1048576) { s = p; d = wp; off = v - 786432; }
    else if (v < 2097152) { s = f1; d = wf1; off = v - 1048576; }
    else { s = f2; d = wf2; off = v - 2097152; }
    float4 x = ((const float4*)s)[off];
    u16x4 o;
    o[0] = f2b(x.x); o[1] = f2b(x.y); o[2] = f2b(x.z); o[3] = f2b(x.w);
    *(u16x4*)(d + (size_t)off * 4) = o;
  }
}

__global__ __launch_bounds__(256) void k_ln_mod(const float* __restrict__ src,
                                                const float* __restrict__ ada,
                                                unsigned short* __restrict__ dst,
                                                int sidx, int hidx) {
  int row = blockIdx.x;
  int b = row >> 10;
  int t = threadIdx.x, lane = t & 63, wv = t >> 6;
  float4 v = *(const float4*)(src + (size_t)row * 1024 + t * 4);
  float s = v.x + v.y + v.z + v.w;
  float s2 = v.x * v.x + v.y * v.y + v.z * v.z + v.w * v.w;
#pragma unroll
  for (int o = 1; o < 64; o <<= 1) { s += __shfl_xor(s, o); s2 += __shfl_xor(s2, o); }
  __shared__ float red[8];
  if (lane == 0) { red[wv] = s; red[4 + wv] = s2; }
  __syncthreads();
  float ts = red[0] + red[1] + red[2] + red[3];
  float ts2 = red[4] + red[5] + red[6] + red[7];
  float mu = ts * (1.f / 1024.f);
  float var = ts2 * (1.f / 1024.f) - mu * mu;
  float rstd = rsqrtf(var + 1e-6f);
  const float* ar = ada + (size_t)b * 6144;
  float4 sc = *(const float4*)(ar + sidx * 1024 + t * 4);
  float4 sh = *(const float4*)(ar + hidx * 1024 + t * 4);
  u16x4 o;
  o[0] = f2b((v.x - mu) * rstd * (sc.x + 1.f) + sh.x);
  o[1] = f2b((v.y - mu) * rstd * (sc.y + 1.f) + sh.y);
  o[2] = f2b((v.z - mu) * rstd * (sc.z + 1.f) + sh.z);
  o[3] = f2b((v.w - mu) * rstd * (sc.w + 1.f) + sh.w);
  *(u16x4*)(dst + (size_t)row * 1024 + t * 4) = o;
}

// ---------- 256x256 8-wave GEMM: free-running quad-buffer rotation ----------
// K-half step s (32 cols): region s&3 of 4x32KB. Per step: issue Q(s+3)'s 4
// global_load_lds (region (s+3)&3 — last read at step s-1, barrier-separated),
// 12 ds_read_b128 + 32 MFMA free-scheduled (per-wave lgkmcnt by compiler),
// then ONE counted vmcnt (keeps Q(s+2),Q(s+3)=8 in flight; lands Q(s+1)) +
// ONE s_barrier. No per-phase lockstep, no lgkm drain, no sched_barrier.
// EPI: 0=qkv(+concat bias, bf16)  2=fc1(+bias, tanh-GELU, bf16)  4=fc2 split-K partial
template <int EPI, int SPLIT>
__global__ __launch_bounds__(512, 1) void k_gemm256(const unsigned short* __restrict__ A,
                                                    const unsigned short* __restrict__ W,
                                                    int N, int lda, int ldb, int nt,
                                                    const float* __restrict__ bias,
                                                    const float* __restrict__ qb,
                                                    const float* __restrict__ vb,
                                                    unsigned short* __restrict__ o0,
                                                    unsigned short* __restrict__ o1,
                                                    unsigned short* __restrict__ o2,
                                                    unsigned short* __restrict__ o3) {
  __shared__ unsigned short LDS[65536];  // 4 regions x (A[256][32] | B[256][32]) = 128 KiB
  const int tid = threadIdx.x;
  const int wv = tid >> 6, lane = tid & 63;
  const int fr = lane & 15, fg = lane >> 4;
  const int wm = wv >> 2, wn = wv & 3;

  const int cpx = gridDim.x >> 3;
  int wid = ((int)blockIdx.x & 7) * cpx + ((int)blockIdx.x >> 3);
  int sp = 0;
  if (SPLIT > 1) { sp = wid & (SPLIT - 1); wid >>= 2; }
  const int nx = N >> 8;
  const int m0 = (wid / nx) * 256, n0 = (wid % nx) * 256;
  const int kbase = sp * (nt << 6);
  unsigned short* outp = (SPLIT > 1) ? (sp == 0 ? o0 : sp == 1 ? o1 : sp == 2 ? o2 : o3) : o0;

  // staging: wave wv covers rows [wv*16, wv*16+16); source chunk pre-swizzled
  const int sRow = lane >> 2;
  const int sCh = (lane & 3) ^ ((lane >> 3) & 3);
  const unsigned short* aG = A + (size_t)(m0 + wv * 16 + sRow) * lda + kbase + sCh * 8;
  const unsigned short* bG = W + (size_t)(n0 + wv * 16 + sRow) * ldb + kbase + sCh * 8;

#define STQ4(qi_)                                                                              \
  {                                                                                            \
    const int wr_ = ((qi_)&3) * 16384;                                                         \
    const int ko_ = (qi_)*32;                                                                  \
    __builtin_amdgcn_global_load_lds(AS1(aG + ko_), AS3(LDS + wr_ + wv * 512), 16, 0, 0);      \
    __builtin_amdgcn_global_load_lds(AS1(aG + (size_t)128 * lda + ko_),                        \
                                     AS3(LDS + wr_ + 4096 + wv * 512), 16, 0, 0);              \
    __builtin_amdgcn_global_load_lds(AS1(bG + ko_), AS3(LDS + wr_ + 8192 + wv * 512), 16, 0, 0);\
    __builtin_amdgcn_global_load_lds(AS1(bG + (size_t)128 * ldb + ko_),                        \
                                     AS3(LDS + wr_ + 12288 + wv * 512), 16, 0, 0);             \
  }

  const int rswz = (fr >> 1) & 3;
  const int aOff = (wm * 128 + fr) * 32 + ((fg ^ rswz) << 3);
  const int bOff = 8192 + (wn * 64 + fr) * 32 + ((fg ^ rswz) << 3);

  f32x4 zz = {0.f, 0.f, 0.f, 0.f};
  f32x4 acc[8][4];
#pragma unroll
  for (int i = 0; i < 8; ++i)
#pragma unroll
    for (int j = 0; j < 4; ++j) acc[i][j] = zz;

  // prologue: issue Q0,Q1,Q2 (12 loads); land Q0
#pragma unroll
  for (int q = 0; q < 3; ++q) STQ4(q);
  asm volatile("s_waitcnt vmcnt(8)" ::: "memory");
  __builtin_amdgcn_s_barrier();

#define LDSV(off) (*(const bf16x8*)(LDS + (off)))

  const int ns = 2 * nt;
  for (int st = 0; st < ns; ++st) {
    if (st + 3 < ns) STQ4(st + 3);
    const int rb = (st & 3) * 16384;
    bf16x8 bf0 = LDSV(rb + bOff);
    bf16x8 bf1 = LDSV(rb + bOff + 512);
    bf16x8 bf2 = LDSV(rb + bOff + 1024);
    bf16x8 bf3 = LDSV(rb + bOff + 1536);
    bf16x8 af[8];
#pragma unroll
    for (int mi = 0; mi < 8; ++mi) af[mi] = LDSV(rb + aOff + mi * 512);
#pragma unroll
    for (int mi = 0; mi < 8; ++mi) {
      acc[mi][0] = __builtin_amdgcn_mfma_f32_16x16x32_bf16(af[mi], bf0, acc[mi][0], 0, 0, 0);
      acc[mi][1] = __builtin_amdgcn_mfma_f32_16x16x32_bf16(af[mi], bf1, acc[mi][1], 0, 0, 0);
      acc[mi][2] = __builtin_amdgcn_mfma_f32_16x16x32_bf16(af[mi], bf2, acc[mi][2], 0, 0, 0);
      acc[mi][3] = __builtin_amdgcn_mfma_f32_16x16x32_bf16(af[mi], bf3, acc[mi][3], 0, 0, 0);
    }
    if (st < ns - 3) {
      asm volatile("s_waitcnt vmcnt(8)" ::: "memory");
    } else if (st == ns - 3) {
      asm volatile("s_waitcnt vmcnt(4)" ::: "memory");
    } else if (st == ns - 2) {
      asm volatile("s_waitcnt vmcnt(0)" ::: "memory");
    }
    __builtin_amdgcn_s_barrier();
  }

  // epilogue
#pragma unroll
  for (int mi = 0; mi < 8; ++mi) {
#pragma unroll
    for (int ni = 0; ni < 4; ++ni) {
#pragma unroll
      for (int r = 0; r < 4; ++r) {
        int m = m0 + wm * 128 + mi * 16 + fg * 4 + r;
        int n = n0 + wn * 64 + ni * 16 + fr;
        float v = acc[mi][ni][r];
        if constexpr (EPI == 0) {
          float bb = (n < 1024) ? qb[n] : ((n < 2048) ? 0.f : vb[n - 2048]);
          outp[(size_t)m * N + n] = f2b(v + bb);
        } else if constexpr (EPI == 2) {
          float z = v + bias[n];
          float u = z * (0.7978845608f + 0.0356774081f * z * z);
          float e = __expf(2.f * u);
          float th = 1.f - 2.f / (e + 1.f);
          outp[(size_t)m * N + n] = f2b(0.5f * z * (1.f + th));
        } else {
          outp[(size_t)m * N + n] = f2b(v);
        }
      }
    }
  }
#undef STQ4
#undef LDSV
}

// ---------- fc2 split-K reduce ----------
__global__ __launch_bounds__(256) void k_fc2red(const unsigned short* __restrict__ P0,
                                                const unsigned short* __restrict__ P1,
                                                const unsigned short* __restrict__ P2,
                                                const unsigned short* __restrict__ P3,
                                                const float* __restrict__ xmid,
                                                const float* __restrict__ bias,
                                                const float* __restrict__ ada,
                                                float* __restrict__ out) {
  size_t idx = ((size_t)blockIdx.x * 256 + threadIdx.x) * 8;
  int n = (int)(idx & 1023);
  int b = (int)(idx >> 20);
  u16x8 v0 = *(const u16x8*)(P0 + idx);
  u16x8 v1 = *(const u16x8*)(P1 + idx);
  u16x8 v2 = *(const u16x8*)(P2 + idx);
  u16x8 v3 = *(const u16x8*)(P3 + idx);
  const float* gp = ada + (size_t)b * 6144 + 1024 + n;
  const float* bp = bias + n;
  const float* xp = xmid + idx;
  float* op = out + idx;
#pragma unroll
  for (int i = 0; i < 8; ++i) {
    float sum = b2f(v0[i]) + b2f(v1[i]) + b2f(v2[i]) + b2f(v3[i]);
    op[i] = xp[i] + (sum + bp[i]) * gp[i];
  }
}

// ---------- 8-wave split-K GEMM (proj) ----------
__global__ __launch_bounds__(512) void k_gemm8(const unsigned short* __restrict__ A,
                                               const unsigned short* __restrict__ W,
                                               int M, int N, int K, int Khalf,
                                               const float* __restrict__ bias,
                                               const float* __restrict__ resid,
                                               const float* __restrict__ ada,
                                               float* __restrict__ outp) {
  __shared__ unsigned short SM[49152];
  const int t = threadIdx.x, lane = t & 63, wv = t >> 6;
  const int grp = wv >> 2, w4 = wv & 3;
  const int wr = w4 >> 1, wc = w4 & 1;
  const int cpx = gridDim.x >> 3;
  const int orig = blockIdx.x;
  const int wid = (orig & 7) * cpx + (orig >> 3);
  const int nx = N >> 7;
  const int m0 = (wid / nx) * 128, n0 = (wid % nx) * 128;

  f32x4 zz = {0.f, 0.f, 0.f, 0.f};
  f32x4 acc[4][4];
#pragma unroll
  for (int i = 0; i < 4; ++i)
#pragma unroll
    for (int j = 0; j < 4; ++j) acc[i][j] = zz;

  const int srow = lane >> 2, scol = (lane & 3) * 8;
  const int kbase = grp * Khalf;
  const unsigned short* aSrc0 = A + (size_t)(m0 + w4 * 16 + srow) * K + kbase + scol;
  const unsigned short* aSrc1 = aSrc0 + (size_t)64 * K;
  const unsigned short* bSrc0 = W + (size_t)(n0 + w4 * 16 + srow) * K + kbase + scol;
  const unsigned short* bSrc1 = bSrc0 + (size_t)64 * K;
  unsigned short* grpA = SM + grp * 24576;

  const int fr = lane & 15, fk = (lane >> 4) * 8;

#define STG8(buf_, k0_)                                                                            \
  {                                                                                                \
    __builtin_amdgcn_global_load_lds(AS1(aSrc0 + (k0_)), AS3(grpA + (buf_)*8192 + w4 * 512), 16, 0, 0); \
    __builtin_amdgcn_global_load_lds(AS1(aSrc1 + (k0_)), AS3(grpA + (buf_)*8192 + 2048 + w4 * 512), 16, 0, 0); \
    __builtin_amdgcn_global_load_lds(AS1(bSrc0 + (k0_)), AS3(grpA + (buf_)*8192 + 4096 + w4 * 512), 16, 0, 0); \
    __builtin_amdgcn_global_load_lds(AS1(bSrc1 + (k0_)), AS3(grpA + (buf_)*8192 + 6144 + w4 * 512), 16, 0, 0); \
  }

  const int nsteps = Khalf >> 5;
  STG8(0, 0);
  STG8(1, 32);
  asm volatile("s_waitcnt vmcnt(4)" ::: "memory");
  __builtin_amdgcn_s_barrier();

  for (int i = 0; i < nsteps; ++i) {
    const int buf = i % 3;
    if (i + 2 < nsteps) STG8((i + 2) % 3, (i + 2) * 32);
    const unsigned short* aRd = grpA + buf * 8192 + (wr * 64 + fr) * 32 + fk;
    const unsigned short* bRd = grpA + buf * 8192 + 4096 + (wc * 64 + fr) * 32 + fk;
    bf16x8 af[4], bfv[4];
#pragma unroll
    for (int q = 0; q < 4; ++q) af[q] = *(const bf16x8*)(aRd + q * 512);
#pragma unroll
    for (int q = 0; q < 4; ++q) bfv[q] = *(const bf16x8*)(bRd + q * 512);
#pragma unroll
    for (int mi = 0; mi < 4; ++mi)
#pragma unroll
      for (int ni = 0; ni < 4; ++ni)
        acc[mi][ni] = __builtin_amdgcn_mfma_f32_16x16x32_bf16(af[mi], bfv[ni], acc[mi][ni], 0, 0, 0);
    if (i < nsteps - 1) {
      if (i + 2 < nsteps) {
        asm volatile("s_waitcnt vmcnt(4)" ::: "memory");
      } else {
        asm volatile("s_waitcnt vmcnt(0)" ::: "memory");
      }
      __builtin_amdgcn_s_barrier();
    }
  }
  __syncthreads();

  float* xch = (float*)SM;
#pragma unroll
  for (int c = 0; c < 16; ++c) {
    if (grp == 1)
      *(f32x4*)&xch[c * 1024 + (w4 * 64 + lane) * 4] = acc[c >> 2][c & 3];
  }
  __syncthreads();
  if (grp == 1) return;
#pragma unroll
  for (int c = 0; c < 16; ++c) {
    f32x4 p = *(const f32x4*)&xch[c * 1024 + (w4 * 64 + lane) * 4];
    acc[c >> 2][c & 3] += p;
  }

  const int fg = lane >> 4;
#pragma unroll
  for (int mi = 0; mi < 4; ++mi) {
#pragma unroll
    for (int ni = 0; ni < 4; ++ni) {
#pragma unroll
      for (int r = 0; r < 4; ++r) {
        int m = m0 + wr * 64 + mi * 16 + fg * 4 + r;
        int n = n0 + wc * 64 + ni * 16 + fr;
        float v = acc[mi][ni][r];
        float g = ada[(size_t)(m >> 10) * 6144 + n];
        outp[(size_t)m * N + n] = resid[(size_t)m * N + n] + (v + bias[n]) * g;
      }
    }
  }
#undef STG8
}

// ---------- q/k l2norm (+sm scale on q) into per-head layout ----------
__global__ __launch_bounds__(256) void k_qknorm(const unsigned short* __restrict__ qkv,
                                                const float* __restrict__ smul,
                                                unsigned short* __restrict__ Qn,
                                                unsigned short* __restrict__ Kn) {
  int row = blockIdx.x;
  int b = row >> 10, l = row & 1023;
  int t = threadIdx.x;
  int h = t >> 4, sl = t & 15;
  const unsigned short* base = qkv + (size_t)row * 3072 + h * 64 + sl * 4;
  size_t off = ((size_t)(b * 16 + h) * 1024 + l) * 64 + sl * 4;
  {
    u16x4 qv = *(const u16x4*)base;
    float q0 = b2f(qv[0]), q1 = b2f(qv[1]), q2 = b2f(qv[2]), q3 = b2f(qv[3]);
    float ss = q0 * q0 + q1 * q1 + q2 * q2 + q3 * q3;
#pragma unroll
    for (int o = 1; o < 16; o <<= 1) ss += __shfl_xor(ss, o);
    float sm = __expf(fminf(smul[h], 4.6051701859880914f));
    float qs = sm / fmaxf(sqrtf(ss), 1e-12f);
    u16x4 o; o[0] = f2b(q0 * qs); o[1] = f2b(q1 * qs); o[2] = f2b(q2 * qs); o[3] = f2b(q3 * qs);
    *(u16x4*)(Qn + off) = o;
  }
  {
    u16x4 kv = *(const u16x4*)(base + 1024);
    float k0 = b2f(kv[0]), k1 = b2f(kv[1]), k2 = b2f(kv[2]), k3 = b2f(kv[3]);
    float ss = k0 * k0 + k1 * k1 + k2 * k2 + k3 * k3;
#pragma unroll
    for (int o = 1; o < 16; o <<= 1) ss += __shfl_xor(ss, o);
    float ks = 1.f / fmaxf(sqrtf(ss), 1e-12f);
    u16x4 o; o[0] = f2b(k0 * ks); o[1] = f2b(k1 * ks); o[2] = f2b(k2 * ks); o[3] = f2b(k3 * ks);
    *(u16x4*)(Kn + off) = o;
  }
}

// ---------- V transpose with k-slot permutation ----------
__global__ __launch_bounds__(256) void k_vtrans(const unsigned short* __restrict__ qkv,
                                                unsigned short* __restrict__ Vt) {
  int bh = blockIdx.y, b = bh >> 4, h = bh & 15;
  int l0 = blockIdx.x * 64;
  __shared__ unsigned short tile[64][72];
  int t = threadIdx.x;
  int lr = t >> 2, dp = (t & 3) * 16;
  const unsigned short* src = qkv + (size_t)(b * 1024 + l0 + lr) * 3072 + 2048 + h * 64 + dp;
  *(u16x8*)&tile[lr][dp] = *(const u16x8*)src;
  *(u16x8*)&tile[lr][dp + 8] = *(const u16x8*)(src + 8);
  __syncthreads();
  int d = t >> 2, lp = (t & 3) * 16;
  unsigned short ov[16];
#pragma unroll
  for (int j = 0; j < 16; ++j) {
    int p = lp + j;
    int l = ((p >> 5) * 2 + ((p >> 2) & 1)) * 16 + ((p >> 3) & 3) * 4 + (p & 3);
    ov[j] = tile[l][d];
  }
  unsigned short* dst = Vt + ((size_t)bh * 64 + d) * 1024 + l0 + lp;
  *(u16x8*)dst = *(u16x8*)&ov[0];
  *(u16x8*)(dst + 8) = *(u16x8*)&ov[8];
}

// ---------- flash attention (unchanged) ----------
__global__ __launch_bounds__(256) void k_attn(const unsigned short* __restrict__ Qn,
                                              const unsigned short* __restrict__ Kn,
                                              const unsigned short* __restrict__ Vt,
                                              const float* __restrict__ smul,
                                              unsigned short* __restrict__ O) {
  const int qt = blockIdx.x, bh = blockIdx.y;
  const int b = bh >> 4, h = bh & 15;
  const int t = threadIdx.x, lane = t & 63, wv = t >> 6;
  const int fr = lane & 15, fg = lane >> 4;
  __shared__ unsigned short Kb[2][4096];
  __shared__ unsigned short Vb[2][4096];

  const int q0 = qt * 128 + wv * 32;
  const unsigned short* qp = Qn + ((size_t)bh * 1024 + q0 + fr) * 64 + fg * 8;
  bf16x8 qf00 = *(const bf16x8*)qp;
  bf16x8 qf01 = *(const bf16x8*)(qp + 32);
  bf16x8 qf10 = *(const bf16x8*)(qp + 1024);
  bf16x8 qf11 = *(const bf16x8*)(qp + 1024 + 32);

  const float M = __expf(fminf(smul[h], 4.6051701859880914f));

  const int srow = lane >> 3, sc = lane & 7;
  const int xr = (sc ^ srow) * 8;
  const unsigned short* kp0 = Kn + (size_t)bh * 65536 + (size_t)(wv * 16 + srow) * 64 + xr;
  const unsigned short* kp1 = kp0 + 8 * 64;
  const unsigned short* vp0 = Vt + (size_t)bh * 65536 + (size_t)(wv * 16 + srow) * 1024 + xr;
  const unsigned short* vp1 = vp0 + 8 * 1024;

  f32x4 zz = {0.f, 0.f, 0.f, 0.f};
  f32x4 oa0[4], oa1[4];
#pragma unroll
  for (int i = 0; i < 4; ++i) { oa0[i] = zz; oa1[i] = zz; }
  float ls0 = 0.f, ls1 = 0.f;

  {
    unsigned short* kd = &Kb[0][wv * 1024];
    unsigned short* vd = &Vb[0][wv * 1024];
    __builtin_amdgcn_global_load_lds(AS1(kp0), AS3(kd), 16, 0, 0);
    __builtin_amdgcn_global_load_lds(AS1(kp1), AS3(kd + 512), 16, 0, 0);
    __builtin_amdgcn_global_load_lds(AS1(vp0), AS3(vd), 16, 0, 0);
    __builtin_amdgcn_global_load_lds(AS1(vp1), AS3(vd + 512), 16, 0, 0);
  }
  __syncthreads();

  int cur = 0;
  for (int kv = 0; kv < 1024; kv += 64) {
    const int nxt = cur ^ 1;
    if (kv + 64 < 1024) {
      const int ko = (kv + 64) * 64;
      const int vo = kv + 64;
      unsigned short* kd = &Kb[nxt][wv * 1024];
      unsigned short* vd = &Vb[nxt][wv * 1024];
      __builtin_amdgcn_global_load_lds(AS1(kp0 + ko), AS3(kd), 16, 0, 0);
      __builtin_amdgcn_global_load_lds(AS1(kp1 + ko), AS3(kd + 512), 16, 0, 0);
      __builtin_amdgcn_global_load_lds(AS1(vp0 + vo), AS3(vd), 16, 0, 0);
      __builtin_amdgcn_global_load_lds(AS1(vp1 + vo), AS3(vd + 512), 16, 0, 0);
    }

    f32x4 s0[4], s1[4];
#pragma unroll
    for (int ct = 0; ct < 4; ++ct) {
      const int row = ct * 16 + fr, r7 = row & 7;
      const unsigned short* kr = &Kb[cur][row * 64];
      bf16x8 kf0 = *(const bf16x8*)(kr + ((fg ^ r7) << 3));
      bf16x8 kf1 = *(const bf16x8*)(kr + (((4 + fg) ^ r7) << 3));
      f32x4 z0 = __builtin_amdgcn_mfma_f32_16x16x32_bf16(kf0, qf00, zz, 0, 0, 0);
      s0[ct] = __builtin_amdgcn_mfma_f32_16x16x32_bf16(kf1, qf01, z0, 0, 0, 0);
      f32x4 z1 = __builtin_amdgcn_mfma_f32_16x16x32_bf16(kf0, qf10, zz, 0, 0, 0);
      s1[ct] = __builtin_amdgcn_mfma_f32_16x16x32_bf16(kf1, qf11, z1, 0, 0, 0);
    }

    bf16x8 pa0[2], pa1[2];
#pragma unroll
    for (int kg = 0; kg < 2; ++kg) {
      bf16x8 a0, a1;
#pragma unroll
      for (int c2 = 0; c2 < 2; ++c2) {
#pragma unroll
        for (int r = 0; r < 4; ++r) {
          float e0 = __expf(s0[kg * 2 + c2][r] - M);
          float e1 = __expf(s1[kg * 2 + c2][r] - M);
          ls0 += e0; ls1 += e1;
          a0[c2 * 4 + r] = (__bf16)e0;
          a1[c2 * 4 + r] = (__bf16)e1;
        }
      }
      pa0[kg] = a0; pa1[kg] = a1;
    }

#pragma unroll
    for (int kg = 0; kg < 2; ++kg) {
#pragma unroll
      for (int dt = 0; dt < 4; ++dt) {
        const int row = dt * 16 + fr, r7 = row & 7;
        bf16x8 vf = *(const bf16x8*)(&Vb[cur][row * 64] + ((((kg << 2) + fg) ^ r7) << 3));
        oa0[dt] = __builtin_amdgcn_mfma_f32_16x16x32_bf16(pa0[kg], vf, oa0[dt], 0, 0, 0);
        oa1[dt] = __builtin_amdgcn_mfma_f32_16x16x32_bf16(pa1[kg], vf, oa1[dt], 0, 0, 0);
      }
    }
    __syncthreads();
    cur = nxt;
  }

  ls0 += __shfl_xor(ls0, 16); ls0 += __shfl_xor(ls0, 32);
  ls1 += __shfl_xor(ls1, 16); ls1 += __shfl_xor(ls1, 32);

#pragma unroll
  for (int r = 0; r < 4; ++r) {
    float i0 = 1.f / __shfl(ls0, fg * 4 + r);
    float i1 = 1.f / __shfl(ls1, fg * 4 + r);
    unsigned short* ob = O + ((size_t)(b * 1024 + q0 + fg * 4 + r)) * 1024 + h * 64 + fr;
#pragma unroll
    for (int dt = 0; dt < 4; ++dt) {
      ob[dt * 16] = f2b(oa0[dt][r] * i0);
      ob[(size_t)16 * 1024 + dt * 16] = f2b(oa1[dt][r] * i1);
    }
  }
}

// ---------- launch ----------
extern "C" void kernel_launch(void* const* d_in, const int* in_sizes, int n_in,
                              void* d_out, int out_size, void* d_ws, size_t ws_size,
                              hipStream_t stream) {
  const float* x        = (const float*)d_in[0];
  const float* cond     = (const float*)d_in[1];
  const float* qkv_w    = (const float*)d_in[2];
  const float* q_bias   = (const float*)d_in[3];
  const float* v_bias   = (const float*)d_in[4];
  const float* scale_mul= (const float*)d_in[5];
  const float* proj_w   = (const float*)d_in[6];
  const float* proj_b   = (const float*)d_in[7];
  const float* ada_w    = (const float*)d_in[8];
  const float* ada_b    = (const float*)d_in[9];
  const float* fc1_w    = (const float*)d_in[10];
  const float* fc1_b    = (const float*)d_in[11];
  const float* fc2_w    = (const float*)d_in[12];
  const float* fc2_b    = (const float*)d_in[13];
  float* out = (float*)d_out;
  char* ws = (char*)d_ws;

  unsigned short* WQ   = (unsigned short*)(ws + 0);          // 6291456
  unsigned short* WP   = (unsigned short*)(ws + 6291456);    // 2097152
  unsigned short* WF1  = (unsigned short*)(ws + 8388608);    // 8388608
  unsigned short* WF2  = (unsigned short*)(ws + 16777216);   // 8388608
  float*          ADA  = (float*)(ws + 25182208);            // 98304
  unsigned short* X1   = (unsigned short*)(ws + 25280512);   // 8388608 (x1, then x2; dead after fc1)
  unsigned short* QKVB = (unsigned short*)(ws + 33669120);   // 25165824 (dead after norm/vtrans)
  unsigned short* QN   = (unsigned short*)(ws + 58834944);   // 8388608 (dead after attn)
  unsigned short* KN   = (unsigned short*)(ws + 67223552);   // 8388608 (dead after attn)
  unsigned short* VT   = (unsigned short*)(ws + 75612160);   // 8388608 (dead after attn)
  unsigned short* OB   = (unsigned short*)(ws + 84000768);   // 8388608 (dead after proj)
  float*          XMID = (float*)(ws + 33669120);            // 16777216 (reuses dead QKVB)
  unsigned short* HB   = (unsigned short*)(ws + 50446336);   // 33554432 (reuses QKVB tail/QN/KN/VT)
  unsigned short* FP0  = (unsigned short*)(ws + 0);          // over WQ (dead after qkv)
  unsigned short* FP1  = (unsigned short*)(ws + 8388608);    // over WF1 (dead after fc1)
  unsigned short* FP2  = (unsigned short*)(ws + 25280512);   // over X1 (dead after fc1)
  unsigned short* FP3  = (unsigned short*)(ws + 84000768);   // over OB (dead after proj)

  (void)in_sizes; (void)n_in; (void)out_size; (void)ws_size;

  k_ada<<<1536, 256, 0, stream>>>(cond, ada_w, ada_b, ADA);
  k_castall<<<2048, 256, 0, stream>>>(qkv_w, proj_w, fc1_w, fc2_w, WQ, WP, WF1, WF2);

  k_ln_mod<<<4096, 256, 0, stream>>>(x, ADA, X1, 2, 4);
  k_gemm256<0, 1><<<192, 512, 0, stream>>>(X1, WQ, 3072, 1024, 1024, 16,
                                           nullptr, q_bias, v_bias, QKVB, nullptr, nullptr, nullptr);
  k_qknorm<<<4096, 256, 0, stream>>>(QKVB, scale_mul, QN, KN);
  k_vtrans<<<dim3(16, 64), 256, 0, stream>>>(QKVB, VT);
  k_attn<<<dim3(8, 64), 256, 0, stream>>>(QN, KN, VT, scale_mul, OB);
  k_gemm8<<<256, 512, 0, stream>>>(OB, WP, 4096, 1024, 1024, 512,
                                   proj_b, x, ADA, XMID);
  k_ln_mod<<<4096, 256, 0, stream>>>(XMID, ADA, X1, 3, 5);
  k_gemm256<2, 1><<<256, 512, 0, stream>>>(X1, WF1, 4096, 1024, 1024, 16,
                                           fc1_b, nullptr, nullptr, HB, nullptr, nullptr, nullptr);
  k_gemm256<4, 4><<<256, 512, 0, stream>>>(HB, WF2, 1024, 4096, 4096, 16,
                                           nullptr, nullptr, nullptr, FP0, FP1, FP2, FP3);
  k_fc2red<<<2048, 256, 0, stream>>>(FP0, FP1, FP2, FP3, XMID, fc2_b, ADA, out);
}